// Round 1
// baseline (2894.715 us; speedup 1.0000x reference)
//
#include <hip/hip_runtime.h>
#include <math.h>

#define LEAKC 0.2f
#define THREEFRY_PARTITIONABLE 1

#define NB 4
#define NC 64
#define NH 48
#define NW 48
#define ND 256
#define NFN 8
#define NT 4
#define NV 16
#define NE 16
#define LLEN 16384
#define HW 2304

__device__ __forceinline__ float leaky(float x){ return x > 0.f ? x : LEAKC*x; }

__device__ __forceinline__ void threefry2x32(unsigned k0, unsigned k1, unsigned& x0, unsigned& x1){
  unsigned ks0=k0, ks1=k1, ks2=k0^k1^0x1BD11BDAu;
  x0+=ks0; x1+=ks1;
  const int rot0[4]={13,15,26,6};
  const int rot1[4]={17,29,16,24};
#define TF_APPLY(rr) {for(int r=0;r<4;r++){x0+=x1; x1=(x1<<rr[r])|(x1>>(32-rr[r])); x1^=x0;}}
  TF_APPLY(rot0); x0+=ks1; x1+=ks2+1u;
  TF_APPLY(rot1); x0+=ks2; x1+=ks0+2u;
  TF_APPLY(rot0); x0+=ks0; x1+=ks1+3u;
  TF_APPLY(rot1); x0+=ks1; x1+=ks2+4u;
  TF_APPLY(rot0); x0+=ks2; x1+=ks0+5u;
#undef TF_APPLY
}

__device__ __forceinline__ float jax_uniform128(int i){
#if THREEFRY_PARTITIONABLE
  unsigned x0=0u, x1=(unsigned)i;
  threefry2x32(0u,42u,x0,x1);
  unsigned bits = x0 ^ x1;
#else
  unsigned j=(unsigned)(i&63);
  unsigned x0=j, x1=j+64u;
  threefry2x32(0u,42u,x0,x1);
  unsigned bits = (i<64) ? x0 : x1;
#endif
  unsigned fb=(bits>>9)|0x3f800000u;
  float f=__uint_as_float(fb)-1.0f;
  float u=f*(1.0f-1e-10f)+1e-10f;
  return fmaxf(1e-10f,u);
}

// ---------------- rms over task_f per b ----------------
__global__ __launch_bounds__(256) void k_rms(const float* __restrict__ task_f, float* __restrict__ rms){
  int b=blockIdx.x;
  const float* x=task_f+b*LLEN;
  float s=0;
  for(int i=threadIdx.x;i<LLEN;i+=256){ float v=x[i]; s+=v*v; }
  __shared__ float red[256];
  red[threadIdx.x]=s; __syncthreads();
  for(int off=128;off;off>>=1){ if(threadIdx.x<off) red[threadIdx.x]+=red[threadIdx.x+off]; __syncthreads(); }
  if(threadIdx.x==0) rms[b]=sqrtf(red[0]/(float)LLEN);
}

// ---------------- branch A conv1 stats (4 ch) ----------------
__global__ __launch_bounds__(256) void k_statsA(const float* __restrict__ task_f, const float* __restrict__ w1,
                         float* __restrict__ totA, float* __restrict__ a0A, float* __restrict__ aLA){
  int b=blockIdx.x, seg=blockIdx.y;
  const float* x=task_f+b*LLEN;
  float tot[4]={0,0,0,0};
  int l0=seg*2048;
  for(int l=l0+threadIdx.x;l<l0+2048;l+=256){
    float xm=(l>0)?x[l-1]:0.f;
    float xc=x[l];
    float xp=(l<LLEN-1)?x[l+1]:0.f;
#pragma unroll
    for(int c=0;c<4;c++){
      float a=leaky(w1[c*3+0]*xm + w1[c*3+1]*xc + w1[c*3+2]*xp);
      tot[c]+=a;
      if(l==0) a0A[b*4+c]=a;
      if(l==LLEN-1) aLA[b*4+c]=a;
    }
  }
  __shared__ float red[4*256];
#pragma unroll
  for(int c=0;c<4;c++) red[c*256+threadIdx.x]=tot[c];
  __syncthreads();
  for(int off=128;off;off>>=1){
    if(threadIdx.x<off){
#pragma unroll
      for(int c=0;c<4;c++) red[c*256+threadIdx.x]+=red[c*256+threadIdx.x+off];
    }
    __syncthreads();
  }
  if(threadIdx.x<4) atomicAdd(&totA[b*4+threadIdx.x], red[threadIdx.x*256]);
}

// ---------------- branch B conv1 stats (64 ch, rms-normalized input) ----------------
__global__ __launch_bounds__(256) void k_statsB(const float* __restrict__ task_f, const float* __restrict__ rms,
                         const float* __restrict__ w1,
                         float* __restrict__ totB, float* __restrict__ a0B, float* __restrict__ aLB){
  int b=blockIdx.x, seg=blockIdx.y;
  float sc=1.f/(rms[b]+1e-8f);
  const float* x=task_f+b*LLEN;
  float tot[64];
#pragma unroll
  for(int c=0;c<64;c++) tot[c]=0.f;
  int l0=seg*2048;
  for(int l=l0+threadIdx.x;l<l0+2048;l+=256){
    float xm=((l>0)?x[l-1]:0.f)*sc;
    float xc=x[l]*sc;
    float xp=((l<LLEN-1)?x[l+1]:0.f)*sc;
#pragma unroll
    for(int c=0;c<64;c++){
      float a=leaky(w1[c*3+0]*xm + w1[c*3+1]*xc + w1[c*3+2]*xp);
      tot[c]+=a;
      if(l==0) a0B[b*64+c]=a;
      if(l==LLEN-1) aLB[b*64+c]=a;
    }
  }
  // wave reduce then cross-wave
#pragma unroll
  for(int c=0;c<64;c++){
    float v=tot[c];
    for(int off=32;off;off>>=1) v+=__shfl_down(v,off);
    tot[c]=v;
  }
  __shared__ float red[4][64];
  int wave=threadIdx.x>>6, lane=threadIdx.x&63;
  if(lane==0){
#pragma unroll
    for(int c=0;c<64;c++) red[wave][c]=tot[c];
  }
  __syncthreads();
  if(threadIdx.x<64){
    float s=red[0][threadIdx.x]+red[1][threadIdx.x]+red[2][threadIdx.x]+red[3][threadIdx.x];
    atomicAdd(&totB[b*64+threadIdx.x], s);
  }
}

// ---------------- iA conv + bn + leaky + spatial mean -> i1 (B,8) ----------------
__global__ __launch_bounds__(256) void k_i1(const float* __restrict__ img, const float* __restrict__ w,
                     const float* __restrict__ bn, float* __restrict__ i1){
  int b=blockIdx.x>>3, oc=blockIdx.x&7;
  __shared__ float wk[576];
  __shared__ float red[256];
  for(int i=threadIdx.x;i<576;i+=256) wk[i]=w[oc*576+i];
  __syncthreads();
  float g=bn[oc], be=bn[8+oc], m=bn[16+oc], v=bn[24+oc];
  float scale=g/sqrtf(v+1e-5f);
  const float* ib=img+b*NC*HW;
  float s=0;
  for(int p=threadIdx.x;p<HW;p+=256){
    int h=p/48, wj=p%48;
    float acc=0;
    for(int c=0;c<64;c++){
      const float* ic=ib+c*HW;
#pragma unroll
      for(int i=0;i<3;i++){
        int hh=h+i-1; if((unsigned)hh>=48u) continue;
#pragma unroll
        for(int j=0;j<3;j++){
          int ww=wj+j-1; if((unsigned)ww>=48u) continue;
          acc+=wk[c*9+i*3+j]*ic[hh*48+ww];
        }
      }
    }
    s+=leaky((acc-m)*scale+be);
  }
  red[threadIdx.x]=s; __syncthreads();
  for(int off=128;off;off>>=1){ if(threadIdx.x<off) red[threadIdx.x]+=red[threadIdx.x+off]; __syncthreads(); }
  if(threadIdx.x==0) i1[b*8+oc]=red[0]*(1.f/2304.f);
}

// ---------------- bv_ic1 conv + bn + leaky -> ie1 (B,64,48,48) ----------------
__global__ __launch_bounds__(256) void k_ic1(const float* __restrict__ img, const float* __restrict__ w,
                      const float* __restrict__ bn, float* __restrict__ ie1){
  int t=blockIdx.x*256+threadIdx.x;
  int wj=t%48, h=(t/48)%48, oc=(t/HW)%64, b=t/(64*HW);
  const float* ib=img+b*NC*HW;
  const float* wk=w+oc*576;
  float acc=0;
  for(int c=0;c<64;c++){
    const float* ic=ib+c*HW;
    const float* wc=wk+c*9;
#pragma unroll
    for(int i=0;i<3;i++){
      int hh=h+i-1; if((unsigned)hh>=48u) continue;
#pragma unroll
      for(int j=0;j<3;j++){
        int ww=wj+j-1; if((unsigned)ww>=48u) continue;
        acc+=wc[i*3+j]*ic[hh*48+ww];
      }
    }
  }
  float g=bn[oc], be=bn[64+oc], m=bn[128+oc], v=bn[192+oc];
  ie1[t]=leaky((acc-m)*(g/sqrtf(v+1e-5f))+be);
}

// ---------------- bv_ic2 conv + bn + leaky + spatial mean -> ie (B,128) ----------------
__global__ __launch_bounds__(256) void k_ic2mean(const float* __restrict__ ie1, const float* __restrict__ w,
                          const float* __restrict__ bn, float* __restrict__ ie){
  int b=blockIdx.x>>7, oc=blockIdx.x&127;
  __shared__ float wk[576];
  __shared__ float red[256];
  for(int i=threadIdx.x;i<576;i+=256) wk[i]=w[oc*576+i];
  __syncthreads();
  float g=bn[oc], be=bn[128+oc], m=bn[256+oc], v=bn[384+oc];
  float scale=g/sqrtf(v+1e-5f);
  const float* ib=ie1+b*64*HW;
  float s=0;
  for(int p=threadIdx.x;p<HW;p+=256){
    int h=p/48, wj=p%48;
    float acc=0;
    for(int c=0;c<64;c++){
      const float* ic=ib+c*HW;
#pragma unroll
      for(int i=0;i<3;i++){
        int hh=h+i-1; if((unsigned)hh>=48u) continue;
#pragma unroll
        for(int j=0;j<3;j++){
          int ww=wj+j-1; if((unsigned)ww>=48u) continue;
          acc+=wk[c*9+i*3+j]*ic[hh*48+ww];
        }
      }
    }
    s+=leaky((acc-m)*scale+be);
  }
  red[threadIdx.x]=s; __syncthreads();
  for(int off=128;off;off>>=1){ if(threadIdx.x<off) red[threadIdx.x]+=red[threadIdx.x+off]; __syncthreads(); }
  if(threadIdx.x==0) ie[b*128+oc]=red[0]*(1.f/2304.f);
}

// ---------------- single-block "everything small" kernel ----------------
struct SmallParams {
  const float *totA,*a0A,*aLA,*totB,*a0B,*aLB,*i1,*ie;
  const float *tA_w2,*bv_t2;
  const float *at_w1,*at_b1,*at_ln_g,*at_ln_b,*at_w2,*at_b2;
  const float *protos,*bank;
  const float *bv_w1,*bv_b1,*bv_ln_g,*bv_ln_b,*bv_w2,*bv_b2;
  const float *m1_w1,*m1_b1,*m1_ln_g,*m1_ln_b;
  const float *m3_w1,*m3_b1,*m3_ln_g,*m3_ln_b;
  int* idx_out; float* hid1; float* hid3;
};

__global__ __launch_bounds__(256) void k_small(SmallParams p){
  __shared__ float t1[32], te[512], h[256], tif[512], tifn[512];
  __shared__ float pn[64], pden[4], tden[32], z[128];
  __shared__ float lnmu[4], lninv[4], hh[256], ffb[1024], fden[4];
  __shared__ float scores[256], bvf[8192], hpre[2048], rmu[32], rinv[32];
  __shared__ int sidx[32], sfirst[16], srank[32], ssel[32], order[256];
  int tid=threadIdx.x;
  const float invL=1.0f/16384.0f;

  // t1 (B,8) from branch-A stats (mean commutes through linear conv2)
  if(tid<32){
    int b=tid>>3, c2=tid&7;
    float s=0;
    for(int c1=0;c1<4;c1++){
      float T=p.totA[b*4+c1], A0=p.a0A[b*4+c1], AL=p.aLA[b*4+c1];
      const float* w=&p.tA_w2[(c2*4+c1)*3];
      s += w[0]*(T-AL) + w[1]*T + w[2]*(T-A0);
    }
    t1[tid]=s*invL;
  }
  // te (B,128) from branch-B stats
  for(int ii=tid;ii<512;ii+=256){
    int b=ii>>7, c2=ii&127;
    float s=0;
    for(int c1=0;c1<64;c1++){
      float T=p.totB[b*64+c1], A0=p.a0B[b*64+c1], AL=p.aLB[b*64+c1];
      const float* w=&p.bv_t2[(c2*64+c1)*3];
      s += w[0]*(T-AL) + w[1]*T + w[2]*(T-A0);
    }
    te[ii]=s*invL;
  }
  __syncthreads();
  // h_pre = f1 @ at_w1 + b1
  {
    int b=tid>>6, j=tid&63;
    float s=p.at_b1[j];
    for(int i=0;i<16;i++){
      float f1=(i<8)?t1[b*8+i]:p.i1[b*8+(i-8)];
      s+=f1*p.at_w1[i*64+j];
    }
    h[tid]=s;
  }
  __syncthreads();
  if(tid<4){
    float mu=0; for(int j=0;j<64;j++) mu+=h[tid*64+j]; mu*=(1.f/64.f);
    float var=0; for(int j=0;j<64;j++){float d=h[tid*64+j]-mu; var+=d*d;} var*=(1.f/64.f);
    lnmu[tid]=mu; lninv[tid]=1.0f/sqrtf(var+1e-5f);
  }
  __syncthreads();
  {
    int b=tid>>6, j=tid&63;
    float v=(h[tid]-lnmu[b])*lninv[b]*p.at_ln_g[j]+p.at_ln_b[j];
    h[tid]=fmaxf(v,0.f);
  }
  __syncthreads();
  // tif = h @ at_w2 + b2   (B,128)
  for(int ii=tid;ii<512;ii+=256){
    int b=ii>>7, n=ii&127;
    float s=p.at_b2[n];
    for(int j=0;j<64;j++) s+=h[b*64+j]*p.at_w2[j*128+n];
    tif[ii]=s;
  }
  __syncthreads();
  if(tid<32){
    int b=tid>>3, f=tid&7;
    float s=0; for(int e=0;e<16;e++){float v=tif[b*128+e*8+f]; s+=v*v;}
    tden[tid]=fmaxf(sqrtf(s),1e-8f);
  } else if(tid<36){
    int t=tid-32;
    float s=0; for(int e=0;e<16;e++){float v=p.protos[t*16+e]; s+=v*v;}
    pden[t]=fmaxf(sqrtf(s),1e-8f);
  }
  __syncthreads();
  for(int ii=tid;ii<512;ii+=256){
    int b=ii>>7, n=ii&127, f=n&7;
    tifn[ii]=tif[ii]/tden[b*8+f];
  }
  if(tid<64){ int t=tid>>4; pn[tid]=p.protos[tid]/pden[t]; }
  __syncthreads();
  // logits + gumbel ; z = logits + g (argmax-equivalent to softmax path)
  if(tid<128){
    int b=tid>>5, f=(tid>>2)&7, t=tid&3;
    float s=0;
    for(int e=0;e<16;e++) s+=pn[t*16+e]*tifn[b*128+e*8+f];
    float u=jax_uniform128(tid);
    float g=-logf(-logf(u));
    z[tid]=s+g;
  }
  __syncthreads();
  if(tid<32){
    float best=z[tid*4]; int bi=0;
    for(int t=1;t<4;t++){ float v=z[tid*4+t]; if(v>best){best=v;bi=t;} }
    sidx[tid]=bi;
  }
  __syncthreads();
  if(tid<16){
    int b=tid>>2, t=tid&3;
    int fi=0;
    for(int f=7;f>=0;f--) if(sidx[b*8+f]==t) fi=f;
    sfirst[tid]=fi;
  } else if(tid<48){
    int r=tid-16, b=r>>3, f=r&7;
    int c=0; for(int f2=0;f2<f;f2++) if(sidx[b*8+f2]==sidx[b*8+f]) c++;
    srank[r]=c;
  }
  __syncthreads();
  // branch-B MLP: ff=[te,ie] -> LN(relu) -> ff2
  {
    int b=tid>>6, j=tid&63;
    float s=p.bv_b1[j];
    for(int k=0;k<256;k++){
      float fv=(k<128)?te[b*128+k]:p.ie[b*128+(k-128)];
      s+=fv*p.bv_w1[k*64+j];
    }
    hh[tid]=s;
  }
  __syncthreads();
  if(tid<4){
    float mu=0; for(int j=0;j<64;j++) mu+=hh[tid*64+j]; mu*=(1.f/64.f);
    float var=0; for(int j=0;j<64;j++){float d=hh[tid*64+j]-mu; var+=d*d;} var*=(1.f/64.f);
    lnmu[tid]=mu; lninv[tid]=1.0f/sqrtf(var+1e-5f);
  }
  __syncthreads();
  {
    int b=tid>>6, j=tid&63;
    float v=(hh[tid]-lnmu[b])*lninv[b]*p.bv_ln_g[j]+p.bv_ln_b[j];
    hh[tid]=fmaxf(v,0.f);
  }
  __syncthreads();
  for(int ii=tid;ii<1024;ii+=256){
    int b=ii>>8, n=ii&255;
    float s=p.bv_b2[n];
    for(int j=0;j<64;j++) s+=hh[b*64+j]*p.bv_w2[j*256+n];
    ffb[ii]=s;
  }
  __syncthreads();
  if(tid<4){
    float s=0; for(int d=0;d<256;d++){float v=ffb[tid*256+d]; s+=v*v;}
    fden[tid]=fmaxf(sqrtf(s),1e-12f);
  }
  __syncthreads();
  for(int ii=tid;ii<1024;ii+=256) ffb[ii]/=fden[ii>>8];
  __syncthreads();
  // scores (b,t,v) = <ffn, l2n(bank[tt,v])>
  {
    int b=tid>>6, t=(tid>>4)&3, v=tid&15;
    int tt=sidx[b*8+sfirst[b*4+t]];
    const float* row=&p.bank[(tt*16+v)*256];
    float s=0, nb=0;
    for(int d=0;d<256;d++){ float rv=row[d]; s+=ffb[b*256+d]*rv; nb+=rv*rv; }
    scores[tid]=s/fmaxf(sqrtf(nb),1e-12f);
  }
  __syncthreads();
  // stable descending argsort over V=16 (selection, ties -> lower index)
  if(tid<16){
    const float* sc=&scores[tid*16];
    unsigned used=0;
    for(int pk=0;pk<16;pk++){
      int best=-1; float bv=-1e30f;
      for(int v2=0;v2<16;v2++){
        if(used&(1u<<v2)) continue;
        float vv=sc[v2];
        if(best<0||vv>bv){bv=vv;best=v2;}
      }
      used|=1u<<best;
      order[tid*16+pk]=best;
    }
  }
  __syncthreads();
  if(tid<32){
    int b=tid>>3;
    int t=sidx[tid];
    ssel[tid]=order[(b*4+t)*16+srank[tid]];
    p.idx_out[tid]=t;
  }
  __syncthreads();
  // bvf rows = bank[idx, sel]
  for(int r=0;r<32;r++){
    int t=sidx[r], v=ssel[r];
    bvf[r*256+tid]=p.bank[(t*16+v)*256+tid];
  }
  __syncthreads();
  // m1 hidden
  for(int ii=tid;ii<2048;ii+=256){
    int row=ii>>6, j=ii&63;
    float s=p.m1_b1[j];
    for(int d=0;d<256;d++) s+=bvf[row*256+d]*p.m1_w1[d*64+j];
    hpre[ii]=s;
  }
  __syncthreads();
  if(tid<32){
    float mu=0; for(int j=0;j<64;j++) mu+=hpre[tid*64+j]; mu*=(1.f/64.f);
    float var=0; for(int j=0;j<64;j++){float d=hpre[tid*64+j]-mu; var+=d*d;} var*=(1.f/64.f);
    rmu[tid]=mu; rinv[tid]=1.0f/sqrtf(var+1e-5f);
  }
  __syncthreads();
  for(int ii=tid;ii<2048;ii+=256){
    int row=ii>>6, j=ii&63;
    float v=(hpre[ii]-rmu[row])*rinv[row]*p.m1_ln_g[j]+p.m1_ln_b[j];
    p.hid1[ii]=fmaxf(v,0.f);
  }
  __syncthreads();
  // m3 hidden
  for(int ii=tid;ii<2048;ii+=256){
    int row=ii>>6, j=ii&63;
    float s=p.m3_b1[j];
    for(int d=0;d<256;d++) s+=bvf[row*256+d]*p.m3_w1[d*64+j];
    hpre[ii]=s;
  }
  __syncthreads();
  if(tid<32){
    float mu=0; for(int j=0;j<64;j++) mu+=hpre[tid*64+j]; mu*=(1.f/64.f);
    float var=0; for(int j=0;j<64;j++){float d=hpre[tid*64+j]-mu; var+=d*d;} var*=(1.f/64.f);
    rmu[tid]=mu; rinv[tid]=1.0f/sqrtf(var+1e-5f);
  }
  __syncthreads();
  for(int ii=tid;ii<2048;ii+=256){
    int row=ii>>6, j=ii&63;
    float v=(hpre[ii]-rmu[row])*rinv[row]*p.m3_ln_g[j]+p.m3_ln_b[j];
    p.hid3[ii]=fmaxf(v,0.f);
  }
}

// ---------------- w1 head: (32,64) @ (64,4096) + b ----------------
__global__ __launch_bounds__(256) void k_w1head(const float* __restrict__ hid, const float* __restrict__ w2,
                         const float* __restrict__ b2, float* __restrict__ out){
  int bf=blockIdx.x;
  int col=blockIdx.y*256+threadIdx.x;
  __shared__ float hl[64];
  if(threadIdx.x<64) hl[threadIdx.x]=hid[bf*64+threadIdx.x];
  __syncthreads();
  float s=b2[col];
  for(int k=0;k<64;k++) s+=hl[k]*w2[k*4096+col];
  out[bf*4096+col]=s;
}

// ---------------- w3 head: (32,64) @ (64,36864) + b ----------------
__global__ __launch_bounds__(256) void k_w3head(const float* __restrict__ hid, const float* __restrict__ w2,
                         const float* __restrict__ b2, float* __restrict__ out){
  int bf=blockIdx.x;
  int col=blockIdx.y*256+threadIdx.x;
  __shared__ float hl[64];
  if(threadIdx.x<64) hl[threadIdx.x]=hid[bf*64+threadIdx.x];
  __syncthreads();
  float s=b2[col];
  for(int k=0;k<64;k++) s+=hl[k]*w2[(size_t)k*36864+col];
  out[(size_t)bf*36864+col]=s;
}

// ---------------- dynamic conv (selected branch) + bn + leaky + mean over f ----------------
__global__ __launch_bounds__(256) void k_dyn(const float* __restrict__ img, const float* __restrict__ w1,
                      const float* __restrict__ w3, const int* __restrict__ idx,
                      const float* __restrict__ bn, float* __restrict__ x){
  int t=blockIdx.x*256+threadIdx.x;
  int wj=t%48, h=(t/48)%48, o=(t/HW)%64, b=t/(64*HW);
  const float* ib=img+b*NC*HW;
  float g=bn[o], be=bn[64+o], m=bn[128+o], v=bn[192+o];
  float scale=g/sqrtf(v+1e-5f);
  float xs=0;
  for(int f=0;f<8;f++){
    int tt=idx[b*8+f];
    float acc=0;
    if(tt==0){
      const float* wr=w1+((b*8+f)*64+o)*64;
      const float* ip=ib+h*48+wj;
      for(int c=0;c<64;c++) acc+=wr[c]*ip[c*HW];
    } else {
      int d=tt;
      const float* wr=w3+(size_t)((b*8+f)*64+o)*64*9;
      for(int c=0;c<64;c++){
        const float* ic=ib+c*HW;
        const float* wc=wr+c*9;
#pragma unroll
        for(int i=0;i<3;i++){
          int hh=h+d*(i-1); if((unsigned)hh>=48u) continue;
#pragma unroll
          for(int j=0;j<3;j++){
            int ww=wj+d*(j-1); if((unsigned)ww>=48u) continue;
            acc+=wc[i*3+j]*ic[hh*48+ww];
          }
        }
      }
    }
    xs+=leaky((acc-m)*scale+be);
  }
  x[t]=xs*0.125f;
}

// ---------------- final: zc 1x1 conv + bias + residual ----------------
__global__ __launch_bounds__(256) void k_final(const float* __restrict__ img, const float* __restrict__ x,
                        const float* __restrict__ zw, const float* __restrict__ zb,
                        float* __restrict__ out){
  int t=blockIdx.x*256+threadIdx.x;
  int o=(t/HW)%64, b=t/(64*HW);
  int p2=t%HW;
  const float* xb=x+b*64*HW+p2;
  const float* wr=zw+o*64;
  float s=zb[o];
  for(int c=0;c<64;c++) s+=wr[c]*xb[c*HW];
  out[t]=s+img[t];
}

extern "C" void kernel_launch(void* const* d_in, const int* in_sizes, int n_in,
                              void* d_out, int out_size, void* d_ws, size_t ws_size,
                              hipStream_t stream){
  const float* bank   =(const float*)d_in[0];
  const float* task_f =(const float*)d_in[1];
  const float* img_f  =(const float*)d_in[2];
  const float* protos =(const float*)d_in[3];
  const float* tA_w1  =(const float*)d_in[4];
  const float* tA_w2  =(const float*)d_in[5];
  const float* iA_w   =(const float*)d_in[6];
  const float* iA_bn  =(const float*)d_in[7];
  const float* at_w1  =(const float*)d_in[8];
  const float* at_b1  =(const float*)d_in[9];
  const float* at_ln_g=(const float*)d_in[10];
  const float* at_ln_b=(const float*)d_in[11];
  const float* at_w2  =(const float*)d_in[12];
  const float* at_b2  =(const float*)d_in[13];
  const float* bv_t1  =(const float*)d_in[14];
  const float* bv_t2  =(const float*)d_in[15];
  const float* bv_ic1 =(const float*)d_in[16];
  const float* bv_bn1 =(const float*)d_in[17];
  const float* bv_ic2 =(const float*)d_in[18];
  const float* bv_bn2 =(const float*)d_in[19];
  const float* bv_w1  =(const float*)d_in[20];
  const float* bv_b1  =(const float*)d_in[21];
  const float* bv_ln_g=(const float*)d_in[22];
  const float* bv_ln_b=(const float*)d_in[23];
  const float* bv_w2  =(const float*)d_in[24];
  const float* bv_b2  =(const float*)d_in[25];
  const float* m1_w1  =(const float*)d_in[26];
  const float* m1_b1  =(const float*)d_in[27];
  const float* m1_ln_g=(const float*)d_in[28];
  const float* m1_ln_b=(const float*)d_in[29];
  const float* m1_w2  =(const float*)d_in[30];
  const float* m1_b2  =(const float*)d_in[31];
  const float* m3_w1  =(const float*)d_in[32];
  const float* m3_b1  =(const float*)d_in[33];
  const float* m3_ln_g=(const float*)d_in[34];
  const float* m3_ln_b=(const float*)d_in[35];
  const float* m3_w2  =(const float*)d_in[36];
  const float* m3_b2  =(const float*)d_in[37];
  const float* blr_bn =(const float*)d_in[38];
  const float* zc_w   =(const float*)d_in[39];
  const float* zc_b   =(const float*)d_in[40];

  float* ws=(float*)d_ws;
  float* totA=ws+0;      float* a0A=ws+16;      float* aLA=ws+32;
  float* totB=ws+48;     float* a0B=ws+304;     float* aLB=ws+560;
  float* rms=ws+816;     float* i1=ws+820;      float* ie=ws+852;
  int*   idxp=(int*)(ws+1364);
  float* hid1=ws+1408;   float* hid3=ws+3456;
  float* w1o=ws+5504;    float* w3o=ws+136576;
  float* ie1=ws+1316224; float* x=ws+1906048;
  // total ws use: 2,495,872 floats (~10 MB)

  hipMemsetAsync(ws, 0, 816*sizeof(float), stream);   // zero atomic accumulators

  k_rms<<<NB,256,0,stream>>>(task_f, rms);
  k_statsA<<<dim3(NB,8),256,0,stream>>>(task_f, tA_w1, totA, a0A, aLA);
  k_statsB<<<dim3(NB,8),256,0,stream>>>(task_f, rms, bv_t1, totB, a0B, aLB);
  k_i1<<<NB*8,256,0,stream>>>(img_f, iA_w, iA_bn, i1);
  k_ic1<<<2304,256,0,stream>>>(img_f, bv_ic1, bv_bn1, ie1);
  k_ic2mean<<<NB*128,256,0,stream>>>(ie1, bv_ic2, bv_bn2, ie);

  SmallParams sp;
  sp.totA=totA; sp.a0A=a0A; sp.aLA=aLA; sp.totB=totB; sp.a0B=a0B; sp.aLB=aLB;
  sp.i1=i1; sp.ie=ie; sp.tA_w2=tA_w2; sp.bv_t2=bv_t2;
  sp.at_w1=at_w1; sp.at_b1=at_b1; sp.at_ln_g=at_ln_g; sp.at_ln_b=at_ln_b;
  sp.at_w2=at_w2; sp.at_b2=at_b2; sp.protos=protos; sp.bank=bank;
  sp.bv_w1=bv_w1; sp.bv_b1=bv_b1; sp.bv_ln_g=bv_ln_g; sp.bv_ln_b=bv_ln_b;
  sp.bv_w2=bv_w2; sp.bv_b2=bv_b2;
  sp.m1_w1=m1_w1; sp.m1_b1=m1_b1; sp.m1_ln_g=m1_ln_g; sp.m1_ln_b=m1_ln_b;
  sp.m3_w1=m3_w1; sp.m3_b1=m3_b1; sp.m3_ln_g=m3_ln_g; sp.m3_ln_b=m3_ln_b;
  sp.idx_out=idxp; sp.hid1=hid1; sp.hid3=hid3;
  k_small<<<1,256,0,stream>>>(sp);

  k_w1head<<<dim3(32,16),256,0,stream>>>(hid1, m1_w2, m1_b2, w1o);
  k_w3head<<<dim3(32,144),256,0,stream>>>(hid3, m3_w2, m3_b2, w3o);
  k_dyn<<<2304,256,0,stream>>>(img_f, w1o, w3o, idxp, blr_bn, x);
  k_final<<<2304,256,0,stream>>>(img_f, x, zc_w, zc_b, (float*)d_out);

  (void)in_sizes; (void)n_in; (void)out_size; (void)ws_size;
}

// Round 2
// 2260.978 us; speedup vs baseline: 1.2803x; 1.2803x over previous
//
#include <hip/hip_runtime.h>
#include <math.h>

#define LEAKC 0.2f

#define NB 4
#define NC 64
#define NH 48
#define NW 48
#define ND 256
#define NFN 8
#define NT 4
#define NV 16
#define NE 16
#define LLEN 16384
#define HW 2304

__device__ __forceinline__ float leaky(float x){ return x > 0.f ? x : LEAKC*x; }

__device__ __forceinline__ float wave_sum64(float v){
  for(int off=32;off;off>>=1) v += __shfl_xor(v,off);
  return v;
}

__device__ __forceinline__ void threefry2x32(unsigned k0, unsigned k1, unsigned& x0, unsigned& x1){
  unsigned ks0=k0, ks1=k1, ks2=k0^k1^0x1BD11BDAu;
  x0+=ks0; x1+=ks1;
  const int rot0[4]={13,15,26,6};
  const int rot1[4]={17,29,16,24};
#define TF_APPLY(rr) {for(int r=0;r<4;r++){x0+=x1; x1=(x1<<rr[r])|(x1>>(32-rr[r])); x1^=x0;}}
  TF_APPLY(rot0); x0+=ks1; x1+=ks2+1u;
  TF_APPLY(rot1); x0+=ks2; x1+=ks0+2u;
  TF_APPLY(rot0); x0+=ks0; x1+=ks1+3u;
  TF_APPLY(rot1); x0+=ks1; x1+=ks2+4u;
  TF_APPLY(rot0); x0+=ks2; x1+=ks0+5u;
#undef TF_APPLY
}

__device__ __forceinline__ float jax_uniform128(int i){
  unsigned x0=0u, x1=(unsigned)i;
  threefry2x32(0u,42u,x0,x1);
  unsigned bits = x0 ^ x1;
  unsigned fb=(bits>>9)|0x3f800000u;
  float f=__uint_as_float(fb)-1.0f;
  float u=f*(1.0f-1e-10f)+1e-10f;
  return fmaxf(1e-10f,u);
}

// ---------------- rms over task_f per b ----------------
__global__ __launch_bounds__(256) void k_rms(const float* __restrict__ task_f, float* __restrict__ rms){
  int b=blockIdx.x;
  const float* x=task_f+b*LLEN;
  float s=0;
  for(int i=threadIdx.x;i<LLEN;i+=256){ float v=x[i]; s+=v*v; }
  __shared__ float red[256];
  red[threadIdx.x]=s; __syncthreads();
  for(int off=128;off;off>>=1){ if(threadIdx.x<off) red[threadIdx.x]+=red[threadIdx.x+off]; __syncthreads(); }
  if(threadIdx.x==0) rms[b]=sqrtf(red[0]/(float)LLEN);
}

// ---------------- branch A conv1 stats (4 ch) ----------------
__global__ __launch_bounds__(256) void k_statsA(const float* __restrict__ task_f, const float* __restrict__ w1,
                         float* __restrict__ totA, float* __restrict__ a0A, float* __restrict__ aLA){
  int b=blockIdx.x, seg=blockIdx.y;
  const float* x=task_f+b*LLEN;
  float tot[4]={0,0,0,0};
  int l0=seg*2048;
  for(int l=l0+threadIdx.x;l<l0+2048;l+=256){
    float xm=(l>0)?x[l-1]:0.f;
    float xc=x[l];
    float xp=(l<LLEN-1)?x[l+1]:0.f;
#pragma unroll
    for(int c=0;c<4;c++){
      float a=leaky(w1[c*3+0]*xm + w1[c*3+1]*xc + w1[c*3+2]*xp);
      tot[c]+=a;
      if(l==0) a0A[b*4+c]=a;
      if(l==LLEN-1) aLA[b*4+c]=a;
    }
  }
#pragma unroll
  for(int c=0;c<4;c++) tot[c]=wave_sum64(tot[c]);
  __shared__ float red[4][4];
  int wave=threadIdx.x>>6, lane=threadIdx.x&63;
  if(lane==0){
#pragma unroll
    for(int c=0;c<4;c++) red[wave][c]=tot[c];
  }
  __syncthreads();
  if(threadIdx.x<4){
    float s=red[0][threadIdx.x]+red[1][threadIdx.x]+red[2][threadIdx.x]+red[3][threadIdx.x];
    atomicAdd(&totA[b*4+threadIdx.x], s);
  }
}

// ---------------- branch B conv1 stats (64 ch, rms-normalized input) ----------------
__global__ __launch_bounds__(256) void k_statsB(const float* __restrict__ task_f, const float* __restrict__ rms,
                         const float* __restrict__ w1,
                         float* __restrict__ totB, float* __restrict__ a0B, float* __restrict__ aLB){
  int b=blockIdx.x, seg=blockIdx.y;
  float sc=1.f/(rms[b]+1e-8f);
  const float* x=task_f+b*LLEN;
  float tot[64];
#pragma unroll
  for(int c=0;c<64;c++) tot[c]=0.f;
  int l0=seg*2048;
  for(int l=l0+threadIdx.x;l<l0+2048;l+=256){
    float xm=((l>0)?x[l-1]:0.f)*sc;
    float xc=x[l]*sc;
    float xp=((l<LLEN-1)?x[l+1]:0.f)*sc;
#pragma unroll
    for(int c=0;c<64;c++){
      float a=leaky(w1[c*3+0]*xm + w1[c*3+1]*xc + w1[c*3+2]*xp);
      tot[c]+=a;
      if(l==0) a0B[b*64+c]=a;
      if(l==LLEN-1) aLB[b*64+c]=a;
    }
  }
#pragma unroll
  for(int c=0;c<64;c++){
    float v=tot[c];
    for(int off=32;off;off>>=1) v+=__shfl_down(v,off);
    tot[c]=v;
  }
  __shared__ float red[4][64];
  int wave=threadIdx.x>>6, lane=threadIdx.x&63;
  if(lane==0){
#pragma unroll
    for(int c=0;c<64;c++) red[wave][c]=tot[c];
  }
  __syncthreads();
  if(threadIdx.x<64){
    float s=red[0][threadIdx.x]+red[1][threadIdx.x]+red[2][threadIdx.x]+red[3][threadIdx.x];
    atomicAdd(&totB[b*64+threadIdx.x], s);
  }
}

// ---------------- iA conv + bn + leaky + spatial mean -> i1 (B,8), widened w/ atomics ----------------
__global__ __launch_bounds__(256) void k_i1(const float* __restrict__ img, const float* __restrict__ w,
                     const float* __restrict__ bn, float* __restrict__ i1){
  int b=blockIdx.x>>3, oc=blockIdx.x&7, seg=blockIdx.y;
  __shared__ float wk[576];
  __shared__ float red[256];
  for(int i=threadIdx.x;i<576;i+=256) wk[i]=w[oc*576+i];
  __syncthreads();
  float g=bn[oc], be=bn[8+oc], m=bn[16+oc], v=bn[24+oc];
  float scale=g/sqrtf(v+1e-5f);
  const float* ib=img+b*NC*HW;
  float s=0;
  for(int p=seg*768+threadIdx.x;p<seg*768+768;p+=256){
    int h=p/48, wj=p%48;
    float acc=0;
    for(int c=0;c<64;c++){
      const float* ic=ib+c*HW;
#pragma unroll
      for(int i=0;i<3;i++){
        int hh=h+i-1; if((unsigned)hh>=48u) continue;
#pragma unroll
        for(int j=0;j<3;j++){
          int ww=wj+j-1; if((unsigned)ww>=48u) continue;
          acc+=wk[c*9+i*3+j]*ic[hh*48+ww];
        }
      }
    }
    s+=leaky((acc-m)*scale+be);
  }
  red[threadIdx.x]=s; __syncthreads();
  for(int off=128;off;off>>=1){ if(threadIdx.x<off) red[threadIdx.x]+=red[threadIdx.x+off]; __syncthreads(); }
  if(threadIdx.x==0) atomicAdd(&i1[b*8+oc], red[0]*(1.f/2304.f));
}

// ---------------- bv_ic1 conv + bn + leaky -> ie1 (B,64,48,48) ----------------
__global__ __launch_bounds__(256) void k_ic1(const float* __restrict__ img, const float* __restrict__ w,
                      const float* __restrict__ bn, float* __restrict__ ie1){
  int t=blockIdx.x*256+threadIdx.x;
  int wj=t%48, h=(t/48)%48, oc=(t/HW)%64, b=t/(64*HW);
  __shared__ float wk[576];
  {
    const float* wr=w+oc*576;
    wk[threadIdx.x]=wr[threadIdx.x];
    wk[256+threadIdx.x]=wr[256+threadIdx.x];
    if(threadIdx.x<64) wk[512+threadIdx.x]=wr[512+threadIdx.x];
  }
  __syncthreads();
  const float* ib=img+b*NC*HW;
  float acc=0;
  for(int c=0;c<64;c++){
    const float* ic=ib+c*HW;
#pragma unroll
    for(int i=0;i<3;i++){
      int hh=h+i-1; if((unsigned)hh>=48u) continue;
#pragma unroll
      for(int j=0;j<3;j++){
        int ww=wj+j-1; if((unsigned)ww>=48u) continue;
        acc+=wk[c*9+i*3+j]*ic[hh*48+ww];
      }
    }
  }
  float g=bn[oc], be=bn[64+oc], m=bn[128+oc], v=bn[192+oc];
  ie1[t]=leaky((acc-m)*(g/sqrtf(v+1e-5f))+be);
}

// ---------------- bv_ic2 conv + bn + leaky + spatial mean -> ie (B,128) ----------------
__global__ __launch_bounds__(256) void k_ic2mean(const float* __restrict__ ie1, const float* __restrict__ w,
                          const float* __restrict__ bn, float* __restrict__ ie){
  int b=blockIdx.x>>7, oc=blockIdx.x&127;
  __shared__ float wk[576];
  __shared__ float red[256];
  for(int i=threadIdx.x;i<576;i+=256) wk[i]=w[oc*576+i];
  __syncthreads();
  float g=bn[oc], be=bn[128+oc], m=bn[256+oc], v=bn[384+oc];
  float scale=g/sqrtf(v+1e-5f);
  const float* ib=ie1+b*64*HW;
  float s=0;
  for(int p=threadIdx.x;p<HW;p+=256){
    int h=p/48, wj=p%48;
    float acc=0;
    for(int c=0;c<64;c++){
      const float* ic=ib+c*HW;
#pragma unroll
      for(int i=0;i<3;i++){
        int hh=h+i-1; if((unsigned)hh>=48u) continue;
#pragma unroll
        for(int j=0;j<3;j++){
          int ww=wj+j-1; if((unsigned)ww>=48u) continue;
          acc+=wk[c*9+i*3+j]*ic[hh*48+ww];
        }
      }
    }
    s+=leaky((acc-m)*scale+be);
  }
  red[threadIdx.x]=s; __syncthreads();
  for(int off=128;off;off>>=1){ if(threadIdx.x<off) red[threadIdx.x]+=red[threadIdx.x+off]; __syncthreads(); }
  if(threadIdx.x==0) ie[b*128+oc]=red[0]*(1.f/2304.f);
}

// ---------------- t1 (B,8) and te (B,128) from conv1 stats ----------------
__global__ __launch_bounds__(256) void k_te(const float* __restrict__ totA, const float* __restrict__ a0A,
                     const float* __restrict__ aLA, const float* __restrict__ totB,
                     const float* __restrict__ a0B, const float* __restrict__ aLB,
                     const float* __restrict__ tA_w2, const float* __restrict__ bv_t2,
                     float* __restrict__ t1o, float* __restrict__ teo){
  int b=blockIdx.x, tid=threadIdx.x;
  const float invL=1.0f/16384.0f;
  __shared__ float sT[64], s0[64], sL[64];
  if(tid<64){ sT[tid]=totB[b*64+tid]; s0[tid]=a0B[b*64+tid]; sL[tid]=aLB[b*64+tid]; }
  __syncthreads();
  if(tid<128){
    int c2=tid;
    const float* wr=bv_t2+c2*192;
    float s=0;
    for(int c1=0;c1<64;c1+=8){
      float4 q[6];
      const float4* r4=(const float4*)(wr+c1*3);
#pragma unroll
      for(int u=0;u<6;u++) q[u]=r4[u];
      const float* qq=(const float*)q;
#pragma unroll
      for(int u=0;u<8;u++){
        int c=c1+u;
        float T=sT[c], A0=s0[c], AL=sL[c];
        s += qq[u*3+0]*(T-AL) + qq[u*3+1]*T + qq[u*3+2]*(T-A0);
      }
    }
    teo[b*128+c2]=s*invL;
  } else if(tid<136){
    int c2=tid-128;
    float s=0;
    for(int c1=0;c1<4;c1++){
      float T=totA[b*4+c1], A0=a0A[b*4+c1], AL=aLA[b*4+c1];
      const float* w=&tA_w2[(c2*4+c1)*3];
      s += w[0]*(T-AL) + w[1]*T + w[2]*(T-A0);
    }
    t1o[b*8+c2]=s*invL;
  }
}

// ---------------- attention MLP -> logits+gumbel -> idx/first/rank ----------------
__global__ __launch_bounds__(256) void k_att(const float* __restrict__ t1, const float* __restrict__ i1,
                      const float* __restrict__ at_w1, const float* __restrict__ at_b1,
                      const float* __restrict__ at_ln_g, const float* __restrict__ at_ln_b,
                      const float* __restrict__ at_w2, const float* __restrict__ at_b2,
                      const float* __restrict__ protos,
                      int* __restrict__ idxo, int* __restrict__ firsto, int* __restrict__ ranko){
  __shared__ float f1[64], h[256], tif[512], tifn[512], tden[32], pden[4], pn[64], z[128];
  __shared__ int sidx[32];
  int tid=threadIdx.x;
  if(tid<32) f1[(tid>>3)*16+(tid&7)]=t1[tid];
  else if(tid<64){ int r=tid-32; f1[(r>>3)*16+8+(r&7)]=i1[r]; }
  __syncthreads();
  int b=tid>>6, j=tid&63;
  float s=at_b1[j];
  for(int i=0;i<16;i++) s+=f1[b*16+i]*at_w1[i*64+j];
  float mu=wave_sum64(s)*(1.f/64.f);
  float d=s-mu;
  float var=wave_sum64(d*d)*(1.f/64.f);
  float inv=1.0f/sqrtf(var+1e-5f);
  h[tid]=fmaxf(d*inv*at_ln_g[j]+at_ln_b[j],0.f);
  __syncthreads();
  for(int ii=tid;ii<512;ii+=256){
    int bb=ii>>7, n=ii&127;
    float ss=at_b2[n];
    for(int k=0;k<64;k++) ss+=h[bb*64+k]*at_w2[k*128+n];
    tif[ii]=ss;
  }
  __syncthreads();
  if(tid<32){
    int bb=tid>>3, f=tid&7;
    float ss=0; for(int e=0;e<16;e++){float v=tif[bb*128+e*8+f]; ss+=v*v;}
    tden[tid]=fmaxf(sqrtf(ss),1e-8f);
  } else if(tid<36){
    int t=tid-32;
    float ss=0; for(int e=0;e<16;e++){float v=protos[t*16+e]; ss+=v*v;}
    pden[t]=fmaxf(sqrtf(ss),1e-8f);
  }
  __syncthreads();
  for(int ii=tid;ii<512;ii+=256){
    int bb=ii>>7, n=ii&127, f=n&7;
    tifn[ii]=tif[ii]/tden[bb*8+f];
  }
  if(tid<64) pn[tid]=protos[tid]/pden[tid>>4];
  __syncthreads();
  if(tid<128){
    int bb=tid>>5, f=(tid>>2)&7, t=tid&3;
    float ss=0;
    for(int e=0;e<16;e++) ss+=pn[t*16+e]*tifn[bb*128+e*8+f];
    float u=jax_uniform128(tid);
    float g=-logf(-logf(u));
    z[tid]=ss+g;
  }
  __syncthreads();
  if(tid<32){
    float best=z[tid*4]; int bi=0;
    for(int t=1;t<4;t++){ float v=z[tid*4+t]; if(v>best){best=v;bi=t;} }
    sidx[tid]=bi;
  }
  __syncthreads();
  if(tid<16){
    int bb=tid>>2, t=tid&3;
    int fi=0;
    for(int f=7;f>=0;f--) if(sidx[bb*8+f]==t) fi=f;
    firsto[tid]=fi;
  } else if(tid<48){
    int r=tid-16, bb=r>>3, f=r&7;
    int c=0; for(int f2=0;f2<f;f2++) if(sidx[bb*8+f2]==sidx[bb*8+f]) c++;
    ranko[r]=c;
  }
  __syncthreads();
  if(tid<32) idxo[tid]=sidx[tid];
}

// ---------------- branch-B MLP -> normalized ff (B,256) ----------------
__global__ __launch_bounds__(256) void k_ff(const float* __restrict__ te, const float* __restrict__ ie,
                     const float* __restrict__ bv_w1, const float* __restrict__ bv_b1,
                     const float* __restrict__ bv_ln_g, const float* __restrict__ bv_ln_b,
                     const float* __restrict__ bv_w2, const float* __restrict__ bv_b2,
                     float* __restrict__ ffn){
  __shared__ float f[1024], hh[256], ffs[1024], finv[4];
  int tid=threadIdx.x;
  for(int ii=tid;ii<512;ii+=256){
    int bb=ii>>7, k=ii&127;
    f[bb*256+k]=te[ii];
    f[bb*256+128+k]=ie[ii];
  }
  __syncthreads();
  int b=tid>>6, j=tid&63;
  float s=bv_b1[j];
  for(int k=0;k<256;k++) s+=f[b*256+k]*bv_w1[k*64+j];
  float mu=wave_sum64(s)*(1.f/64.f);
  float d=s-mu;
  float var=wave_sum64(d*d)*(1.f/64.f);
  float inv=1.0f/sqrtf(var+1e-5f);
  hh[tid]=fmaxf(d*inv*bv_ln_g[j]+bv_ln_b[j],0.f);
  __syncthreads();
  for(int ii=tid;ii<1024;ii+=256){
    int bb=ii>>8, n=ii&255;
    float ss=bv_b2[n];
    for(int k=0;k<64;k++) ss+=hh[bb*64+k]*bv_w2[k*256+n];
    ffs[ii]=ss;
  }
  __syncthreads();
  {
    int lane=tid&63;
    float sq=0;
#pragma unroll
    for(int u=0;u<4;u++){ float v=ffs[b*256+u*64+lane]; sq+=v*v; }
    sq=wave_sum64(sq);
    if(lane==0) finv[b]=1.0f/fmaxf(sqrtf(sq),1e-12f);
  }
  __syncthreads();
  for(int ii=tid;ii<1024;ii+=256) ffn[ii]=ffs[ii]*finv[ii>>8];
}

// ---------------- scores + argsort + selection -> rowidx (32 ints into bank) ----------------
__global__ __launch_bounds__(256) void k_sel(const float* __restrict__ ffn, const float* __restrict__ bank,
                      const int* __restrict__ idx, const int* __restrict__ first,
                      const int* __restrict__ rank, int* __restrict__ rowidx){
  __shared__ float fl[1024], scores[256];
  __shared__ int order[256], sidx[32], sfirst[16], srank[32];
  int tid=threadIdx.x;
  for(int ii=tid;ii<1024;ii+=256) fl[ii]=ffn[ii];
  if(tid<32){ sidx[tid]=idx[tid]; srank[tid]=rank[tid]; }
  else if(tid<48) sfirst[tid-32]=first[tid-32];
  __syncthreads();
  {
    int b=tid>>6, t=(tid>>4)&3, v=tid&15;
    int tt=sidx[b*8+sfirst[b*4+t]];
    const float4* row=(const float4*)(bank+(tt*16+v)*256);
    float s=0, nb=0;
    for(int d4=0;d4<64;d4++){
      float4 r=row[d4];
      const float* fb=&fl[b*256+d4*4];
      s +=fb[0]*r.x+fb[1]*r.y+fb[2]*r.z+fb[3]*r.w;
      nb+=r.x*r.x+r.y*r.y+r.z*r.z+r.w*r.w;
    }
    scores[tid]=s/fmaxf(sqrtf(nb),1e-12f);
  }
  __syncthreads();
  if(tid<16){
    const float* sc=&scores[tid*16];
    unsigned used=0;
    for(int pk=0;pk<16;pk++){
      int best=-1; float bv=-1e30f;
      for(int v2=0;v2<16;v2++){
        if(used&(1u<<v2)) continue;
        float vv=sc[v2];
        if(best<0||vv>bv){bv=vv;best=v2;}
      }
      used|=1u<<best;
      order[tid*16+pk]=best;
    }
  }
  __syncthreads();
  if(tid<32){
    int b=tid>>3;
    int t=sidx[tid];
    int v=order[(b*4+t)*16+srank[tid]];
    rowidx[tid]=t*16+v;
  }
}

// ---------------- m1/m3 hidden (32 blocks x 64 threads) ----------------
__global__ __launch_bounds__(64) void k_hid(const float* __restrict__ bank, const int* __restrict__ rowidx,
                     const float* __restrict__ m1_w1, const float* __restrict__ m1_b1,
                     const float* __restrict__ m1_g, const float* __restrict__ m1_b,
                     const float* __restrict__ m3_w1, const float* __restrict__ m3_b1,
                     const float* __restrict__ m3_g, const float* __restrict__ m3_b,
                     float* __restrict__ hid1, float* __restrict__ hid3){
  int bf=blockIdx.x, j=threadIdx.x;
  __shared__ float br[256];
  int ri=rowidx[bf];
  const float* row=bank+ri*256;
  for(int i=j;i<256;i+=64) br[i]=row[i];
  __syncthreads();
  {
    float s=m1_b1[j];
    for(int d=0;d<256;d++) s+=br[d]*m1_w1[d*64+j];
    float mu=wave_sum64(s)*(1.f/64.f);
    float dd=s-mu;
    float var=wave_sum64(dd*dd)*(1.f/64.f);
    float inv=1.0f/sqrtf(var+1e-5f);
    hid1[bf*64+j]=fmaxf(dd*inv*m1_g[j]+m1_b[j],0.f);
  }
  {
    float s=m3_b1[j];
    for(int d=0;d<256;d++) s+=br[d]*m3_w1[d*64+j];
    float mu=wave_sum64(s)*(1.f/64.f);
    float dd=s-mu;
    float var=wave_sum64(dd*dd)*(1.f/64.f);
    float inv=1.0f/sqrtf(var+1e-5f);
    hid3[bf*64+j]=fmaxf(dd*inv*m3_g[j]+m3_b[j],0.f);
  }
}

// ---------------- w1 head: (32,64) @ (64,4096) + b ----------------
__global__ __launch_bounds__(256) void k_w1head(const float* __restrict__ hid, const float* __restrict__ w2,
                         const float* __restrict__ b2, float* __restrict__ out){
  int bf=blockIdx.x;
  int col=blockIdx.y*256+threadIdx.x;
  __shared__ float hl[64];
  if(threadIdx.x<64) hl[threadIdx.x]=hid[bf*64+threadIdx.x];
  __syncthreads();
  float s=b2[col];
  for(int k=0;k<64;k++) s+=hl[k]*w2[k*4096+col];
  out[bf*4096+col]=s;
}

// ---------------- w3 head: (32,64) @ (64,36864) + b ----------------
__global__ __launch_bounds__(256) void k_w3head(const float* __restrict__ hid, const float* __restrict__ w2,
                         const float* __restrict__ b2, float* __restrict__ out){
  int bf=blockIdx.x;
  int col=blockIdx.y*256+threadIdx.x;
  __shared__ float hl[64];
  if(threadIdx.x<64) hl[threadIdx.x]=hid[bf*64+threadIdx.x];
  __syncthreads();
  float s=b2[col];
  for(int k=0;k<64;k++) s+=hl[k]*w2[(size_t)k*36864+col];
  out[(size_t)bf*36864+col]=s;
}

// ---------------- dynamic conv, one (b,f,o) slab per block, LDS weights, atomic f-mean ----------------
__global__ __launch_bounds__(256) void k_dyn2(const float* __restrict__ img, const float* __restrict__ w1o,
                       const float* __restrict__ w3o, const int* __restrict__ idx,
                       const float* __restrict__ bn, float* __restrict__ x){
  int blk=blockIdx.x;
  int bfo=blk/9, sub=blk-bfo*9;
  int o=bfo&63, f=(bfo>>6)&7, b=bfo>>9;
  int tt=idx[b*8+f];
  __shared__ float wl[576];
  if(tt==0){
    if(threadIdx.x<64) wl[threadIdx.x]=w1o[((b*8+f)*64+o)*64+threadIdx.x];
  } else {
    const float* wr=w3o+(size_t)((b*8+f)*64+o)*576;
    wl[threadIdx.x]=wr[threadIdx.x];
    wl[256+threadIdx.x]=wr[256+threadIdx.x];
    if(threadIdx.x<64) wl[512+threadIdx.x]=wr[512+threadIdx.x];
  }
  __syncthreads();
  int p=sub*256+threadIdx.x;
  int h=p/48, wj=p-h*48;
  const float* ib=img+b*NC*HW;
  float acc=0;
  if(tt==0){
    const float* ip=ib+p;
    for(int c=0;c<64;c++) acc+=wl[c]*ip[c*HW];
  } else {
    int dd=tt;
    for(int c=0;c<64;c++){
      const float* ic=ib+c*HW;
      const float* wc=&wl[c*9];
#pragma unroll
      for(int i=0;i<3;i++){
        int hh=h+dd*(i-1); if((unsigned)hh>=48u) continue;
#pragma unroll
        for(int jj=0;jj<3;jj++){
          int ww=wj+dd*(jj-1); if((unsigned)ww>=48u) continue;
          acc+=wc[i*3+jj]*ic[hh*48+ww];
        }
      }
    }
  }
  float g=bn[o], be=bn[64+o], m=bn[128+o], v=bn[192+o];
  float r=leaky((acc-m)*(g/sqrtf(v+1e-5f))+be)*0.125f;
  atomicAdd(&x[(b*64+o)*HW+p], r);
}

// ---------------- final: zc 1x1 conv + bias + residual ----------------
__global__ __launch_bounds__(256) void k_final(const float* __restrict__ img, const float* __restrict__ x,
                        const float* __restrict__ zw, const float* __restrict__ zb,
                        float* __restrict__ out){
  int t=blockIdx.x*256+threadIdx.x;
  int o=(t/HW)%64, b=t/(64*HW);
  int p2=t%HW;
  const float* xb=x+b*64*HW+p2;
  const float* wr=zw+o*64;
  float s=zb[o];
  for(int c=0;c<64;c++) s+=wr[c]*xb[c*HW];
  out[t]=s+img[t];
}

extern "C" void kernel_launch(void* const* d_in, const int* in_sizes, int n_in,
                              void* d_out, int out_size, void* d_ws, size_t ws_size,
                              hipStream_t stream){
  const float* bank   =(const float*)d_in[0];
  const float* task_f =(const float*)d_in[1];
  const float* img_f  =(const float*)d_in[2];
  const float* protos =(const float*)d_in[3];
  const float* tA_w1  =(const float*)d_in[4];
  const float* tA_w2  =(const float*)d_in[5];
  const float* iA_w   =(const float*)d_in[6];
  const float* iA_bn  =(const float*)d_in[7];
  const float* at_w1  =(const float*)d_in[8];
  const float* at_b1  =(const float*)d_in[9];
  const float* at_ln_g=(const float*)d_in[10];
  const float* at_ln_b=(const float*)d_in[11];
  const float* at_w2  =(const float*)d_in[12];
  const float* at_b2  =(const float*)d_in[13];
  const float* bv_t1  =(const float*)d_in[14];
  const float* bv_t2  =(const float*)d_in[15];
  const float* bv_ic1 =(const float*)d_in[16];
  const float* bv_bn1 =(const float*)d_in[17];
  const float* bv_ic2 =(const float*)d_in[18];
  const float* bv_bn2 =(const float*)d_in[19];
  const float* bv_w1  =(const float*)d_in[20];
  const float* bv_b1  =(const float*)d_in[21];
  const float* bv_ln_g=(const float*)d_in[22];
  const float* bv_ln_b=(const float*)d_in[23];
  const float* bv_w2  =(const float*)d_in[24];
  const float* bv_b2  =(const float*)d_in[25];
  const float* m1_w1  =(const float*)d_in[26];
  const float* m1_b1  =(const float*)d_in[27];
  const float* m1_ln_g=(const float*)d_in[28];
  const float* m1_ln_b=(const float*)d_in[29];
  const float* m1_w2  =(const float*)d_in[30];
  const float* m1_b2  =(const float*)d_in[31];
  const float* m3_w1  =(const float*)d_in[32];
  const float* m3_b1  =(const float*)d_in[33];
  const float* m3_ln_g=(const float*)d_in[34];
  const float* m3_ln_b=(const float*)d_in[35];
  const float* m3_w2  =(const float*)d_in[36];
  const float* m3_b2  =(const float*)d_in[37];
  const float* blr_bn =(const float*)d_in[38];
  const float* zc_w   =(const float*)d_in[39];
  const float* zc_b   =(const float*)d_in[40];

  float* ws=(float*)d_ws;
  float* totA=ws+0;       float* a0A=ws+16;      float* aLA=ws+32;
  float* totB=ws+48;      float* a0B=ws+304;     float* aLB=ws+560;
  float* rms =ws+816;     float* i1 =ws+820;     float* ie =ws+852;
  float* t1  =ws+1364;    float* te =ws+1396;    float* ffn=ws+1908;
  int*   idxp =(int*)(ws+2932);
  int*   firstp=(int*)(ws+2964);
  int*   rankp =(int*)(ws+2980);
  int*   rowidx=(int*)(ws+3012);
  float* hid1=ws+3044;    float* hid3=ws+5092;
  float* w1o =ws+7140;    float* w3o =ws+138212;
  float* ie1 =ws+1317860; float* x   =ws+1907684;
  // total: 2,497,508 floats (~10 MB)

  hipMemsetAsync(ws, 0, 852*sizeof(float), stream);        // stats accumulators + i1
  hipMemsetAsync(x, 0, 589824*sizeof(float), stream);      // f-mean accumulator

  k_rms<<<NB,256,0,stream>>>(task_f, rms);
  k_statsA<<<dim3(NB,8),256,0,stream>>>(task_f, tA_w1, totA, a0A, aLA);
  k_statsB<<<dim3(NB,8),256,0,stream>>>(task_f, rms, bv_t1, totB, a0B, aLB);
  k_i1<<<dim3(NB*8,3),256,0,stream>>>(img_f, iA_w, iA_bn, i1);
  k_ic1<<<2304,256,0,stream>>>(img_f, bv_ic1, bv_bn1, ie1);
  k_ic2mean<<<NB*128,256,0,stream>>>(ie1, bv_ic2, bv_bn2, ie);
  k_te<<<NB,256,0,stream>>>(totA,a0A,aLA,totB,a0B,aLB, tA_w2, bv_t2, t1, te);
  k_att<<<1,256,0,stream>>>(t1, i1, at_w1, at_b1, at_ln_g, at_ln_b, at_w2, at_b2, protos,
                            idxp, firstp, rankp);
  k_ff<<<1,256,0,stream>>>(te, ie, bv_w1, bv_b1, bv_ln_g, bv_ln_b, bv_w2, bv_b2, ffn);
  k_sel<<<1,256,0,stream>>>(ffn, bank, idxp, firstp, rankp, rowidx);
  k_hid<<<32,64,0,stream>>>(bank, rowidx, m1_w1, m1_b1, m1_ln_g, m1_ln_b,
                            m3_w1, m3_b1, m3_ln_g, m3_ln_b, hid1, hid3);
  k_w1head<<<dim3(32,16),256,0,stream>>>(hid1, m1_w2, m1_b2, w1o);
  k_w3head<<<dim3(32,144),256,0,stream>>>(hid3, m3_w2, m3_b2, w3o);
  k_dyn2<<<18432,256,0,stream>>>(img_f, w1o, w3o, idxp, blr_bn, x);
  k_final<<<2304,256,0,stream>>>(img_f, x, zc_w, zc_b, (float*)d_out);

  (void)in_sizes; (void)n_in; (void)out_size; (void)ws_size;
}

// Round 3
// 798.923 us; speedup vs baseline: 3.6233x; 2.8300x over previous
//
#include <hip/hip_runtime.h>
#include <math.h>

#define LEAKC 0.2f

#define NB 4
#define NC 64
#define NH 48
#define NW 48
#define LLEN 16384
#define HW 2304

typedef __attribute__((ext_vector_type(8))) short short8;
typedef __attribute__((ext_vector_type(4))) float floatx4;

__device__ __forceinline__ float leaky(float x){ return x > 0.f ? x : LEAKC*x; }

__device__ __forceinline__ float wave_sum64(float v){
  for(int off=32;off;off>>=1) v += __shfl_xor(v,off);
  return v;
}

__device__ __forceinline__ unsigned short f2bf(float x){
  unsigned u=__float_as_uint(x);
  unsigned r=u+0x7FFFu+((u>>16)&1u);
  return (unsigned short)(r>>16);
}

__device__ __forceinline__ void threefry2x32(unsigned k0, unsigned k1, unsigned& x0, unsigned& x1){
  unsigned ks0=k0, ks1=k1, ks2=k0^k1^0x1BD11BDAu;
  x0+=ks0; x1+=ks1;
  const int rot0[4]={13,15,26,6};
  const int rot1[4]={17,29,16,24};
#define TF_APPLY(rr) {for(int r=0;r<4;r++){x0+=x1; x1=(x1<<rr[r])|(x1>>(32-rr[r])); x1^=x0;}}
  TF_APPLY(rot0); x0+=ks1; x1+=ks2+1u;
  TF_APPLY(rot1); x0+=ks2; x1+=ks0+2u;
  TF_APPLY(rot0); x0+=ks0; x1+=ks1+3u;
  TF_APPLY(rot1); x0+=ks1; x1+=ks2+4u;
  TF_APPLY(rot0); x0+=ks2; x1+=ks0+5u;
#undef TF_APPLY
}

__device__ __forceinline__ float jax_uniform128(int i){
  unsigned x0=0u, x1=(unsigned)i;
  threefry2x32(0u,42u,x0,x1);
  unsigned bits = x0 ^ x1;
  unsigned fb=(bits>>9)|0x3f800000u;
  float f=__uint_as_float(fb)-1.0f;
  float u=f*(1.0f-1e-10f)+1e-10f;
  return fmaxf(1e-10f,u);
}

// ---------------- rms over task_f per b ----------------
__global__ __launch_bounds__(256) void k_rms(const float* __restrict__ task_f, float* __restrict__ rms){
  int b=blockIdx.x;
  const float* x=task_f+b*LLEN;
  float s=0;
  for(int i=threadIdx.x;i<LLEN;i+=256){ float v=x[i]; s+=v*v; }
  __shared__ float red[256];
  red[threadIdx.x]=s; __syncthreads();
  for(int off=128;off;off>>=1){ if(threadIdx.x<off) red[threadIdx.x]+=red[threadIdx.x+off]; __syncthreads(); }
  if(threadIdx.x==0) rms[b]=sqrtf(red[0]/(float)LLEN);
}

// ---------------- branch A conv1 stats (4 ch) ----------------
__global__ __launch_bounds__(256) void k_statsA(const float* __restrict__ task_f, const float* __restrict__ w1,
                         float* __restrict__ totA, float* __restrict__ a0A, float* __restrict__ aLA){
  int b=blockIdx.x, seg=blockIdx.y;
  const float* x=task_f+b*LLEN;
  float tot[4]={0,0,0,0};
  int l0=seg*2048;
  for(int l=l0+threadIdx.x;l<l0+2048;l+=256){
    float xm=(l>0)?x[l-1]:0.f;
    float xc=x[l];
    float xp=(l<LLEN-1)?x[l+1]:0.f;
#pragma unroll
    for(int c=0;c<4;c++){
      float a=leaky(w1[c*3+0]*xm + w1[c*3+1]*xc + w1[c*3+2]*xp);
      tot[c]+=a;
      if(l==0) a0A[b*4+c]=a;
      if(l==LLEN-1) aLA[b*4+c]=a;
    }
  }
#pragma unroll
  for(int c=0;c<4;c++) tot[c]=wave_sum64(tot[c]);
  __shared__ float red[4][4];
  int wave=threadIdx.x>>6, lane=threadIdx.x&63;
  if(lane==0){
#pragma unroll
    for(int c=0;c<4;c++) red[wave][c]=tot[c];
  }
  __syncthreads();
  if(threadIdx.x<4){
    float s=red[0][threadIdx.x]+red[1][threadIdx.x]+red[2][threadIdx.x]+red[3][threadIdx.x];
    atomicAdd(&totA[b*4+threadIdx.x], s);
  }
}

// ---------------- branch B conv1 stats (64 ch) ----------------
__global__ __launch_bounds__(256) void k_statsB(const float* __restrict__ task_f, const float* __restrict__ rms,
                         const float* __restrict__ w1,
                         float* __restrict__ totB, float* __restrict__ a0B, float* __restrict__ aLB){
  int b=blockIdx.x, seg=blockIdx.y;
  float sc=1.f/(rms[b]+1e-8f);
  const float* x=task_f+b*LLEN;
  float tot[64];
#pragma unroll
  for(int c=0;c<64;c++) tot[c]=0.f;
  int l0=seg*512;
  for(int l=l0+threadIdx.x;l<l0+512;l+=256){
    float xm=((l>0)?x[l-1]:0.f)*sc;
    float xc=x[l]*sc;
    float xp=((l<LLEN-1)?x[l+1]:0.f)*sc;
#pragma unroll
    for(int c=0;c<64;c++){
      float a=leaky(w1[c*3+0]*xm + w1[c*3+1]*xc + w1[c*3+2]*xp);
      tot[c]+=a;
      if(l==0) a0B[b*64+c]=a;
      if(l==LLEN-1) aLB[b*64+c]=a;
    }
  }
#pragma unroll
  for(int c=0;c<64;c++){
    float v=tot[c];
    for(int off=32;off;off>>=1) v+=__shfl_down(v,off);
    tot[c]=v;
  }
  __shared__ float red[4][64];
  int wave=threadIdx.x>>6, lane=threadIdx.x&63;
  if(lane==0){
#pragma unroll
    for(int c=0;c<64;c++) red[wave][c]=tot[c];
  }
  __syncthreads();
  if(threadIdx.x<64){
    float s=red[0][threadIdx.x]+red[1][threadIdx.x]+red[2][threadIdx.x]+red[3][threadIdx.x];
    atomicAdd(&totB[b*64+threadIdx.x], s);
  }
}

// ---------------- iA conv + bn + leaky + spatial mean -> i1 (B,8) ----------------
__global__ __launch_bounds__(256) void k_i1(const float* __restrict__ img, const float* __restrict__ w,
                     const float* __restrict__ bn, float* __restrict__ i1){
  int b=blockIdx.x>>3, oc=blockIdx.x&7, seg=blockIdx.y;
  __shared__ float wk[576];
  __shared__ float red[256];
  for(int i=threadIdx.x;i<576;i+=256) wk[i]=w[oc*576+i];
  __syncthreads();
  float g=bn[oc], be=bn[8+oc], m=bn[16+oc], v=bn[24+oc];
  float scale=g/sqrtf(v+1e-5f);
  const float* ib=img+b*NC*HW;
  int p=seg*256+threadIdx.x;
  int h=p/48, wj=p%48;
  float acc=0;
  for(int c=0;c<64;c++){
    const float* ic=ib+c*HW;
#pragma unroll
    for(int i=0;i<3;i++){
      int hh=h+i-1; if((unsigned)hh>=48u) continue;
#pragma unroll
      for(int j=0;j<3;j++){
        int ww=wj+j-1; if((unsigned)ww>=48u) continue;
        acc+=wk[c*9+i*3+j]*ic[hh*48+ww];
      }
    }
  }
  float s=leaky((acc-m)*scale+be);
  red[threadIdx.x]=s; __syncthreads();
  for(int off=128;off;off>>=1){ if(threadIdx.x<off) red[threadIdx.x]+=red[threadIdx.x+off]; __syncthreads(); }
  if(threadIdx.x==0) atomicAdd(&i1[b*8+oc], red[0]*(1.f/2304.f));
}

// ---------------- bv_ic1 conv + bn + leaky -> ie1 (B,64,48,48) ----------------
__global__ __launch_bounds__(256) void k_ic1(const float* __restrict__ img, const float* __restrict__ w,
                      const float* __restrict__ bn, float* __restrict__ ie1){
  int t=blockIdx.x*256+threadIdx.x;
  int wj=t%48, h=(t/48)%48, oc=(t/HW)%64, b=t/(64*HW);
  __shared__ float wk[576];
  {
    const float* wr=w+oc*576;
    wk[threadIdx.x]=wr[threadIdx.x];
    wk[256+threadIdx.x]=wr[256+threadIdx.x];
    if(threadIdx.x<64) wk[512+threadIdx.x]=wr[512+threadIdx.x];
  }
  __syncthreads();
  const float* ib=img+b*NC*HW;
  float acc=0;
  for(int c=0;c<64;c++){
    const float* ic=ib+c*HW;
#pragma unroll
    for(int i=0;i<3;i++){
      int hh=h+i-1; if((unsigned)hh>=48u) continue;
#pragma unroll
      for(int j=0;j<3;j++){
        int ww=wj+j-1; if((unsigned)ww>=48u) continue;
        acc+=wk[c*9+i*3+j]*ic[hh*48+ww];
      }
    }
  }
  float g=bn[oc], be=bn[64+oc], m=bn[128+oc], v=bn[192+oc];
  ie1[t]=leaky((acc-m)*(g/sqrtf(v+1e-5f))+be);
}

// ---------------- bv_ic2 conv + bn + leaky + spatial mean -> ie (B,128) ----------------
__global__ __launch_bounds__(256) void k_ic2mean(const float* __restrict__ ie1, const float* __restrict__ w,
                          const float* __restrict__ bn, float* __restrict__ ie){
  int b=blockIdx.x>>7, oc=blockIdx.x&127, seg=blockIdx.y;
  __shared__ float wk[576];
  __shared__ float red[256];
  for(int i=threadIdx.x;i<576;i+=256) wk[i]=w[oc*576+i];
  __syncthreads();
  float g=bn[oc], be=bn[128+oc], m=bn[256+oc], v=bn[384+oc];
  float scale=g/sqrtf(v+1e-5f);
  const float* ib=ie1+b*64*HW;
  float s=0;
  for(int p=seg*768+threadIdx.x;p<seg*768+768;p+=256){
    int h=p/48, wj=p%48;
    float acc=0;
    for(int c=0;c<64;c++){
      const float* ic=ib+c*HW;
#pragma unroll
      for(int i=0;i<3;i++){
        int hh=h+i-1; if((unsigned)hh>=48u) continue;
#pragma unroll
        for(int j=0;j<3;j++){
          int ww=wj+j-1; if((unsigned)ww>=48u) continue;
          acc+=wk[c*9+i*3+j]*ic[hh*48+ww];
        }
      }
    }
    s+=leaky((acc-m)*scale+be);
  }
  red[threadIdx.x]=s; __syncthreads();
  for(int off=128;off;off>>=1){ if(threadIdx.x<off) red[threadIdx.x]+=red[threadIdx.x+off]; __syncthreads(); }
  if(threadIdx.x==0) atomicAdd(&ie[b*128+oc], red[0]*(1.f/2304.f));
}

// ---------------- img -> bf16 transposed [b][px][c] ----------------
__global__ __launch_bounds__(256) void k_imgT(const float* __restrict__ img, unsigned short* __restrict__ imgT){
  int blk=blockIdx.x;
  int b=blk/36, t=blk%36;
  int p0=t*64;
  __shared__ float tile[64][65];
  int pp=threadIdx.x&63, c4=threadIdx.x>>6;
  for(int r=0;r<16;r++){
    int c=c4*16+r;
    tile[c][pp]=img[(b*64+c)*HW + p0+pp];
  }
  __syncthreads();
  int px=threadIdx.x>>2, cg=(threadIdx.x&3)*16;
  unsigned out[8];
#pragma unroll
  for(int q=0;q<8;q++){
    unsigned lo=f2bf(tile[cg+2*q][px]);
    unsigned hi=f2bf(tile[cg+2*q+1][px]);
    out[q]=lo|(hi<<16);
  }
  unsigned* dst=(unsigned*)(imgT + ((size_t)(b*HW+p0+px)*64 + cg));
#pragma unroll
  for(int q=0;q<8;q++) dst[q]=out[q];
}

// ---------------- t1 (B,8) and te (B,128) from conv1 stats ----------------
__global__ __launch_bounds__(256) void k_te(const float* __restrict__ totA, const float* __restrict__ a0A,
                     const float* __restrict__ aLA, const float* __restrict__ totB,
                     const float* __restrict__ a0B, const float* __restrict__ aLB,
                     const float* __restrict__ tA_w2, const float* __restrict__ bv_t2,
                     float* __restrict__ t1o, float* __restrict__ teo){
  int b=blockIdx.x, tid=threadIdx.x;
  const float invL=1.0f/16384.0f;
  __shared__ float sT[64], s0[64], sL[64];
  if(tid<64){ sT[tid]=totB[b*64+tid]; s0[tid]=a0B[b*64+tid]; sL[tid]=aLB[b*64+tid]; }
  __syncthreads();
  if(tid<128){
    int c2=tid;
    const float* wr=bv_t2+c2*192;
    float s=0;
    for(int c1=0;c1<64;c1+=8){
      float4 q[6];
      const float4* r4=(const float4*)(wr+c1*3);
#pragma unroll
      for(int u=0;u<6;u++) q[u]=r4[u];
      const float* qq=(const float*)q;
#pragma unroll
      for(int u=0;u<8;u++){
        int c=c1+u;
        float T=sT[c], A0=s0[c], AL=sL[c];
        s += qq[u*3+0]*(T-AL) + qq[u*3+1]*T + qq[u*3+2]*(T-A0);
      }
    }
    teo[b*128+c2]=s*invL;
  } else if(tid<136){
    int c2=tid-128;
    float s=0;
    for(int c1=0;c1<4;c1++){
      float T=totA[b*4+c1], A0=a0A[b*4+c1], AL=aLA[b*4+c1];
      const float* w=&tA_w2[(c2*4+c1)*3];
      s += w[0]*(T-AL) + w[1]*T + w[2]*(T-A0);
    }
    t1o[b*8+c2]=s*invL;
  }
}

// ---------------- attention MLP -> idx/first/rank ----------------
__global__ __launch_bounds__(256) void k_att(const float* __restrict__ t1, const float* __restrict__ i1,
                      const float* __restrict__ at_w1, const float* __restrict__ at_b1,
                      const float* __restrict__ at_ln_g, const float* __restrict__ at_ln_b,
                      const float* __restrict__ at_w2, const float* __restrict__ at_b2,
                      const float* __restrict__ protos,
                      int* __restrict__ idxo, int* __restrict__ firsto, int* __restrict__ ranko){
  __shared__ float f1[64], h[256], tif[512], tifn[512], tden[32], pden[4], pn[64], z[128];
  __shared__ int sidx[32];
  int tid=threadIdx.x;
  if(tid<32) f1[(tid>>3)*16+(tid&7)]=t1[tid];
  else if(tid<64){ int r=tid-32; f1[(r>>3)*16+8+(r&7)]=i1[r]; }
  __syncthreads();
  int b=tid>>6, j=tid&63;
  float s=at_b1[j];
  for(int i=0;i<16;i++) s+=f1[b*16+i]*at_w1[i*64+j];
  float mu=wave_sum64(s)*(1.f/64.f);
  float d=s-mu;
  float var=wave_sum64(d*d)*(1.f/64.f);
  float inv=1.0f/sqrtf(var+1e-5f);
  h[tid]=fmaxf(d*inv*at_ln_g[j]+at_ln_b[j],0.f);
  __syncthreads();
  for(int ii=tid;ii<512;ii+=256){
    int bb=ii>>7, n=ii&127;
    float ss=at_b2[n];
    for(int k=0;k<64;k++) ss+=h[bb*64+k]*at_w2[k*128+n];
    tif[ii]=ss;
  }
  __syncthreads();
  if(tid<32){
    int bb=tid>>3, f=tid&7;
    float ss=0; for(int e=0;e<16;e++){float v=tif[bb*128+e*8+f]; ss+=v*v;}
    tden[tid]=fmaxf(sqrtf(ss),1e-8f);
  } else if(tid<36){
    int t=tid-32;
    float ss=0; for(int e=0;e<16;e++){float v=protos[t*16+e]; ss+=v*v;}
    pden[t]=fmaxf(sqrtf(ss),1e-8f);
  }
  __syncthreads();
  for(int ii=tid;ii<512;ii+=256){
    int bb=ii>>7, n=ii&127, f=n&7;
    tifn[ii]=tif[ii]/tden[bb*8+f];
  }
  if(tid<64) pn[tid]=protos[tid]/pden[tid>>4];
  __syncthreads();
  if(tid<128){
    int bb=tid>>5, f=(tid>>2)&7, t=tid&3;
    float ss=0;
    for(int e=0;e<16;e++) ss+=pn[t*16+e]*tifn[bb*128+e*8+f];
    float u=jax_uniform128(tid);
    float g=-logf(-logf(u));
    z[tid]=ss+g;
  }
  __syncthreads();
  if(tid<32){
    float best=z[tid*4]; int bi=0;
    for(int t=1;t<4;t++){ float v=z[tid*4+t]; if(v>best){best=v;bi=t;} }
    sidx[tid]=bi;
  }
  __syncthreads();
  if(tid<16){
    int bb=tid>>2, t=tid&3;
    int fi=0;
    for(int f=7;f>=0;f--) if(sidx[bb*8+f]==t) fi=f;
    firsto[tid]=fi;
  } else if(tid<48){
    int r=tid-16, bb=r>>3, f=r&7;
    int c=0; for(int f2=0;f2<f;f2++) if(sidx[bb*8+f2]==sidx[bb*8+f]) c++;
    ranko[r]=c;
  }
  __syncthreads();
  if(tid<32) idxo[tid]=sidx[tid];
}

// ---------------- branch-B MLP -> normalized ff (B,256) ----------------
__global__ __launch_bounds__(256) void k_ff(const float* __restrict__ te, const float* __restrict__ ie,
                     const float* __restrict__ bv_w1, const float* __restrict__ bv_b1,
                     const float* __restrict__ bv_ln_g, const float* __restrict__ bv_ln_b,
                     const float* __restrict__ bv_w2, const float* __restrict__ bv_b2,
                     float* __restrict__ ffn){
  __shared__ float f[1024], hh[256], ffs[1024], finv[4];
  int tid=threadIdx.x;
  for(int ii=tid;ii<512;ii+=256){
    int bb=ii>>7, k=ii&127;
    f[bb*256+k]=te[ii];
    f[bb*256+128+k]=ie[ii];
  }
  __syncthreads();
  int b=tid>>6, j=tid&63;
  float s=bv_b1[j];
  for(int k=0;k<256;k++) s+=f[b*256+k]*bv_w1[k*64+j];
  float mu=wave_sum64(s)*(1.f/64.f);
  float d=s-mu;
  float var=wave_sum64(d*d)*(1.f/64.f);
  float inv=1.0f/sqrtf(var+1e-5f);
  hh[tid]=fmaxf(d*inv*bv_ln_g[j]+bv_ln_b[j],0.f);
  __syncthreads();
  for(int ii=tid;ii<1024;ii+=256){
    int bb=ii>>8, n=ii&255;
    float ss=bv_b2[n];
    for(int k=0;k<64;k++) ss+=hh[bb*64+k]*bv_w2[k*256+n];
    ffs[ii]=ss;
  }
  __syncthreads();
  {
    int lane=tid&63;
    float sq=0;
#pragma unroll
    for(int u=0;u<4;u++){ float v=ffs[b*256+u*64+lane]; sq+=v*v; }
    sq=wave_sum64(sq);
    if(lane==0) finv[b]=1.0f/fmaxf(sqrtf(sq),1e-12f);
  }
  __syncthreads();
  for(int ii=tid;ii<1024;ii+=256) ffn[ii]=ffs[ii]*finv[ii>>8];
}

// ---------------- scores + argsort + selection -> rowidx ----------------
__global__ __launch_bounds__(256) void k_sel(const float* __restrict__ ffn, const float* __restrict__ bank,
                      const int* __restrict__ idx, const int* __restrict__ first,
                      const int* __restrict__ rank, int* __restrict__ rowidx){
  __shared__ float fl[1024], scores[256];
  __shared__ int order[256], sidx[32], sfirst[16], srank[32];
  int tid=threadIdx.x;
  for(int ii=tid;ii<1024;ii+=256) fl[ii]=ffn[ii];
  if(tid<32){ sidx[tid]=idx[tid]; srank[tid]=rank[tid]; }
  else if(tid<48) sfirst[tid-32]=first[tid-32];
  __syncthreads();
  {
    int b=tid>>6, t=(tid>>4)&3, v=tid&15;
    int tt=sidx[b*8+sfirst[b*4+t]];
    const float4* row=(const float4*)(bank+(tt*16+v)*256);
    float s=0, nb=0;
    for(int d4=0;d4<64;d4++){
      float4 r=row[d4];
      const float* fb=&fl[b*256+d4*4];
      s +=fb[0]*r.x+fb[1]*r.y+fb[2]*r.z+fb[3]*r.w;
      nb+=r.x*r.x+r.y*r.y+r.z*r.z+r.w*r.w;
    }
    scores[tid]=s/fmaxf(sqrtf(nb),1e-12f);
  }
  __syncthreads();
  if(tid<16){
    const float* sc=&scores[tid*16];
    unsigned used=0;
    for(int pk=0;pk<16;pk++){
      int best=-1; float bv=-1e30f;
      for(int v2=0;v2<16;v2++){
        if(used&(1u<<v2)) continue;
        float vv=sc[v2];
        if(best<0||vv>bv){bv=vv;best=v2;}
      }
      used|=1u<<best;
      order[tid*16+pk]=best;
    }
  }
  __syncthreads();
  if(tid<32){
    int b=tid>>3;
    int t=sidx[tid];
    int v=order[(b*4+t)*16+srank[tid]];
    rowidx[tid]=t*16+v;
  }
}

// ---------------- m1/m3 hidden (32 blocks x 64 threads) ----------------
__global__ __launch_bounds__(64) void k_hid(const float* __restrict__ bank, const int* __restrict__ rowidx,
                     const float* __restrict__ m1_w1, const float* __restrict__ m1_b1,
                     const float* __restrict__ m1_g, const float* __restrict__ m1_b,
                     const float* __restrict__ m3_w1, const float* __restrict__ m3_b1,
                     const float* __restrict__ m3_g, const float* __restrict__ m3_b,
                     float* __restrict__ hid1, float* __restrict__ hid3){
  int bf=blockIdx.x, j=threadIdx.x;
  __shared__ float br[256];
  int ri=rowidx[bf];
  const float* row=bank+ri*256;
  for(int i=j;i<256;i+=64) br[i]=row[i];
  __syncthreads();
  {
    float s=m1_b1[j];
    for(int d=0;d<256;d++) s+=br[d]*m1_w1[d*64+j];
    float mu=wave_sum64(s)*(1.f/64.f);
    float dd=s-mu;
    float var=wave_sum64(dd*dd)*(1.f/64.f);
    float inv=1.0f/sqrtf(var+1e-5f);
    hid1[bf*64+j]=fmaxf(dd*inv*m1_g[j]+m1_b[j],0.f);
  }
  {
    float s=m3_b1[j];
    for(int d=0;d<256;d++) s+=br[d]*m3_w1[d*64+j];
    float mu=wave_sum64(s)*(1.f/64.f);
    float dd=s-mu;
    float var=wave_sum64(dd*dd)*(1.f/64.f);
    float inv=1.0f/sqrtf(var+1e-5f);
    hid3[bf*64+j]=fmaxf(dd*inv*m3_g[j]+m3_b[j],0.f);
  }
}

// ---------------- w1 head -> A1 bf16 [bf][o][c] ----------------
__global__ __launch_bounds__(256) void k_w1headT(const float* __restrict__ hid, const float* __restrict__ w2,
                          const float* __restrict__ b2, unsigned short* __restrict__ A1){
  int n=blockIdx.x*256+threadIdx.x;    // 0..4095, n = o*64+c
  __shared__ float hl[2048];
  for(int i=threadIdx.x;i<2048;i+=256) hl[i]=hid[i];
  __syncthreads();
  float wcol[64];
#pragma unroll
  for(int k=0;k<64;k++) wcol[k]=w2[k*4096+n];
  float bb=b2[n];
  for(int bf=0;bf<32;bf++){
    float s=bb;
#pragma unroll
    for(int k=0;k<64;k++) s+=hl[bf*64+k]*wcol[k];
    A1[bf*4096+n]=f2bf(s);
  }
}

// ---------------- w3 head -> A3 bf16 [bf][tap][o][c] ----------------
__global__ __launch_bounds__(256) void k_w3headT(const float* __restrict__ hid, const float* __restrict__ w2,
                          const float* __restrict__ b2, unsigned short* __restrict__ A3){
  int n=blockIdx.x*256+threadIdx.x;    // 0..36863, n = o*576 + c*9 + tap
  __shared__ float hl[2048];
  for(int i=threadIdx.x;i<2048;i+=256) hl[i]=hid[i];
  __syncthreads();
  float wcol[64];
#pragma unroll
  for(int k=0;k<64;k++) wcol[k]=w2[(size_t)k*36864+n];
  float bb=b2[n];
  int o=n/576, rem=n-o*576;
  int c=rem/9, tap=rem-c*9;
  size_t base=((size_t)tap*64+o)*64+c;
  for(int bf=0;bf<32;bf++){
    float s=bb;
#pragma unroll
    for(int k=0;k<64;k++) s+=hl[bf*64+k]*wcol[k];
    A3[(size_t)bf*9*4096+base]=f2bf(s);
  }
}

// ---------------- dynamic conv via MFMA: per (b,f) GEMM of 9 shifted taps ----------------
__global__ __launch_bounds__(256) void k_dynM(const unsigned short* __restrict__ imgT,
                       const unsigned short* __restrict__ A1, const unsigned short* __restrict__ A3,
                       const int* __restrict__ idx, const float* __restrict__ bn,
                       float* __restrict__ x){
  int blk=blockIdx.x;
  int bf=blk/24, hp=blk-bf*24;          // 32 bf × 24 row-pairs
  int b=bf>>3, f=bf&7;
  int tt=idx[b*8+f];
  int lane=threadIdx.x&63, mt=threadIdx.x>>6;   // wave = M-tile (16 o's)
  int n0=lane&15, kg=lane>>4;
  int h0=hp*2;
  const unsigned short* ib=imgT+(size_t)b*HW*64;
  floatx4 acc[6];
#pragma unroll
  for(int i=0;i<6;i++) acc[i]=(floatx4){0.f,0.f,0.f,0.f};
  if(tt==0){
    const unsigned short* Ab=A1+(size_t)bf*4096;
#pragma unroll
    for(int c0=0;c0<64;c0+=32){
      short8 a=*(const short8*)(Ab+((mt*16+n0)*64+c0+kg*8));
#pragma unroll
      for(int rr=0;rr<2;rr++){
#pragma unroll
        for(int wc=0;wc<3;wc++){
          int px=(h0+rr)*48+wc*16+n0;
          short8 bv=*(const short8*)(ib+((size_t)px*64+c0+kg*8));
          acc[rr*3+wc]=__builtin_amdgcn_mfma_f32_16x16x32_bf16(a,bv,acc[rr*3+wc],0,0,0);
        }
      }
    }
  } else {
    int d=tt;
    const unsigned short* A3b=A3+(size_t)bf*9*4096;
    for(int ti=0;ti<3;ti++){
      for(int tj=0;tj<3;tj++){
        int tap=ti*3+tj;
        int dh=d*(ti-1), dw=d*(tj-1);
        const unsigned short* Ab=A3b+(size_t)tap*4096;
#pragma unroll
        for(int c0=0;c0<64;c0+=32){
          short8 a=*(const short8*)(Ab+((mt*16+n0)*64+c0+kg*8));
#pragma unroll
          for(int rr=0;rr<2;rr++){
            int r=h0+rr+dh;
            if((unsigned)r>=48u) continue;
#pragma unroll
            for(int wc=0;wc<3;wc++){
              int w=wc*16+n0+dw;
              bool inb=(unsigned)w<48u;
              int px=r*48+w;
              short8 bv={0,0,0,0,0,0,0,0};
              if(inb) bv=*(const short8*)(ib+((size_t)px*64+c0+kg*8));
              acc[rr*3+wc]=__builtin_amdgcn_mfma_f32_16x16x32_bf16(a,bv,acc[rr*3+wc],0,0,0);
            }
          }
        }
      }
    }
  }
  // epilogue: C-frag col=lane&15 (px), row=kg*4+reg (o within tile); bn+leaky, mean over f via atomics
  int obase=mt*16+kg*4;
#pragma unroll
  for(int reg=0;reg<4;reg++){
    int o=obase+reg;
    float scale=bn[o]/sqrtf(bn[192+o]+1e-5f);
    float m_=bn[128+o], be_=bn[64+o];
#pragma unroll
    for(int rr=0;rr<2;rr++){
#pragma unroll
      for(int wc=0;wc<3;wc++){
        int px=(h0+rr)*48+wc*16+n0;
        float val=leaky((acc[rr*3+wc][reg]-m_)*scale+be_)*0.125f;
        atomicAdd(&x[((size_t)b*64+o)*HW+px],val);
      }
    }
  }
}

// ---------------- final: zc 1x1 conv + bias + residual ----------------
__global__ __launch_bounds__(256) void k_final(const float* __restrict__ img, const float* __restrict__ x,
                        const float* __restrict__ zw, const float* __restrict__ zb,
                        float* __restrict__ out){
  int t=blockIdx.x*256+threadIdx.x;
  int o=(t/HW)%64, b=t/(64*HW);
  int p2=t%HW;
  const float* xb=x+b*64*HW+p2;
  const float* wr=zw+o*64;
  float s=zb[o];
  for(int c=0;c<64;c++) s+=wr[c]*xb[c*HW];
  out[t]=s+img[t];
}

extern "C" void kernel_launch(void* const* d_in, const int* in_sizes, int n_in,
                              void* d_out, int out_size, void* d_ws, size_t ws_size,
                              hipStream_t stream){
  const float* bank   =(const float*)d_in[0];
  const float* task_f =(const float*)d_in[1];
  const float* img_f  =(const float*)d_in[2];
  const float* protos =(const float*)d_in[3];
  const float* tA_w1  =(const float*)d_in[4];
  const float* tA_w2  =(const float*)d_in[5];
  const float* iA_w   =(const float*)d_in[6];
  const float* iA_bn  =(const float*)d_in[7];
  const float* at_w1  =(const float*)d_in[8];
  const float* at_b1  =(const float*)d_in[9];
  const float* at_ln_g=(const float*)d_in[10];
  const float* at_ln_b=(const float*)d_in[11];
  const float* at_w2  =(const float*)d_in[12];
  const float* at_b2  =(const float*)d_in[13];
  const float* bv_t1  =(const float*)d_in[14];
  const float* bv_t2  =(const float*)d_in[15];
  const float* bv_ic1 =(const float*)d_in[16];
  const float* bv_bn1 =(const float*)d_in[17];
  const float* bv_ic2 =(const float*)d_in[18];
  const float* bv_bn2 =(const float*)d_in[19];
  const float* bv_w1  =(const float*)d_in[20];
  const float* bv_b1  =(const float*)d_in[21];
  const float* bv_ln_g=(const float*)d_in[22];
  const float* bv_ln_b=(const float*)d_in[23];
  const float* bv_w2  =(const float*)d_in[24];
  const float* bv_b2  =(const float*)d_in[25];
  const float* m1_w1  =(const float*)d_in[26];
  const float* m1_b1  =(const float*)d_in[27];
  const float* m1_ln_g=(const float*)d_in[28];
  const float* m1_ln_b=(const float*)d_in[29];
  const float* m1_w2  =(const float*)d_in[30];
  const float* m1_b2  =(const float*)d_in[31];
  const float* m3_w1  =(const float*)d_in[32];
  const float* m3_b1  =(const float*)d_in[33];
  const float* m3_ln_g=(const float*)d_in[34];
  const float* m3_ln_b=(const float*)d_in[35];
  const float* m3_w2  =(const float*)d_in[36];
  const float* m3_b2  =(const float*)d_in[37];
  const float* blr_bn =(const float*)d_in[38];
  const float* zc_w   =(const float*)d_in[39];
  const float* zc_b   =(const float*)d_in[40];

  float* ws=(float*)d_ws;
  float* totA=ws+0;       float* a0A=ws+16;      float* aLA=ws+32;
  float* totB=ws+48;      float* a0B=ws+304;     float* aLB=ws+560;
  float* rms =ws+816;     float* i1 =ws+820;     float* ie =ws+852;     // ie: 852..1364
  float* t1  =ws+1364;    float* te =ws+1396;    float* ffn=ws+1908;
  int*   idxp  =(int*)(ws+2932);
  int*   firstp=(int*)(ws+2964);
  int*   rankp =(int*)(ws+2980);
  int*   rowidx=(int*)(ws+3012);
  float* hid1=ws+3044;    float* hid3=ws+5092;
  unsigned short* A1p =(unsigned short*)(ws+7140);     // 131072 bf16
  unsigned short* A3p =(unsigned short*)(ws+72676);    // 1179648 bf16
  unsigned short* imgT=(unsigned short*)(ws+662500);   // 589824 bf16
  float* ie1 =ws+957412;
  float* x   =ws+1547236;
  // total: 2,137,060 floats (~8.5 MB)

  hipMemsetAsync(ws, 0, 1364*sizeof(float), stream);       // stats + i1 + ie accumulators
  hipMemsetAsync(x, 0, 589824*sizeof(float), stream);      // f-mean accumulator

  k_rms<<<NB,256,0,stream>>>(task_f, rms);
  k_statsA<<<dim3(NB,8),256,0,stream>>>(task_f, tA_w1, totA, a0A, aLA);
  k_statsB<<<dim3(NB,32),256,0,stream>>>(task_f, rms, bv_t1, totB, a0B, aLB);
  k_i1<<<dim3(NB*8,9),256,0,stream>>>(img_f, iA_w, iA_bn, i1);
  k_ic1<<<2304,256,0,stream>>>(img_f, bv_ic1, bv_bn1, ie1);
  k_ic2mean<<<dim3(NB*128,3),256,0,stream>>>(ie1, bv_ic2, bv_bn2, ie);
  k_imgT<<<144,256,0,stream>>>(img_f, imgT);
  k_te<<<NB,256,0,stream>>>(totA,a0A,aLA,totB,a0B,aLB, tA_w2, bv_t2, t1, te);
  k_att<<<1,256,0,stream>>>(t1, i1, at_w1, at_b1, at_ln_g, at_ln_b, at_w2, at_b2, protos,
                            idxp, firstp, rankp);
  k_ff<<<1,256,0,stream>>>(te, ie, bv_w1, bv_b1, bv_ln_g, bv_ln_b, bv_w2, bv_b2, ffn);
  k_sel<<<1,256,0,stream>>>(ffn, bank, idxp, firstp, rankp, rowidx);
  k_hid<<<32,64,0,stream>>>(bank, rowidx, m1_w1, m1_b1, m1_ln_g, m1_ln_b,
                            m3_w1, m3_b1, m3_ln_g, m3_ln_b, hid1, hid3);
  k_w1headT<<<16,256,0,stream>>>(hid1, m1_w2, m1_b2, A1p);
  k_w3headT<<<144,256,0,stream>>>(hid3, m3_w2, m3_b2, A3p);
  k_dynM<<<768,256,0,stream>>>(imgT, A1p, A3p, idxp, blr_bn, x);
  k_final<<<2304,256,0,stream>>>(img_f, x, zc_w, zc_b, (float*)d_out);

  (void)in_sizes; (void)n_in; (void)out_size; (void)ws_size;
}

// Round 4
// 540.539 us; speedup vs baseline: 5.3552x; 1.4780x over previous
//
#include <hip/hip_runtime.h>
#include <math.h>

#define LEAKC 0.2f

#define NB 4
#define NC 64
#define NH 48
#define NW 48
#define LLEN 16384
#define HW 2304

typedef __attribute__((ext_vector_type(8))) short short8;
typedef __attribute__((ext_vector_type(4))) float floatx4;

__device__ __forceinline__ float leaky(float x){ return x > 0.f ? x : LEAKC*x; }

__device__ __forceinline__ float wave_sum64(float v){
  for(int off=32;off;off>>=1) v += __shfl_xor(v,off);
  return v;
}

__device__ __forceinline__ unsigned short f2bf(float x){
  unsigned u=__float_as_uint(x);
  unsigned r=u+0x7FFFu+((u>>16)&1u);
  return (unsigned short)(r>>16);
}

__device__ __forceinline__ void threefry2x32(unsigned k0, unsigned k1, unsigned& x0, unsigned& x1){
  unsigned ks0=k0, ks1=k1, ks2=k0^k1^0x1BD11BDAu;
  x0+=ks0; x1+=ks1;
  const int rot0[4]={13,15,26,6};
  const int rot1[4]={17,29,16,24};
#define TF_APPLY(rr) {for(int r=0;r<4;r++){x0+=x1; x1=(x1<<rr[r])|(x1>>(32-rr[r])); x1^=x0;}}
  TF_APPLY(rot0); x0+=ks1; x1+=ks2+1u;
  TF_APPLY(rot1); x0+=ks2; x1+=ks0+2u;
  TF_APPLY(rot0); x0+=ks0; x1+=ks1+3u;
  TF_APPLY(rot1); x0+=ks1; x1+=ks2+4u;
  TF_APPLY(rot0); x0+=ks2; x1+=ks0+5u;
#undef TF_APPLY
}

__device__ __forceinline__ float jax_uniform128(int i){
  unsigned x0=0u, x1=(unsigned)i;
  threefry2x32(0u,42u,x0,x1);
  unsigned bits = x0 ^ x1;
  unsigned fb=(bits>>9)|0x3f800000u;
  float f=__uint_as_float(fb)-1.0f;
  float u=f*(1.0f-1e-10f)+1e-10f;
  return fmaxf(1e-10f,u);
}

// ---------------- rms over task_f per b ----------------
__global__ __launch_bounds__(256) void k_rms(const float* __restrict__ task_f, float* __restrict__ rms){
  int b=blockIdx.x;
  const float* x=task_f+b*LLEN;
  float s=0;
  for(int i=threadIdx.x;i<LLEN;i+=256){ float v=x[i]; s+=v*v; }
  __shared__ float red[256];
  red[threadIdx.x]=s; __syncthreads();
  for(int off=128;off;off>>=1){ if(threadIdx.x<off) red[threadIdx.x]+=red[threadIdx.x+off]; __syncthreads(); }
  if(threadIdx.x==0) rms[b]=sqrtf(red[0]/(float)LLEN);
}

// ---------------- branch A conv1 stats (4 ch) ----------------
__global__ __launch_bounds__(256) void k_statsA(const float* __restrict__ task_f, const float* __restrict__ w1,
                         float* __restrict__ totA, float* __restrict__ a0A, float* __restrict__ aLA){
  int b=blockIdx.x, seg=blockIdx.y;
  const float* x=task_f+b*LLEN;
  float tot[4]={0,0,0,0};
  int l0=seg*2048;
  for(int l=l0+threadIdx.x;l<l0+2048;l+=256){
    float xm=(l>0)?x[l-1]:0.f;
    float xc=x[l];
    float xp=(l<LLEN-1)?x[l+1]:0.f;
#pragma unroll
    for(int c=0;c<4;c++){
      float a=leaky(w1[c*3+0]*xm + w1[c*3+1]*xc + w1[c*3+2]*xp);
      tot[c]+=a;
      if(l==0) a0A[b*4+c]=a;
      if(l==LLEN-1) aLA[b*4+c]=a;
    }
  }
#pragma unroll
  for(int c=0;c<4;c++) tot[c]=wave_sum64(tot[c]);
  __shared__ float red[4][4];
  int wave=threadIdx.x>>6, lane=threadIdx.x&63;
  if(lane==0){
#pragma unroll
    for(int c=0;c<4;c++) red[wave][c]=tot[c];
  }
  __syncthreads();
  if(threadIdx.x<4){
    float s=red[0][threadIdx.x]+red[1][threadIdx.x]+red[2][threadIdx.x]+red[3][threadIdx.x];
    atomicAdd(&totA[b*4+threadIdx.x], s);
  }
}

// ---------------- branch B conv1 stats (64 ch) ----------------
__global__ __launch_bounds__(256) void k_statsB(const float* __restrict__ task_f, const float* __restrict__ rms,
                         const float* __restrict__ w1,
                         float* __restrict__ totB, float* __restrict__ a0B, float* __restrict__ aLB){
  int b=blockIdx.x, seg=blockIdx.y;
  float sc=1.f/(rms[b]+1e-8f);
  const float* x=task_f+b*LLEN;
  float tot[64];
#pragma unroll
  for(int c=0;c<64;c++) tot[c]=0.f;
  int l0=seg*512;
  for(int l=l0+threadIdx.x;l<l0+512;l+=256){
    float xm=((l>0)?x[l-1]:0.f)*sc;
    float xc=x[l]*sc;
    float xp=((l<LLEN-1)?x[l+1]:0.f)*sc;
#pragma unroll
    for(int c=0;c<64;c++){
      float a=leaky(w1[c*3+0]*xm + w1[c*3+1]*xc + w1[c*3+2]*xp);
      tot[c]+=a;
      if(l==0) a0B[b*64+c]=a;
      if(l==LLEN-1) aLB[b*64+c]=a;
    }
  }
#pragma unroll
  for(int c=0;c<64;c++){
    float v=tot[c];
    for(int off=32;off;off>>=1) v+=__shfl_down(v,off);
    tot[c]=v;
  }
  __shared__ float red[4][64];
  int wave=threadIdx.x>>6, lane=threadIdx.x&63;
  if(lane==0){
#pragma unroll
    for(int c=0;c<64;c++) red[wave][c]=tot[c];
  }
  __syncthreads();
  if(threadIdx.x<64){
    float s=red[0][threadIdx.x]+red[1][threadIdx.x]+red[2][threadIdx.x]+red[3][threadIdx.x];
    atomicAdd(&totB[b*64+threadIdx.x], s);
  }
}

// ---------------- iA conv + bn + leaky + spatial mean -> i1 (B,8) ----------------
__global__ __launch_bounds__(256) void k_i1(const float* __restrict__ img, const float* __restrict__ w,
                     const float* __restrict__ bn, float* __restrict__ i1){
  int b=blockIdx.x>>3, oc=blockIdx.x&7, seg=blockIdx.y;
  __shared__ float wk[576];
  __shared__ float red[256];
  for(int i=threadIdx.x;i<576;i+=256) wk[i]=w[oc*576+i];
  __syncthreads();
  float g=bn[oc], be=bn[8+oc], m=bn[16+oc], v=bn[24+oc];
  float scale=g/sqrtf(v+1e-5f);
  const float* ib=img+b*NC*HW;
  int p=seg*256+threadIdx.x;
  int h=p/48, wj=p%48;
  float acc=0;
  for(int c=0;c<64;c++){
    const float* ic=ib+c*HW;
#pragma unroll
    for(int i=0;i<3;i++){
      int hh=h+i-1; if((unsigned)hh>=48u) continue;
#pragma unroll
      for(int j=0;j<3;j++){
        int ww=wj+j-1; if((unsigned)ww>=48u) continue;
        acc+=wk[c*9+i*3+j]*ic[hh*48+ww];
      }
    }
  }
  float s=leaky((acc-m)*scale+be);
  red[threadIdx.x]=s; __syncthreads();
  for(int off=128;off;off>>=1){ if(threadIdx.x<off) red[threadIdx.x]+=red[threadIdx.x+off]; __syncthreads(); }
  if(threadIdx.x==0) atomicAdd(&i1[b*8+oc], red[0]*(1.f/2304.f));
}

// ---------------- img -> bf16 transposed [b][px][c] ----------------
__global__ __launch_bounds__(256) void k_imgT(const float* __restrict__ img, unsigned short* __restrict__ imgT){
  int blk=blockIdx.x;
  int b=blk/36, t=blk%36;
  int p0=t*64;
  __shared__ float tile[64][65];
  int pp=threadIdx.x&63, c4=threadIdx.x>>6;
  for(int r=0;r<16;r++){
    int c=c4*16+r;
    tile[c][pp]=img[(b*64+c)*HW + p0+pp];
  }
  __syncthreads();
  int px=threadIdx.x>>2, cg=(threadIdx.x&3)*16;
  unsigned out[8];
#pragma unroll
  for(int q=0;q<8;q++){
    unsigned lo=f2bf(tile[cg+2*q][px]);
    unsigned hi=f2bf(tile[cg+2*q+1][px]);
    out[q]=lo|(hi<<16);
  }
  unsigned* dst=(unsigned*)(imgT + ((size_t)(b*HW+p0+px)*64 + cg));
#pragma unroll
  for(int q=0;q<8;q++) dst[q]=out[q];
}

// ---------------- static conv weights -> bf16 [tap][oc][c] ----------------
__global__ __launch_bounds__(256) void k_prepW(const float* __restrict__ w1, const float* __restrict__ w2,
                        unsigned short* __restrict__ W1T, unsigned short* __restrict__ W2T){
  int n=blockIdx.x*256+threadIdx.x;
  if(n<9*64*64){
    int tap=n>>12, oc=(n>>6)&63, c=n&63;
    W1T[n]=f2bf(w1[oc*576+c*9+tap]);
  } else {
    int m=n-9*64*64;
    if(m<9*128*64){
      int tap=m/8192, r=m-tap*8192, oc=r>>6, c=r&63;
      W2T[m]=f2bf(w2[oc*576+c*9+tap]);
    }
  }
}

// ---------------- bv_ic1 conv via MFMA -> ie1T bf16 [b][px][c] ----------------
__global__ __launch_bounds__(256) void k_ic1M(const unsigned short* __restrict__ imgT,
                       const unsigned short* __restrict__ W1T,
                       const float* __restrict__ bn, unsigned short* __restrict__ ie1T){
  int blk=blockIdx.x;
  int b=blk/24, hp=blk-b*24;
  int lane=threadIdx.x&63, mt=threadIdx.x>>6;
  int n0=lane&15, kg=lane>>4;
  int h0=hp*2;
  const unsigned short* ib=imgT+(size_t)b*HW*64;
  floatx4 acc[6];
#pragma unroll
  for(int i=0;i<6;i++) acc[i]=(floatx4){0.f,0.f,0.f,0.f};
  for(int ti=0;ti<3;ti++){
    for(int tj=0;tj<3;tj++){
      int tap=ti*3+tj;
      int dh=ti-1, dw=tj-1;
      const unsigned short* Ab=W1T+(size_t)tap*4096;
#pragma unroll
      for(int c0=0;c0<64;c0+=32){
        short8 a=*(const short8*)(Ab+((mt*16+n0)*64+c0+kg*8));
#pragma unroll
        for(int rr=0;rr<2;rr++){
          int r=h0+rr+dh;
          if((unsigned)r>=48u) continue;
#pragma unroll
          for(int wc=0;wc<3;wc++){
            int w=wc*16+n0+dw;
            bool inb=(unsigned)w<48u;
            short8 bv={0,0,0,0,0,0,0,0};
            if(inb) bv=*(const short8*)(ib+((size_t)(r*48+w)*64+c0+kg*8));
            acc[rr*3+wc]=__builtin_amdgcn_mfma_f32_16x16x32_bf16(a,bv,acc[rr*3+wc],0,0,0);
          }
        }
      }
    }
  }
  int obase=mt*16+kg*4;
  float scale[4],m_[4],be_[4];
#pragma unroll
  for(int reg=0;reg<4;reg++){
    int o=obase+reg;
    scale[reg]=bn[o]/sqrtf(bn[192+o]+1e-5f);
    m_[reg]=bn[128+o]; be_[reg]=bn[64+o];
  }
#pragma unroll
  for(int rr=0;rr<2;rr++){
#pragma unroll
    for(int wc=0;wc<3;wc++){
      int px=(h0+rr)*48+wc*16+n0;
      float v0=leaky((acc[rr*3+wc][0]-m_[0])*scale[0]+be_[0]);
      float v1=leaky((acc[rr*3+wc][1]-m_[1])*scale[1]+be_[1]);
      float v2=leaky((acc[rr*3+wc][2]-m_[2])*scale[2]+be_[2]);
      float v3=leaky((acc[rr*3+wc][3]-m_[3])*scale[3]+be_[3]);
      unsigned w0=f2bf(v0)|((unsigned)f2bf(v1)<<16);
      unsigned w1=f2bf(v2)|((unsigned)f2bf(v3)<<16);
      uint2 pk={w0,w1};
      *(uint2*)(ie1T+((size_t)(b*HW+px)*64+obase))=pk;
    }
  }
}

// ---------------- bv_ic2 conv via MFMA + bn + leaky + spatial mean -> ie (B,128) ----------------
__global__ __launch_bounds__(256) void k_ic2M(const unsigned short* __restrict__ ie1T,
                       const unsigned short* __restrict__ W2T,
                       const float* __restrict__ bn, float* __restrict__ ie){
  int blk=blockIdx.x;
  int b=blk/24, hp=blk-b*24;
  int mo=blockIdx.y*64;
  int lane=threadIdx.x&63, mt=threadIdx.x>>6;
  int n0=lane&15, kg=lane>>4;
  int h0=hp*2;
  const unsigned short* ib=ie1T+(size_t)b*HW*64;
  floatx4 acc[6];
#pragma unroll
  for(int i=0;i<6;i++) acc[i]=(floatx4){0.f,0.f,0.f,0.f};
  for(int ti=0;ti<3;ti++){
    for(int tj=0;tj<3;tj++){
      int tap=ti*3+tj;
      int dh=ti-1, dw=tj-1;
      const unsigned short* Ab=W2T+(size_t)tap*8192;
#pragma unroll
      for(int c0=0;c0<64;c0+=32){
        short8 a=*(const short8*)(Ab+((mo+mt*16+n0)*64+c0+kg*8));
#pragma unroll
        for(int rr=0;rr<2;rr++){
          int r=h0+rr+dh;
          if((unsigned)r>=48u) continue;
#pragma unroll
          for(int wc=0;wc<3;wc++){
            int w=wc*16+n0+dw;
            bool inb=(unsigned)w<48u;
            short8 bv={0,0,0,0,0,0,0,0};
            if(inb) bv=*(const short8*)(ib+((size_t)(r*48+w)*64+c0+kg*8));
            acc[rr*3+wc]=__builtin_amdgcn_mfma_f32_16x16x32_bf16(a,bv,acc[rr*3+wc],0,0,0);
          }
        }
      }
    }
  }
  int obase=mo+mt*16+kg*4;
#pragma unroll
  for(int reg=0;reg<4;reg++){
    int o=obase+reg;
    float scale=bn[o]/sqrtf(bn[384+o]+1e-5f);
    float m_=bn[256+o], be_=bn[128+o];
    float part=0;
#pragma unroll
    for(int i=0;i<6;i++) part+=leaky((acc[i][reg]-m_)*scale+be_);
    // reduce over the 16 px-lanes (n0); xor of low 4 bits stays in same kg group
    for(int off=1;off<16;off<<=1) part+=__shfl_xor(part,off);
    if(n0==0) atomicAdd(&ie[b*128+o], part*(1.f/2304.f));
  }
}

// ---------------- t1 (B,8) and te (B,128) from conv1 stats ----------------
__global__ __launch_bounds__(256) void k_te(const float* __restrict__ totA, const float* __restrict__ a0A,
                     const float* __restrict__ aLA, const float* __restrict__ totB,
                     const float* __restrict__ a0B, const float* __restrict__ aLB,
                     const float* __restrict__ tA_w2, const float* __restrict__ bv_t2,
                     float* __restrict__ t1o, float* __restrict__ teo){
  int b=blockIdx.x, tid=threadIdx.x;
  const float invL=1.0f/16384.0f;
  __shared__ float sT[64], s0[64], sL[64];
  if(tid<64){ sT[tid]=totB[b*64+tid]; s0[tid]=a0B[b*64+tid]; sL[tid]=aLB[b*64+tid]; }
  __syncthreads();
  if(tid<128){
    int c2=tid;
    const float* wr=bv_t2+c2*192;
    float s=0;
    for(int c1=0;c1<64;c1+=8){
      float4 q[6];
      const float4* r4=(const float4*)(wr+c1*3);
#pragma unroll
      for(int u=0;u<6;u++) q[u]=r4[u];
      const float* qq=(const float*)q;
#pragma unroll
      for(int u=0;u<8;u++){
        int c=c1+u;
        float T=sT[c], A0=s0[c], AL=sL[c];
        s += qq[u*3+0]*(T-AL) + qq[u*3+1]*T + qq[u*3+2]*(T-A0);
      }
    }
    teo[b*128+c2]=s*invL;
  } else if(tid<136){
    int c2=tid-128;
    float s=0;
    for(int c1=0;c1<4;c1++){
      float T=totA[b*4+c1], A0=a0A[b*4+c1], AL=aLA[b*4+c1];
      const float* w=&tA_w2[(c2*4+c1)*3];
      s += w[0]*(T-AL) + w[1]*T + w[2]*(T-A0);
    }
    t1o[b*8+c2]=s*invL;
  }
}

// ---------------- attention MLP -> idx/first/rank ----------------
__global__ __launch_bounds__(256) void k_att(const float* __restrict__ t1, const float* __restrict__ i1,
                      const float* __restrict__ at_w1, const float* __restrict__ at_b1,
                      const float* __restrict__ at_ln_g, const float* __restrict__ at_ln_b,
                      const float* __restrict__ at_w2, const float* __restrict__ at_b2,
                      const float* __restrict__ protos,
                      int* __restrict__ idxo, int* __restrict__ firsto, int* __restrict__ ranko){
  __shared__ float f1[64], h[256], tif[512], tifn[512], tden[32], pden[4], pn[64], z[128];
  __shared__ int sidx[32];
  int tid=threadIdx.x;
  if(tid<32) f1[(tid>>3)*16+(tid&7)]=t1[tid];
  else if(tid<64){ int r=tid-32; f1[(r>>3)*16+8+(r&7)]=i1[r]; }
  __syncthreads();
  int b=tid>>6, j=tid&63;
  float s=at_b1[j];
  for(int i=0;i<16;i++) s+=f1[b*16+i]*at_w1[i*64+j];
  float mu=wave_sum64(s)*(1.f/64.f);
  float d=s-mu;
  float var=wave_sum64(d*d)*(1.f/64.f);
  float inv=1.0f/sqrtf(var+1e-5f);
  h[tid]=fmaxf(d*inv*at_ln_g[j]+at_ln_b[j],0.f);
  __syncthreads();
  for(int ii=tid;ii<512;ii+=256){
    int bb=ii>>7, n=ii&127;
    float ss=at_b2[n];
    for(int k=0;k<64;k++) ss+=h[bb*64+k]*at_w2[k*128+n];
    tif[ii]=ss;
  }
  __syncthreads();
  if(tid<32){
    int bb=tid>>3, f=tid&7;
    float ss=0; for(int e=0;e<16;e++){float v=tif[bb*128+e*8+f]; ss+=v*v;}
    tden[tid]=fmaxf(sqrtf(ss),1e-8f);
  } else if(tid<36){
    int t=tid-32;
    float ss=0; for(int e=0;e<16;e++){float v=protos[t*16+e]; ss+=v*v;}
    pden[t]=fmaxf(sqrtf(ss),1e-8f);
  }
  __syncthreads();
  for(int ii=tid;ii<512;ii+=256){
    int bb=ii>>7, n=ii&127, f=n&7;
    tifn[ii]=tif[ii]/tden[bb*8+f];
  }
  if(tid<64) pn[tid]=protos[tid]/pden[tid>>4];
  __syncthreads();
  if(tid<128){
    int bb=tid>>5, f=(tid>>2)&7, t=tid&3;
    float ss=0;
    for(int e=0;e<16;e++) ss+=pn[t*16+e]*tifn[bb*128+e*8+f];
    float u=jax_uniform128(tid);
    float g=-logf(-logf(u));
    z[tid]=ss+g;
  }
  __syncthreads();
  if(tid<32){
    float best=z[tid*4]; int bi=0;
    for(int t=1;t<4;t++){ float v=z[tid*4+t]; if(v>best){best=v;bi=t;} }
    sidx[tid]=bi;
  }
  __syncthreads();
  if(tid<16){
    int bb=tid>>2, t=tid&3;
    int fi=0;
    for(int f=7;f>=0;f--) if(sidx[bb*8+f]==t) fi=f;
    firsto[tid]=fi;
  } else if(tid<48){
    int r=tid-16, bb=r>>3, f=r&7;
    int c=0; for(int f2=0;f2<f;f2++) if(sidx[bb*8+f2]==sidx[bb*8+f]) c++;
    ranko[r]=c;
  }
  __syncthreads();
  if(tid<32) idxo[tid]=sidx[tid];
}

// ---------------- branch-B MLP -> normalized ff (B,256) ----------------
__global__ __launch_bounds__(256) void k_ff(const float* __restrict__ te, const float* __restrict__ ie,
                     const float* __restrict__ bv_w1, const float* __restrict__ bv_b1,
                     const float* __restrict__ bv_ln_g, const float* __restrict__ bv_ln_b,
                     const float* __restrict__ bv_w2, const float* __restrict__ bv_b2,
                     float* __restrict__ ffn){
  __shared__ float f[1024], hh[256], ffs[1024], finv[4];
  int tid=threadIdx.x;
  for(int ii=tid;ii<512;ii+=256){
    int bb=ii>>7, k=ii&127;
    f[bb*256+k]=te[ii];
    f[bb*256+128+k]=ie[ii];
  }
  __syncthreads();
  int b=tid>>6, j=tid&63;
  float s=bv_b1[j];
  for(int k=0;k<256;k++) s+=f[b*256+k]*bv_w1[k*64+j];
  float mu=wave_sum64(s)*(1.f/64.f);
  float d=s-mu;
  float var=wave_sum64(d*d)*(1.f/64.f);
  float inv=1.0f/sqrtf(var+1e-5f);
  hh[tid]=fmaxf(d*inv*bv_ln_g[j]+bv_ln_b[j],0.f);
  __syncthreads();
  for(int ii=tid;ii<1024;ii+=256){
    int bb=ii>>8, n=ii&255;
    float ss=bv_b2[n];
    for(int k=0;k<64;k++) ss+=hh[bb*64+k]*bv_w2[k*256+n];
    ffs[ii]=ss;
  }
  __syncthreads();
  {
    int lane=tid&63;
    float sq=0;
#pragma unroll
    for(int u=0;u<4;u++){ float v=ffs[b*256+u*64+lane]; sq+=v*v; }
    sq=wave_sum64(sq);
    if(lane==0) finv[b]=1.0f/fmaxf(sqrtf(sq),1e-12f);
  }
  __syncthreads();
  for(int ii=tid;ii<1024;ii+=256) ffn[ii]=ffs[ii]*finv[ii>>8];
}

// ---------------- scores + argsort + selection -> rowidx ----------------
__global__ __launch_bounds__(256) void k_sel(const float* __restrict__ ffn, const float* __restrict__ bank,
                      const int* __restrict__ idx, const int* __restrict__ first,
                      const int* __restrict__ rank, int* __restrict__ rowidx){
  __shared__ float fl[1024], scores[256];
  __shared__ int order[256], sidx[32], sfirst[16], srank[32];
  int tid=threadIdx.x;
  for(int ii=tid;ii<1024;ii+=256) fl[ii]=ffn[ii];
  if(tid<32){ sidx[tid]=idx[tid]; srank[tid]=rank[tid]; }
  else if(tid<48) sfirst[tid-32]=first[tid-32];
  __syncthreads();
  {
    int b=tid>>6, t=(tid>>4)&3, v=tid&15;
    int tt=sidx[b*8+sfirst[b*4+t]];
    const float4* row=(const float4*)(bank+(tt*16+v)*256);
    float s=0, nb=0;
    for(int d4=0;d4<64;d4++){
      float4 r=row[d4];
      const float* fb=&fl[b*256+d4*4];
      s +=fb[0]*r.x+fb[1]*r.y+fb[2]*r.z+fb[3]*r.w;
      nb+=r.x*r.x+r.y*r.y+r.z*r.z+r.w*r.w;
    }
    scores[tid]=s/fmaxf(sqrtf(nb),1e-12f);
  }
  __syncthreads();
  if(tid<16){
    const float* sc=&scores[tid*16];
    unsigned used=0;
    for(int pk=0;pk<16;pk++){
      int best=-1; float bv=-1e30f;
      for(int v2=0;v2<16;v2++){
        if(used&(1u<<v2)) continue;
        float vv=sc[v2];
        if(best<0||vv>bv){bv=vv;best=v2;}
      }
      used|=1u<<best;
      order[tid*16+pk]=best;
    }
  }
  __syncthreads();
  if(tid<32){
    int b=tid>>3;
    int t=sidx[tid];
    int v=order[(b*4+t)*16+srank[tid]];
    rowidx[tid]=t*16+v;
  }
}

// ---------------- m1/m3 hidden (32 blocks x 64 threads) ----------------
__global__ __launch_bounds__(64) void k_hid(const float* __restrict__ bank, const int* __restrict__ rowidx,
                     const float* __restrict__ m1_w1, const float* __restrict__ m1_b1,
                     const float* __restrict__ m1_g, const float* __restrict__ m1_b,
                     const float* __restrict__ m3_w1, const float* __restrict__ m3_b1,
                     const float* __restrict__ m3_g, const float* __restrict__ m3_b,
                     float* __restrict__ hid1, float* __restrict__ hid3){
  int bf=blockIdx.x, j=threadIdx.x;
  __shared__ float br[256];
  int ri=rowidx[bf];
  const float* row=bank+ri*256;
  for(int i=j;i<256;i+=64) br[i]=row[i];
  __syncthreads();
  {
    float s=m1_b1[j];
    for(int d=0;d<256;d++) s+=br[d]*m1_w1[d*64+j];
    float mu=wave_sum64(s)*(1.f/64.f);
    float dd=s-mu;
    float var=wave_sum64(dd*dd)*(1.f/64.f);
    float inv=1.0f/sqrtf(var+1e-5f);
    hid1[bf*64+j]=fmaxf(dd*inv*m1_g[j]+m1_b[j],0.f);
  }
  {
    float s=m3_b1[j];
    for(int d=0;d<256;d++) s+=br[d]*m3_w1[d*64+j];
    float mu=wave_sum64(s)*(1.f/64.f);
    float dd=s-mu;
    float var=wave_sum64(dd*dd)*(1.f/64.f);
    float inv=1.0f/sqrtf(var+1e-5f);
    hid3[bf*64+j]=fmaxf(dd*inv*m3_g[j]+m3_b[j],0.f);
  }
}

// ---------------- w1 head -> A1 bf16 [bf][o][c] ----------------
__global__ __launch_bounds__(256) void k_w1headT(const float* __restrict__ hid, const float* __restrict__ w2,
                          const float* __restrict__ b2, unsigned short* __restrict__ A1){
  int n=blockIdx.x*256+threadIdx.x;
  __shared__ float hl[2048];
  for(int i=threadIdx.x;i<2048;i+=256) hl[i]=hid[i];
  __syncthreads();
  float wcol[64];
#pragma unroll
  for(int k=0;k<64;k++) wcol[k]=w2[k*4096+n];
  float bb=b2[n];
  for(int bf=0;bf<32;bf++){
    float s=bb;
#pragma unroll
    for(int k=0;k<64;k++) s+=hl[bf*64+k]*wcol[k];
    A1[bf*4096+n]=f2bf(s);
  }
}

// ---------------- w3 head -> A3 bf16 [bf][tap][o][c] ----------------
__global__ __launch_bounds__(256) void k_w3headT(const float* __restrict__ hid, const float* __restrict__ w2,
                          const float* __restrict__ b2, unsigned short* __restrict__ A3){
  int n=blockIdx.x*256+threadIdx.x;
  __shared__ float hl[2048];
  for(int i=threadIdx.x;i<2048;i+=256) hl[i]=hid[i];
  __syncthreads();
  float wcol[64];
#pragma unroll
  for(int k=0;k<64;k++) wcol[k]=w2[(size_t)k*36864+n];
  float bb=b2[n];
  int o=n/576, rem=n-o*576;
  int c=rem/9, tap=rem-c*9;
  size_t base=((size_t)tap*64+o)*64+c;
  for(int bf=0;bf<32;bf++){
    float s=bb;
#pragma unroll
    for(int k=0;k<64;k++) s+=hl[bf*64+k]*wcol[k];
    A3[(size_t)bf*9*4096+base]=f2bf(s);
  }
}

// ---------------- dynamic conv via MFMA ----------------
__global__ __launch_bounds__(256) void k_dynM(const unsigned short* __restrict__ imgT,
                       const unsigned short* __restrict__ A1, const unsigned short* __restrict__ A3,
                       const int* __restrict__ idx, const float* __restrict__ bn,
                       float* __restrict__ x){
  int blk=blockIdx.x;
  int bf=blk/24, hp=blk-bf*24;
  int b=bf>>3, f=bf&7;
  int tt=idx[b*8+f];
  int lane=threadIdx.x&63, mt=threadIdx.x>>6;
  int n0=lane&15, kg=lane>>4;
  int h0=hp*2;
  const unsigned short* ib=imgT+(size_t)b*HW*64;
  floatx4 acc[6];
#pragma unroll
  for(int i=0;i<6;i++) acc[i]=(floatx4){0.f,0.f,0.f,0.f};
  if(tt==0){
    const unsigned short* Ab=A1+(size_t)bf*4096;
#pragma unroll
    for(int c0=0;c0<64;c0+=32){
      short8 a=*(const short8*)(Ab+((mt*16+n0)*64+c0+kg*8));
#pragma unroll
      for(int rr=0;rr<2;rr++){
#pragma unroll
        for(int wc=0;wc<3;wc++){
          int px=(h0+rr)*48+wc*16+n0;
          short8 bv=*(const short8*)(ib+((size_t)px*64+c0+kg*8));
          acc[rr*3+wc]=__builtin_amdgcn_mfma_f32_16x16x32_bf16(a,bv,acc[rr*3+wc],0,0,0);
        }
      }
    }
  } else {
    int d=tt;
    const unsigned short* A3b=A3+(size_t)bf*9*4096;
    for(int ti=0;ti<3;ti++){
      for(int tj=0;tj<3;tj++){
        int tap=ti*3+tj;
        int dh=d*(ti-1), dw=d*(tj-1);
        const unsigned short* Ab=A3b+(size_t)tap*4096;
#pragma unroll
        for(int c0=0;c0<64;c0+=32){
          short8 a=*(const short8*)(Ab+((mt*16+n0)*64+c0+kg*8));
#pragma unroll
          for(int rr=0;rr<2;rr++){
            int r=h0+rr+dh;
            if((unsigned)r>=48u) continue;
#pragma unroll
            for(int wc=0;wc<3;wc++){
              int w=wc*16+n0+dw;
              bool inb=(unsigned)w<48u;
              int px=r*48+w;
              short8 bv={0,0,0,0,0,0,0,0};
              if(inb) bv=*(const short8*)(ib+((size_t)px*64+c0+kg*8));
              acc[rr*3+wc]=__builtin_amdgcn_mfma_f32_16x16x32_bf16(a,bv,acc[rr*3+wc],0,0,0);
            }
          }
        }
      }
    }
  }
  int obase=mt*16+kg*4;
#pragma unroll
  for(int reg=0;reg<4;reg++){
    int o=obase+reg;
    float scale=bn[o]/sqrtf(bn[192+o]+1e-5f);
    float m_=bn[128+o], be_=bn[64+o];
#pragma unroll
    for(int rr=0;rr<2;rr++){
#pragma unroll
      for(int wc=0;wc<3;wc++){
        int px=(h0+rr)*48+wc*16+n0;
        float val=leaky((acc[rr*3+wc][reg]-m_)*scale+be_)*0.125f;
        atomicAdd(&x[((size_t)b*64+o)*HW+px],val);
      }
    }
  }
}

// ---------------- final: zc 1x1 conv + bias + residual ----------------
__global__ __launch_bounds__(256) void k_final(const float* __restrict__ img, const float* __restrict__ x,
                        const float* __restrict__ zw, const float* __restrict__ zb,
                        float* __restrict__ out){
  int t=blockIdx.x*256+threadIdx.x;
  int o=(t/HW)%64, b=t/(64*HW);
  int p2=t%HW;
  const float* xb=x+b*64*HW+p2;
  const float* wr=zw+o*64;
  float s=zb[o];
  for(int c=0;c<64;c++) s+=wr[c]*xb[c*HW];
  out[t]=s+img[t];
}

extern "C" void kernel_launch(void* const* d_in, const int* in_sizes, int n_in,
                              void* d_out, int out_size, void* d_ws, size_t ws_size,
                              hipStream_t stream){
  const float* bank   =(const float*)d_in[0];
  const float* task_f =(const float*)d_in[1];
  const float* img_f  =(const float*)d_in[2];
  const float* protos =(const float*)d_in[3];
  const float* tA_w1  =(const float*)d_in[4];
  const float* tA_w2  =(const float*)d_in[5];
  const float* iA_w   =(const float*)d_in[6];
  const float* iA_bn  =(const float*)d_in[7];
  const float* at_w1  =(const float*)d_in[8];
  const float* at_b1  =(const float*)d_in[9];
  const float* at_ln_g=(const float*)d_in[10];
  const float* at_ln_b=(const float*)d_in[11];
  const float* at_w2  =(const float*)d_in[12];
  const float* at_b2  =(const float*)d_in[13];
  const float* bv_t1  =(const float*)d_in[14];
  const float* bv_t2  =(const float*)d_in[15];
  const float* bv_ic1 =(const float*)d_in[16];
  const float* bv_bn1 =(const float*)d_in[17];
  const float* bv_ic2 =(const float*)d_in[18];
  const float* bv_bn2 =(const float*)d_in[19];
  const float* bv_w1  =(const float*)d_in[20];
  const float* bv_b1  =(const float*)d_in[21];
  const float* bv_ln_g=(const float*)d_in[22];
  const float* bv_ln_b=(const float*)d_in[23];
  const float* bv_w2  =(const float*)d_in[24];
  const float* bv_b2  =(const float*)d_in[25];
  const float* m1_w1  =(const float*)d_in[26];
  const float* m1_b1  =(const float*)d_in[27];
  const float* m1_ln_g=(const float*)d_in[28];
  const float* m1_ln_b=(const float*)d_in[29];
  const float* m1_w2  =(const float*)d_in[30];
  const float* m1_b2  =(const float*)d_in[31];
  const float* m3_w1  =(const float*)d_in[32];
  const float* m3_b1  =(const float*)d_in[33];
  const float* m3_ln_g=(const float*)d_in[34];
  const float* m3_ln_b=(const float*)d_in[35];
  const float* m3_w2  =(const float*)d_in[36];
  const float* m3_b2  =(const float*)d_in[37];
  const float* blr_bn =(const float*)d_in[38];
  const float* zc_w   =(const float*)d_in[39];
  const float* zc_b   =(const float*)d_in[40];

  float* ws=(float*)d_ws;
  float* totA=ws+0;       float* a0A=ws+16;      float* aLA=ws+32;
  float* totB=ws+48;      float* a0B=ws+304;     float* aLB=ws+560;
  float* rms =ws+816;     float* i1 =ws+820;     float* ie =ws+852;     // ie: 852..1364
  float* t1  =ws+1364;    float* te =ws+1396;    float* ffn=ws+1908;
  int*   idxp  =(int*)(ws+2932);
  int*   firstp=(int*)(ws+2964);
  int*   rankp =(int*)(ws+2980);
  int*   rowidx=(int*)(ws+3012);
  float* hid1=ws+3044;    float* hid3=ws+5092;
  unsigned short* A1p =(unsigned short*)(ws+7140);     // 131072 bf16 -> 65536 f
  unsigned short* A3p =(unsigned short*)(ws+72676);    // 1179648 bf16 -> 589824 f
  unsigned short* imgT=(unsigned short*)(ws+662500);   // 589824 bf16 -> 294912 f
  unsigned short* ie1T=(unsigned short*)(ws+957412);   // 589824 bf16 -> 294912 f
  unsigned short* W1Tp=(unsigned short*)(ws+1252324);  // 36864 bf16 -> 18432 f
  unsigned short* W2Tp=(unsigned short*)(ws+1270756);  // 73728 bf16 -> 36864 f
  float* x   =ws+1307620;                              // 589824 f -> ends 1897444
  // total ~7.6 MB

  hipMemsetAsync(ws, 0, 1364*sizeof(float), stream);       // stats + i1 + ie accumulators
  hipMemsetAsync(x, 0, 589824*sizeof(float), stream);      // f-mean accumulator

  k_rms<<<NB,256,0,stream>>>(task_f, rms);
  k_statsA<<<dim3(NB,8),256,0,stream>>>(task_f, tA_w1, totA, a0A, aLA);
  k_statsB<<<dim3(NB,32),256,0,stream>>>(task_f, rms, bv_t1, totB, a0B, aLB);
  k_imgT<<<144,256,0,stream>>>(img_f, imgT);
  k_prepW<<<(9*64*64+9*128*64+255)/256,256,0,stream>>>(bv_ic1, bv_ic2, W1Tp, W2Tp);
  k_i1<<<dim3(NB*8,9),256,0,stream>>>(img_f, iA_w, iA_bn, i1);
  k_ic1M<<<96,256,0,stream>>>(imgT, W1Tp, bv_bn1, ie1T);
  k_ic2M<<<dim3(96,2),256,0,stream>>>(ie1T, W2Tp, bv_bn2, ie);
  k_te<<<NB,256,0,stream>>>(totA,a0A,aLA,totB,a0B,aLB, tA_w2, bv_t2, t1, te);
  k_att<<<1,256,0,stream>>>(t1, i1, at_w1, at_b1, at_ln_g, at_ln_b, at_w2, at_b2, protos,
                            idxp, firstp, rankp);
  k_ff<<<1,256,0,stream>>>(te, ie, bv_w1, bv_b1, bv_ln_g, bv_ln_b, bv_w2, bv_b2, ffn);
  k_sel<<<1,256,0,stream>>>(ffn, bank, idxp, firstp, rankp, rowidx);
  k_hid<<<32,64,0,stream>>>(bank, rowidx, m1_w1, m1_b1, m1_ln_g, m1_ln_b,
                            m3_w1, m3_b1, m3_ln_g, m3_ln_b, hid1, hid3);
  k_w1headT<<<16,256,0,stream>>>(hid1, m1_w2, m1_b2, A1p);
  k_w3headT<<<144,256,0,stream>>>(hid3, m3_w2, m3_b2, A3p);
  k_dynM<<<768,256,0,stream>>>(imgT, A1p, A3p, idxp, blr_bn, x);
  k_final<<<2304,256,0,stream>>>(img_f, x, zc_w, zc_b, (float*)d_out);

  (void)in_sizes; (void)n_in; (void)out_size; (void)ws_size;
}

// Round 5
// 404.380 us; speedup vs baseline: 7.1584x; 1.3367x over previous
//
#include <hip/hip_runtime.h>
#include <math.h>

#define LEAKC 0.2f

#define NB 4
#define NC 64
#define NH 48
#define NW 48
#define LLEN 16384
#define HW 2304

typedef __attribute__((ext_vector_type(8))) short short8;
typedef __attribute__((ext_vector_type(4))) float floatx4;

__device__ __forceinline__ float leaky(float x){ return x > 0.f ? x : LEAKC*x; }

__device__ __forceinline__ float wave_sum64(float v){
  for(int off=32;off;off>>=1) v += __shfl_xor(v,off);
  return v;
}

__device__ __forceinline__ unsigned short f2bf(float x){
  unsigned u=__float_as_uint(x);
  unsigned r=u+0x7FFFu+((u>>16)&1u);
  return (unsigned short)(r>>16);
}

__device__ __forceinline__ void threefry2x32(unsigned k0, unsigned k1, unsigned& x0, unsigned& x1){
  unsigned ks0=k0, ks1=k1, ks2=k0^k1^0x1BD11BDAu;
  x0+=ks0; x1+=ks1;
  const int rot0[4]={13,15,26,6};
  const int rot1[4]={17,29,16,24};
#define TF_APPLY(rr) {for(int r=0;r<4;r++){x0+=x1; x1=(x1<<rr[r])|(x1>>(32-rr[r])); x1^=x0;}}
  TF_APPLY(rot0); x0+=ks1; x1+=ks2+1u;
  TF_APPLY(rot1); x0+=ks2; x1+=ks0+2u;
  TF_APPLY(rot0); x0+=ks0; x1+=ks1+3u;
  TF_APPLY(rot1); x0+=ks1; x1+=ks2+4u;
  TF_APPLY(rot0); x0+=ks2; x1+=ks0+5u;
#undef TF_APPLY
}

__device__ __forceinline__ float jax_uniform128(int i){
  unsigned x0=0u, x1=(unsigned)i;
  threefry2x32(0u,42u,x0,x1);
  unsigned bits = x0 ^ x1;
  unsigned fb=(bits>>9)|0x3f800000u;
  float f=__uint_as_float(fb)-1.0f;
  float u=f*(1.0f-1e-10f)+1e-10f;
  return fmaxf(1e-10f,u);
}

// ---------------- rms over task_f per b ----------------
__global__ __launch_bounds__(256) void k_rms(const float* __restrict__ task_f, float* __restrict__ rms){
  int b=blockIdx.x;
  const float* x=task_f+b*LLEN;
  float s=0;
  for(int i=threadIdx.x;i<LLEN;i+=256){ float v=x[i]; s+=v*v; }
  __shared__ float red[256];
  red[threadIdx.x]=s; __syncthreads();
  for(int off=128;off;off>>=1){ if(threadIdx.x<off) red[threadIdx.x]+=red[threadIdx.x+off]; __syncthreads(); }
  if(threadIdx.x==0) rms[b]=sqrtf(red[0]/(float)LLEN);
}

// ---------------- branch A conv1 stats (4 ch) ----------------
__global__ __launch_bounds__(256) void k_statsA(const float* __restrict__ task_f, const float* __restrict__ w1,
                         float* __restrict__ totA, float* __restrict__ a0A, float* __restrict__ aLA){
  int b=blockIdx.x, seg=blockIdx.y;
  const float* x=task_f+b*LLEN;
  float tot[4]={0,0,0,0};
  int l0=seg*2048;
  for(int l=l0+threadIdx.x;l<l0+2048;l+=256){
    float xm=(l>0)?x[l-1]:0.f;
    float xc=x[l];
    float xp=(l<LLEN-1)?x[l+1]:0.f;
#pragma unroll
    for(int c=0;c<4;c++){
      float a=leaky(w1[c*3+0]*xm + w1[c*3+1]*xc + w1[c*3+2]*xp);
      tot[c]+=a;
      if(l==0) a0A[b*4+c]=a;
      if(l==LLEN-1) aLA[b*4+c]=a;
    }
  }
#pragma unroll
  for(int c=0;c<4;c++) tot[c]=wave_sum64(tot[c]);
  __shared__ float red[4][4];
  int wave=threadIdx.x>>6, lane=threadIdx.x&63;
  if(lane==0){
#pragma unroll
    for(int c=0;c<4;c++) red[wave][c]=tot[c];
  }
  __syncthreads();
  if(threadIdx.x<4){
    float s=red[0][threadIdx.x]+red[1][threadIdx.x]+red[2][threadIdx.x]+red[3][threadIdx.x];
    atomicAdd(&totA[b*4+threadIdx.x], s);
  }
}

// ---------------- branch B conv1 stats (64 ch) ----------------
__global__ __launch_bounds__(256) void k_statsB(const float* __restrict__ task_f, const float* __restrict__ rms,
                         const float* __restrict__ w1,
                         float* __restrict__ totB, float* __restrict__ a0B, float* __restrict__ aLB){
  int b=blockIdx.x, seg=blockIdx.y;
  float sc=1.f/(rms[b]+1e-8f);
  const float* x=task_f+b*LLEN;
  float tot[64];
#pragma unroll
  for(int c=0;c<64;c++) tot[c]=0.f;
  int l0=seg*512;
  for(int l=l0+threadIdx.x;l<l0+512;l+=256){
    float xm=((l>0)?x[l-1]:0.f)*sc;
    float xc=x[l]*sc;
    float xp=((l<LLEN-1)?x[l+1]:0.f)*sc;
#pragma unroll
    for(int c=0;c<64;c++){
      float a=leaky(w1[c*3+0]*xm + w1[c*3+1]*xc + w1[c*3+2]*xp);
      tot[c]+=a;
      if(l==0) a0B[b*64+c]=a;
      if(l==LLEN-1) aLB[b*64+c]=a;
    }
  }
#pragma unroll
  for(int c=0;c<64;c++){
    float v=tot[c];
    for(int off=32;off;off>>=1) v+=__shfl_down(v,off);
    tot[c]=v;
  }
  __shared__ float red[4][64];
  int wave=threadIdx.x>>6, lane=threadIdx.x&63;
  if(lane==0){
#pragma unroll
    for(int c=0;c<64;c++) red[wave][c]=tot[c];
  }
  __syncthreads();
  if(threadIdx.x<64){
    float s=red[0][threadIdx.x]+red[1][threadIdx.x]+red[2][threadIdx.x]+red[3][threadIdx.x];
    atomicAdd(&totB[b*64+threadIdx.x], s);
  }
}

// ---------------- img -> bf16 transposed [b][px][c] ----------------
__global__ __launch_bounds__(256) void k_imgT(const float* __restrict__ img, unsigned short* __restrict__ imgT){
  int blk=blockIdx.x;
  int b=blk/36, t=blk%36;
  int p0=t*64;
  __shared__ float tile[64][65];
  int pp=threadIdx.x&63, c4=threadIdx.x>>6;
  for(int r=0;r<16;r++){
    int c=c4*16+r;
    tile[c][pp]=img[(b*64+c)*HW + p0+pp];
  }
  __syncthreads();
  int px=threadIdx.x>>2, cg=(threadIdx.x&3)*16;
  unsigned out[8];
#pragma unroll
  for(int q=0;q<8;q++){
    unsigned lo=f2bf(tile[cg+2*q][px]);
    unsigned hi=f2bf(tile[cg+2*q+1][px]);
    out[q]=lo|(hi<<16);
  }
  unsigned* dst=(unsigned*)(imgT + ((size_t)(b*HW+p0+px)*64 + cg));
#pragma unroll
  for(int q=0;q<8;q++) dst[q]=out[q];
}

// ---------------- static conv weights -> bf16 [tap][oc][c] ----------------
__global__ __launch_bounds__(256) void k_prepW(const float* __restrict__ w1, const float* __restrict__ w2,
                        const float* __restrict__ wa,
                        unsigned short* __restrict__ W1T, unsigned short* __restrict__ W2T,
                        unsigned short* __restrict__ WAT){
  int n=blockIdx.x*256+threadIdx.x;
  if(n<9*64*64){
    int tap=n>>12, oc=(n>>6)&63, c=n&63;
    W1T[n]=f2bf(w1[oc*576+c*9+tap]);
  } else if(n<9*64*64+9*128*64){
    int m=n-9*64*64;
    int tap=m/8192, r=m-tap*8192, oc=r>>6, c=r&63;
    W2T[m]=f2bf(w2[oc*576+c*9+tap]);
  } else {
    int q=n-9*64*64-9*128*64;
    if(q<9*16*64){
      int tap=q>>10, r=q&1023, o=r>>6, c=r&63;
      WAT[q]=(o<8)?f2bf(wa[o*576+c*9+tap]):(unsigned short)0;
    }
  }
}

// ---------------- iA conv via MFMA + bn + leaky + spatial mean -> i1 (B,8) ----------------
__global__ __launch_bounds__(256) void k_i1M(const unsigned short* __restrict__ imgT,
                      const unsigned short* __restrict__ WAT,
                      const float* __restrict__ bn, float* __restrict__ i1){
  int blk=blockIdx.x;
  int b=blk/6, hg=blk%6;
  int lane=threadIdx.x&63, mt=threadIdx.x>>6;
  int n0=lane&15, kg=lane>>4;
  int hp=hg*4+mt;
  int h0=hp*2;
  const unsigned short* ib=imgT+(size_t)b*HW*64;
  floatx4 acc[6];
#pragma unroll
  for(int i=0;i<6;i++) acc[i]=(floatx4){0.f,0.f,0.f,0.f};
  for(int ti=0;ti<3;ti++){
    for(int tj=0;tj<3;tj++){
      int tap=ti*3+tj;
      int dh=ti-1, dw=tj-1;
      const unsigned short* Ab=WAT+(size_t)tap*1024;
#pragma unroll
      for(int c0=0;c0<64;c0+=32){
        short8 a=*(const short8*)(Ab+(n0*64+c0+kg*8));
#pragma unroll
        for(int rr=0;rr<2;rr++){
          int r=h0+rr+dh;
          if((unsigned)r>=48u) continue;
#pragma unroll
          for(int wc=0;wc<3;wc++){
            int w=wc*16+n0+dw;
            bool inb=(unsigned)w<48u;
            short8 bv={0,0,0,0,0,0,0,0};
            if(inb) bv=*(const short8*)(ib+((size_t)(r*48+w)*64+c0+kg*8));
            acc[rr*3+wc]=__builtin_amdgcn_mfma_f32_16x16x32_bf16(a,bv,acc[rr*3+wc],0,0,0);
          }
        }
      }
    }
  }
  int obase=kg*4;
#pragma unroll
  for(int reg=0;reg<4;reg++){
    int o=obase+reg;
    float part=0;
    if(o<8){
      float scale=bn[o]/sqrtf(bn[24+o]+1e-5f);
      float m_=bn[16+o], be_=bn[8+o];
#pragma unroll
      for(int i=0;i<6;i++) part+=leaky((acc[i][reg]-m_)*scale+be_);
    }
    for(int off=1;off<16;off<<=1) part+=__shfl_xor(part,off);
    if(n0==0 && o<8) atomicAdd(&i1[b*8+o], part*(1.f/2304.f));
  }
}

// ---------------- bv_ic1 conv via MFMA -> ie1T bf16 [b][px][c] ----------------
__global__ __launch_bounds__(256) void k_ic1M(const unsigned short* __restrict__ imgT,
                       const unsigned short* __restrict__ W1T,
                       const float* __restrict__ bn, unsigned short* __restrict__ ie1T){
  int blk=blockIdx.x;
  int b=blk/24, hp=blk-b*24;
  int lane=threadIdx.x&63, mt=threadIdx.x>>6;
  int n0=lane&15, kg=lane>>4;
  int h0=hp*2;
  const unsigned short* ib=imgT+(size_t)b*HW*64;
  floatx4 acc[6];
#pragma unroll
  for(int i=0;i<6;i++) acc[i]=(floatx4){0.f,0.f,0.f,0.f};
  for(int ti=0;ti<3;ti++){
    for(int tj=0;tj<3;tj++){
      int tap=ti*3+tj;
      int dh=ti-1, dw=tj-1;
      const unsigned short* Ab=W1T+(size_t)tap*4096;
#pragma unroll
      for(int c0=0;c0<64;c0+=32){
        short8 a=*(const short8*)(Ab+((mt*16+n0)*64+c0+kg*8));
#pragma unroll
        for(int rr=0;rr<2;rr++){
          int r=h0+rr+dh;
          if((unsigned)r>=48u) continue;
#pragma unroll
          for(int wc=0;wc<3;wc++){
            int w=wc*16+n0+dw;
            bool inb=(unsigned)w<48u;
            short8 bv={0,0,0,0,0,0,0,0};
            if(inb) bv=*(const short8*)(ib+((size_t)(r*48+w)*64+c0+kg*8));
            acc[rr*3+wc]=__builtin_amdgcn_mfma_f32_16x16x32_bf16(a,bv,acc[rr*3+wc],0,0,0);
          }
        }
      }
    }
  }
  int obase=mt*16+kg*4;
  float scale[4],m_[4],be_[4];
#pragma unroll
  for(int reg=0;reg<4;reg++){
    int o=obase+reg;
    scale[reg]=bn[o]/sqrtf(bn[192+o]+1e-5f);
    m_[reg]=bn[128+o]; be_[reg]=bn[64+o];
  }
#pragma unroll
  for(int rr=0;rr<2;rr++){
#pragma unroll
    for(int wc=0;wc<3;wc++){
      int px=(h0+rr)*48+wc*16+n0;
      float v0=leaky((acc[rr*3+wc][0]-m_[0])*scale[0]+be_[0]);
      float v1=leaky((acc[rr*3+wc][1]-m_[1])*scale[1]+be_[1]);
      float v2=leaky((acc[rr*3+wc][2]-m_[2])*scale[2]+be_[2]);
      float v3=leaky((acc[rr*3+wc][3]-m_[3])*scale[3]+be_[3]);
      unsigned w0=f2bf(v0)|((unsigned)f2bf(v1)<<16);
      unsigned w1=f2bf(v2)|((unsigned)f2bf(v3)<<16);
      uint2 pk={w0,w1};
      *(uint2*)(ie1T+((size_t)(b*HW+px)*64+obase))=pk;
    }
  }
}

// ---------------- bv_ic2 conv via MFMA + bn + leaky + spatial mean -> ie (B,128) ----------------
__global__ __launch_bounds__(256) void k_ic2M(const unsigned short* __restrict__ ie1T,
                       const unsigned short* __restrict__ W2T,
                       const float* __restrict__ bn, float* __restrict__ ie){
  int blk=blockIdx.x;
  int b=blk/24, hp=blk-b*24;
  int mo=blockIdx.y*64;
  int lane=threadIdx.x&63, mt=threadIdx.x>>6;
  int n0=lane&15, kg=lane>>4;
  int h0=hp*2;
  const unsigned short* ib=ie1T+(size_t)b*HW*64;
  floatx4 acc[6];
#pragma unroll
  for(int i=0;i<6;i++) acc[i]=(floatx4){0.f,0.f,0.f,0.f};
  for(int ti=0;ti<3;ti++){
    for(int tj=0;tj<3;tj++){
      int tap=ti*3+tj;
      int dh=ti-1, dw=tj-1;
      const unsigned short* Ab=W2T+(size_t)tap*8192;
#pragma unroll
      for(int c0=0;c0<64;c0+=32){
        short8 a=*(const short8*)(Ab+((mo+mt*16+n0)*64+c0+kg*8));
#pragma unroll
        for(int rr=0;rr<2;rr++){
          int r=h0+rr+dh;
          if((unsigned)r>=48u) continue;
#pragma unroll
          for(int wc=0;wc<3;wc++){
            int w=wc*16+n0+dw;
            bool inb=(unsigned)w<48u;
            short8 bv={0,0,0,0,0,0,0,0};
            if(inb) bv=*(const short8*)(ib+((size_t)(r*48+w)*64+c0+kg*8));
            acc[rr*3+wc]=__builtin_amdgcn_mfma_f32_16x16x32_bf16(a,bv,acc[rr*3+wc],0,0,0);
          }
        }
      }
    }
  }
  int obase=mo+mt*16+kg*4;
#pragma unroll
  for(int reg=0;reg<4;reg++){
    int o=obase+reg;
    float scale=bn[o]/sqrtf(bn[384+o]+1e-5f);
    float m_=bn[256+o], be_=bn[128+o];
    float part=0;
#pragma unroll
    for(int i=0;i<6;i++) part+=leaky((acc[i][reg]-m_)*scale+be_);
    for(int off=1;off<16;off<<=1) part+=__shfl_xor(part,off);
    if(n0==0) atomicAdd(&ie[b*128+o], part*(1.f/2304.f));
  }
}

// ---------------- fused mid: te + att + ff + sel (single block) ----------------
__global__ __launch_bounds__(256) void k_mid(
    const float* __restrict__ totA, const float* __restrict__ a0A, const float* __restrict__ aLA,
    const float* __restrict__ totB, const float* __restrict__ a0B, const float* __restrict__ aLB,
    const float* __restrict__ tA_w2, const float* __restrict__ bv_t2,
    const float* __restrict__ i1, const float* __restrict__ ie,
    const float* __restrict__ at_w1, const float* __restrict__ at_b1,
    const float* __restrict__ at_ln_g, const float* __restrict__ at_ln_b,
    const float* __restrict__ at_w2, const float* __restrict__ at_b2,
    const float* __restrict__ protos,
    const float* __restrict__ bv_w1, const float* __restrict__ bv_b1,
    const float* __restrict__ bv_ln_g, const float* __restrict__ bv_ln_b,
    const float* __restrict__ bv_w2, const float* __restrict__ bv_b2,
    const float* __restrict__ bank,
    int* __restrict__ idxo, int* __restrict__ rowidx){
  __shared__ float sT[256], s0[256], sL[256];
  __shared__ float te_s[512], t1_s[32];
  __shared__ float f1[64], h[256], tif[512], tifn[512], tden[32], pden[4], pn[64], z[128];
  __shared__ int sidx[32], sfirst[16], srank[32];
  __shared__ float fbuf[1024], hh[256], ffn_s[1024], finv[4];
  __shared__ float scores[256];
  __shared__ int order[256];
  int tid=threadIdx.x;
  const float invL=1.0f/16384.0f;

  // ---- stage 1: te (B,128) + t1 (B,8) ----
  sT[tid]=totB[tid]; s0[tid]=a0B[tid]; sL[tid]=aLB[tid];
  __syncthreads();
  for(int ii=tid;ii<512;ii+=256){
    int b=ii>>7, c2=ii&127;
    const float* wr=bv_t2+c2*192;
    float s=0;
    for(int c1=0;c1<64;c1+=8){
      float4 q[6];
      const float4* r4=(const float4*)(wr+c1*3);
#pragma unroll
      for(int u=0;u<6;u++) q[u]=r4[u];
      const float* qq=(const float*)q;
#pragma unroll
      for(int u=0;u<8;u++){
        int c=c1+u;
        float T=sT[b*64+c], A0=s0[b*64+c], AL=sL[b*64+c];
        s += qq[u*3+0]*(T-AL) + qq[u*3+1]*T + qq[u*3+2]*(T-A0);
      }
    }
    te_s[ii]=s*invL;
  }
  if(tid<32){
    int b=tid>>3, c2=tid&7;
    float s=0;
    for(int c1=0;c1<4;c1++){
      float T=totA[b*4+c1], A0=a0A[b*4+c1], AL=aLA[b*4+c1];
      const float* w=&tA_w2[(c2*4+c1)*3];
      s += w[0]*(T-AL) + w[1]*T + w[2]*(T-A0);
    }
    t1_s[tid]=s*invL;
  }
  __syncthreads();

  // ---- stage 2: attention MLP -> idx/first/rank ----
  if(tid<32) f1[(tid>>3)*16+(tid&7)]=t1_s[tid];
  else if(tid<64){ int r=tid-32; f1[(r>>3)*16+8+(r&7)]=i1[r]; }
  __syncthreads();
  int b=tid>>6, j=tid&63;
  {
    float s=at_b1[j];
    for(int i=0;i<16;i++) s+=f1[b*16+i]*at_w1[i*64+j];
    float mu=wave_sum64(s)*(1.f/64.f);
    float d=s-mu;
    float var=wave_sum64(d*d)*(1.f/64.f);
    float inv=1.0f/sqrtf(var+1e-5f);
    h[tid]=fmaxf(d*inv*at_ln_g[j]+at_ln_b[j],0.f);
  }
  __syncthreads();
  for(int ii=tid;ii<512;ii+=256){
    int bb=ii>>7, n=ii&127;
    float ss=at_b2[n];
    for(int k=0;k<64;k++) ss+=h[bb*64+k]*at_w2[k*128+n];
    tif[ii]=ss;
  }
  __syncthreads();
  if(tid<32){
    int bb=tid>>3, f=tid&7;
    float ss=0; for(int e=0;e<16;e++){float v=tif[bb*128+e*8+f]; ss+=v*v;}
    tden[tid]=fmaxf(sqrtf(ss),1e-8f);
  } else if(tid<36){
    int t=tid-32;
    float ss=0; for(int e=0;e<16;e++){float v=protos[t*16+e]; ss+=v*v;}
    pden[t]=fmaxf(sqrtf(ss),1e-8f);
  }
  __syncthreads();
  for(int ii=tid;ii<512;ii+=256){
    int bb=ii>>7, n=ii&127, f=n&7;
    tifn[ii]=tif[ii]/tden[bb*8+f];
  }
  if(tid<64) pn[tid]=protos[tid]/pden[tid>>4];
  __syncthreads();
  if(tid<128){
    int bb=tid>>5, f=(tid>>2)&7, t=tid&3;
    float ss=0;
    for(int e=0;e<16;e++) ss+=pn[t*16+e]*tifn[bb*128+e*8+f];
    float u=jax_uniform128(tid);
    float g=-logf(-logf(u));
    z[tid]=ss+g;
  }
  __syncthreads();
  if(tid<32){
    float best=z[tid*4]; int bi=0;
    for(int t=1;t<4;t++){ float v=z[tid*4+t]; if(v>best){best=v;bi=t;} }
    sidx[tid]=bi;
  }
  __syncthreads();
  if(tid<16){
    int bb=tid>>2, t=tid&3;
    int fi=0;
    for(int f=7;f>=0;f--) if(sidx[bb*8+f]==t) fi=f;
    sfirst[tid]=fi;
  } else if(tid<48){
    int r=tid-16, bb=r>>3, f=r&7;
    int c=0; for(int f2=0;f2<f;f2++) if(sidx[bb*8+f2]==sidx[bb*8+f]) c++;
    srank[r]=c;
  }
  __syncthreads();

  // ---- stage 3: branch-B MLP -> normalized ff ----
  for(int ii=tid;ii<512;ii+=256){
    int bb=ii>>7, k=ii&127;
    fbuf[bb*256+k]=te_s[ii];
    fbuf[bb*256+128+k]=ie[ii];
  }
  __syncthreads();
  {
    float s=bv_b1[j];
    for(int k=0;k<256;k++) s+=fbuf[b*256+k]*bv_w1[k*64+j];
    float mu=wave_sum64(s)*(1.f/64.f);
    float d=s-mu;
    float var=wave_sum64(d*d)*(1.f/64.f);
    float inv=1.0f/sqrtf(var+1e-5f);
    hh[tid]=fmaxf(d*inv*bv_ln_g[j]+bv_ln_b[j],0.f);
  }
  __syncthreads();
  for(int ii=tid;ii<1024;ii+=256){
    int bb=ii>>8, n=ii&255;
    float ss=bv_b2[n];
    for(int k=0;k<64;k++) ss+=hh[bb*64+k]*bv_w2[k*256+n];
    ffn_s[ii]=ss;
  }
  __syncthreads();
  {
    int lane=tid&63;
    float sq=0;
#pragma unroll
    for(int u=0;u<4;u++){ float v=ffn_s[b*256+u*64+lane]; sq+=v*v; }
    sq=wave_sum64(sq);
    if(lane==0) finv[b]=1.0f/fmaxf(sqrtf(sq),1e-12f);
  }
  __syncthreads();
  for(int ii=tid;ii<1024;ii+=256) ffn_s[ii]*=finv[ii>>8];
  __syncthreads();

  // ---- stage 4: scores + argsort + selection ----
  {
    int bb=tid>>6, t=(tid>>4)&3, v=tid&15;
    int tt=sidx[bb*8+sfirst[bb*4+t]];
    const float4* row=(const float4*)(bank+(tt*16+v)*256);
    float s=0, nb=0;
    for(int d4=0;d4<64;d4++){
      float4 r=row[d4];
      const float* fb=&ffn_s[bb*256+d4*4];
      s +=fb[0]*r.x+fb[1]*r.y+fb[2]*r.z+fb[3]*r.w;
      nb+=r.x*r.x+r.y*r.y+r.z*r.z+r.w*r.w;
    }
    scores[tid]=s/fmaxf(sqrtf(nb),1e-12f);
  }
  __syncthreads();
  if(tid<16){
    const float* sc=&scores[tid*16];
    unsigned used=0;
    for(int pk=0;pk<16;pk++){
      int best=-1; float bv=-1e30f;
      for(int v2=0;v2<16;v2++){
        if(used&(1u<<v2)) continue;
        float vv=sc[v2];
        if(best<0||vv>bv){bv=vv;best=v2;}
      }
      used|=1u<<best;
      order[tid*16+pk]=best;
    }
  }
  __syncthreads();
  if(tid<32){
    int bb=tid>>3;
    int t=sidx[tid];
    int v=order[(bb*4+t)*16+srank[tid]];
    rowidx[tid]=t*16+v;
    idxo[tid]=t;
  }
}

// ---------------- m1/m3 hidden (32 blocks x 64 threads) ----------------
__global__ __launch_bounds__(64) void k_hid(const float* __restrict__ bank, const int* __restrict__ rowidx,
                     const float* __restrict__ m1_w1, const float* __restrict__ m1_b1,
                     const float* __restrict__ m1_g, const float* __restrict__ m1_b,
                     const float* __restrict__ m3_w1, const float* __restrict__ m3_b1,
                     const float* __restrict__ m3_g, const float* __restrict__ m3_b,
                     float* __restrict__ hid1, float* __restrict__ hid3){
  int bf=blockIdx.x, j=threadIdx.x;
  __shared__ float br[256];
  int ri=rowidx[bf];
  const float* row=bank+ri*256;
  for(int i=j;i<256;i+=64) br[i]=row[i];
  __syncthreads();
  {
    float s=m1_b1[j];
    for(int d=0;d<256;d++) s+=br[d]*m1_w1[d*64+j];
    float mu=wave_sum64(s)*(1.f/64.f);
    float dd=s-mu;
    float var=wave_sum64(dd*dd)*(1.f/64.f);
    float inv=1.0f/sqrtf(var+1e-5f);
    hid1[bf*64+j]=fmaxf(dd*inv*m1_g[j]+m1_b[j],0.f);
  }
  {
    float s=m3_b1[j];
    for(int d=0;d<256;d++) s+=br[d]*m3_w1[d*64+j];
    float mu=wave_sum64(s)*(1.f/64.f);
    float dd=s-mu;
    float var=wave_sum64(dd*dd)*(1.f/64.f);
    float inv=1.0f/sqrtf(var+1e-5f);
    hid3[bf*64+j]=fmaxf(dd*inv*m3_g[j]+m3_b[j],0.f);
  }
}

// ---------------- w1 head -> A1 bf16 [bf][o][c] ----------------
__global__ __launch_bounds__(256) void k_w1headT(const float* __restrict__ hid, const float* __restrict__ w2,
                          const float* __restrict__ b2, unsigned short* __restrict__ A1){
  int n=blockIdx.x*256+threadIdx.x;
  __shared__ float hl[2048];
  for(int i=threadIdx.x;i<2048;i+=256) hl[i]=hid[i];
  __syncthreads();
  float wcol[64];
#pragma unroll
  for(int k=0;k<64;k++) wcol[k]=w2[k*4096+n];
  float bb=b2[n];
  for(int bf=0;bf<32;bf++){
    float s=bb;
#pragma unroll
    for(int k=0;k<64;k++) s+=hl[bf*64+k]*wcol[k];
    A1[bf*4096+n]=f2bf(s);
  }
}

// ---------------- w3 head -> A3 bf16 [bf][tap][o][c] ----------------
__global__ __launch_bounds__(256) void k_w3headT(const float* __restrict__ hid, const float* __restrict__ w2,
                          const float* __restrict__ b2, unsigned short* __restrict__ A3){
  int n=blockIdx.x*256+threadIdx.x;
  __shared__ float hl[2048];
  for(int i=threadIdx.x;i<2048;i+=256) hl[i]=hid[i];
  __syncthreads();
  float wcol[64];
#pragma unroll
  for(int k=0;k<64;k++) wcol[k]=w2[(size_t)k*36864+n];
  float bb=b2[n];
  int o=n/576, rem=n-o*576;
  int c=rem/9, tap=rem-c*9;
  size_t base=((size_t)tap*64+o)*64+c;
  for(int bf=0;bf<32;bf++){
    float s=bb;
#pragma unroll
    for(int k=0;k<64;k++) s+=hl[bf*64+k]*wcol[k];
    A3[(size_t)bf*9*4096+base]=f2bf(s);
  }
}

// ---------------- dynamic conv via MFMA ----------------
__global__ __launch_bounds__(256) void k_dynM(const unsigned short* __restrict__ imgT,
                       const unsigned short* __restrict__ A1, const unsigned short* __restrict__ A3,
                       const int* __restrict__ idx, const float* __restrict__ bn,
                       float* __restrict__ x){
  int blk=blockIdx.x;
  int bf=blk/24, hp=blk-bf*24;
  int b=bf>>3, f=bf&7;
  int tt=idx[b*8+f];
  int lane=threadIdx.x&63, mt=threadIdx.x>>6;
  int n0=lane&15, kg=lane>>4;
  int h0=hp*2;
  const unsigned short* ib=imgT+(size_t)b*HW*64;
  floatx4 acc[6];
#pragma unroll
  for(int i=0;i<6;i++) acc[i]=(floatx4){0.f,0.f,0.f,0.f};
  if(tt==0){
    const unsigned short* Ab=A1+(size_t)bf*4096;
#pragma unroll
    for(int c0=0;c0<64;c0+=32){
      short8 a=*(const short8*)(Ab+((mt*16+n0)*64+c0+kg*8));
#pragma unroll
      for(int rr=0;rr<2;rr++){
#pragma unroll
        for(int wc=0;wc<3;wc++){
          int px=(h0+rr)*48+wc*16+n0;
          short8 bv=*(const short8*)(ib+((size_t)px*64+c0+kg*8));
          acc[rr*3+wc]=__builtin_amdgcn_mfma_f32_16x16x32_bf16(a,bv,acc[rr*3+wc],0,0,0);
        }
      }
    }
  } else {
    int d=tt;
    const unsigned short* A3b=A3+(size_t)bf*9*4096;
    for(int ti=0;ti<3;ti++){
      for(int tj=0;tj<3;tj++){
        int tap=ti*3+tj;
        int dh=d*(ti-1), dw=d*(tj-1);
        const unsigned short* Ab=A3b+(size_t)tap*4096;
#pragma unroll
        for(int c0=0;c0<64;c0+=32){
          short8 a=*(const short8*)(Ab+((mt*16+n0)*64+c0+kg*8));
#pragma unroll
          for(int rr=0;rr<2;rr++){
            int r=h0+rr+dh;
            if((unsigned)r>=48u) continue;
#pragma unroll
            for(int wc=0;wc<3;wc++){
              int w=wc*16+n0+dw;
              bool inb=(unsigned)w<48u;
              int px=r*48+w;
              short8 bv={0,0,0,0,0,0,0,0};
              if(inb) bv=*(const short8*)(ib+((size_t)px*64+c0+kg*8));
              acc[rr*3+wc]=__builtin_amdgcn_mfma_f32_16x16x32_bf16(a,bv,acc[rr*3+wc],0,0,0);
            }
          }
        }
      }
    }
  }
  int obase=mt*16+kg*4;
#pragma unroll
  for(int reg=0;reg<4;reg++){
    int o=obase+reg;
    float scale=bn[o]/sqrtf(bn[192+o]+1e-5f);
    float m_=bn[128+o], be_=bn[64+o];
#pragma unroll
    for(int rr=0;rr<2;rr++){
#pragma unroll
      for(int wc=0;wc<3;wc++){
        int px=(h0+rr)*48+wc*16+n0;
        float val=leaky((acc[rr*3+wc][reg]-m_)*scale+be_)*0.125f;
        atomicAdd(&x[((size_t)b*64+o)*HW+px],val);
      }
    }
  }
}

// ---------------- final: zc 1x1 conv + bias + residual ----------------
__global__ __launch_bounds__(256) void k_final(const float* __restrict__ img, const float* __restrict__ x,
                        const float* __restrict__ zw, const float* __restrict__ zb,
                        float* __restrict__ out){
  int t=blockIdx.x*256+threadIdx.x;
  int o=(t/HW)%64, b=t/(64*HW);
  int p2=t%HW;
  const float* xb=x+b*64*HW+p2;
  const float* wr=zw+o*64;
  float s=zb[o];
  for(int c=0;c<64;c++) s+=wr[c]*xb[c*HW];
  out[t]=s+img[t];
}

extern "C" void kernel_launch(void* const* d_in, const int* in_sizes, int n_in,
                              void* d_out, int out_size, void* d_ws, size_t ws_size,
                              hipStream_t stream){
  const float* bank   =(const float*)d_in[0];
  const float* task_f =(const float*)d_in[1];
  const float* img_f  =(const float*)d_in[2];
  const float* protos =(const float*)d_in[3];
  const float* tA_w1  =(const float*)d_in[4];
  const float* tA_w2  =(const float*)d_in[5];
  const float* iA_w   =(const float*)d_in[6];
  const float* iA_bn  =(const float*)d_in[7];
  const float* at_w1  =(const float*)d_in[8];
  const float* at_b1  =(const float*)d_in[9];
  const float* at_ln_g=(const float*)d_in[10];
  const float* at_ln_b=(const float*)d_in[11];
  const float* at_w2  =(const float*)d_in[12];
  const float* at_b2  =(const float*)d_in[13];
  const float* bv_t1  =(const float*)d_in[14];
  const float* bv_t2  =(const float*)d_in[15];
  const float* bv_ic1 =(const float*)d_in[16];
  const float* bv_bn1 =(const float*)d_in[17];
  const float* bv_ic2 =(const float*)d_in[18];
  const float* bv_bn2 =(const float*)d_in[19];
  const float* bv_w1  =(const float*)d_in[20];
  const float* bv_b1  =(const float*)d_in[21];
  const float* bv_ln_g=(const float*)d_in[22];
  const float* bv_ln_b=(const float*)d_in[23];
  const float* bv_w2  =(const float*)d_in[24];
  const float* bv_b2  =(const float*)d_in[25];
  const float* m1_w1  =(const float*)d_in[26];
  const float* m1_b1  =(const float*)d_in[27];
  const float* m1_ln_g=(const float*)d_in[28];
  const float* m1_ln_b=(const float*)d_in[29];
  const float* m1_w2  =(const float*)d_in[30];
  const float* m1_b2  =(const float*)d_in[31];
  const float* m3_w1  =(const float*)d_in[32];
  const float* m3_b1  =(const float*)d_in[33];
  const float* m3_ln_g=(const float*)d_in[34];
  const float* m3_ln_b=(const float*)d_in[35];
  const float* m3_w2  =(const float*)d_in[36];
  const float* m3_b2  =(const float*)d_in[37];
  const float* blr_bn =(const float*)d_in[38];
  const float* zc_w   =(const float*)d_in[39];
  const float* zc_b   =(const float*)d_in[40];

  float* ws=(float*)d_ws;
  float* totA=ws+0;       float* a0A=ws+16;      float* aLA=ws+32;
  float* totB=ws+48;      float* a0B=ws+304;     float* aLB=ws+560;
  float* rms =ws+816;     float* i1 =ws+820;     float* ie =ws+852;     // ie: 852..1364
  int*   idxp  =(int*)(ws+2932);
  int*   rowidx=(int*)(ws+3012);
  float* hid1=ws+3044;    float* hid3=ws+5092;
  unsigned short* A1p =(unsigned short*)(ws+7140);     // 131072 bf16
  unsigned short* A3p =(unsigned short*)(ws+72676);    // 1179648 bf16
  unsigned short* imgT=(unsigned short*)(ws+662500);   // 589824 bf16
  unsigned short* ie1T=(unsigned short*)(ws+957412);   // 589824 bf16
  unsigned short* W1Tp=(unsigned short*)(ws+1252324);  // 36864 bf16
  unsigned short* W2Tp=(unsigned short*)(ws+1270756);  // 73728 bf16
  unsigned short* WATp=(unsigned short*)(ws+1307620);  // 9216 bf16 -> 4608 f
  float* x   =ws+1312228;                              // 589824 f -> ends 1902052
  // total ~7.6 MB

  hipMemsetAsync(ws, 0, 1364*sizeof(float), stream);       // stats + i1 + ie accumulators
  hipMemsetAsync(x, 0, 589824*sizeof(float), stream);      // f-mean accumulator

  k_rms<<<NB,256,0,stream>>>(task_f, rms);
  k_statsA<<<dim3(NB,8),256,0,stream>>>(task_f, tA_w1, totA, a0A, aLA);
  k_statsB<<<dim3(NB,32),256,0,stream>>>(task_f, rms, bv_t1, totB, a0B, aLB);
  k_imgT<<<144,256,0,stream>>>(img_f, imgT);
  k_prepW<<<(9*64*64+9*128*64+9*16*64+255)/256,256,0,stream>>>(bv_ic1, bv_ic2, iA_w, W1Tp, W2Tp, WATp);
  k_i1M<<<24,256,0,stream>>>(imgT, WATp, iA_bn, i1);
  k_ic1M<<<96,256,0,stream>>>(imgT, W1Tp, bv_bn1, ie1T);
  k_ic2M<<<dim3(96,2),256,0,stream>>>(ie1T, W2Tp, bv_bn2, ie);
  k_mid<<<1,256,0,stream>>>(totA,a0A,aLA,totB,a0B,aLB, tA_w2, bv_t2, i1, ie,
                            at_w1, at_b1, at_ln_g, at_ln_b, at_w2, at_b2, protos,
                            bv_w1, bv_b1, bv_ln_g, bv_ln_b, bv_w2, bv_b2, bank,
                            idxp, rowidx);
  k_hid<<<32,64,0,stream>>>(bank, rowidx, m1_w1, m1_b1, m1_ln_g, m1_ln_b,
                            m3_w1, m3_b1, m3_ln_g, m3_ln_b, hid1, hid3);
  k_w1headT<<<16,256,0,stream>>>(hid1, m1_w2, m1_b2, A1p);
  k_w3headT<<<144,256,0,stream>>>(hid3, m3_w2, m3_b2, A3p);
  k_dynM<<<768,256,0,stream>>>(imgT, A1p, A3p, idxp, blr_bn, x);
  k_final<<<2304,256,0,stream>>>(img_f, x, zc_w, zc_b, (float*)d_out);

  (void)in_sizes; (void)n_in; (void)out_size; (void)ws_size;
}

// Round 6
// 401.199 us; speedup vs baseline: 7.2152x; 1.0079x over previous
//
#include <hip/hip_runtime.h>
#include <math.h>

#define LEAKC 0.2f

#define NB 4
#define NC 64
#define LLEN 16384
#define HW 2304

typedef __attribute__((ext_vector_type(8))) short short8;
typedef __attribute__((ext_vector_type(4))) float floatx4;

__device__ __forceinline__ float leaky(float x){ return x > 0.f ? x : LEAKC*x; }

__device__ __forceinline__ float wave_sum64(float v){
  for(int off=32;off;off>>=1) v += __shfl_xor(v,off);
  return v;
}

__device__ __forceinline__ unsigned short f2bf(float x){
  unsigned u=__float_as_uint(x);
  unsigned r=u+0x7FFFu+((u>>16)&1u);
  return (unsigned short)(r>>16);
}

__device__ __forceinline__ void threefry2x32(unsigned k0, unsigned k1, unsigned& x0, unsigned& x1){
  unsigned ks0=k0, ks1=k1, ks2=k0^k1^0x1BD11BDAu;
  x0+=ks0; x1+=ks1;
  const int rot0[4]={13,15,26,6};
  const int rot1[4]={17,29,16,24};
#define TF_APPLY(rr) {for(int r=0;r<4;r++){x0+=x1; x1=(x1<<rr[r])|(x1>>(32-rr[r])); x1^=x0;}}
  TF_APPLY(rot0); x0+=ks1; x1+=ks2+1u;
  TF_APPLY(rot1); x0+=ks2; x1+=ks0+2u;
  TF_APPLY(rot0); x0+=ks0; x1+=ks1+3u;
  TF_APPLY(rot1); x0+=ks1; x1+=ks2+4u;
  TF_APPLY(rot0); x0+=ks2; x1+=ks0+5u;
#undef TF_APPLY
}

__device__ __forceinline__ float jax_uniform128(int i){
  unsigned x0=0u, x1=(unsigned)i;
  threefry2x32(0u,42u,x0,x1);
  unsigned bits = x0 ^ x1;
  unsigned fb=(bits>>9)|0x3f800000u;
  float f=__uint_as_float(fb)-1.0f;
  float u=f*(1.0f-1e-10f)+1e-10f;
  return fmaxf(1e-10f,u);
}

// ---------------- single-pass task_f stats: sumsq + branchA(4ch) + branchB(64ch raw) ----------------
__global__ __launch_bounds__(256) void k_stats(const float* __restrict__ task_f,
                        const float* __restrict__ w1A, const float* __restrict__ w1B,
                        float* __restrict__ totA, float* __restrict__ a0A, float* __restrict__ aLA,
                        float* __restrict__ totB, float* __restrict__ a0B, float* __restrict__ aLB,
                        float* __restrict__ rmsacc){
  int b=blockIdx.x, seg=blockIdx.y;
  const float* x=task_f+b*LLEN;
  float tA[4]={0,0,0,0};
  float tB[64];
#pragma unroll
  for(int c=0;c<64;c++) tB[c]=0.f;
  float sq=0.f;
  int l0=seg*512;
  for(int l=l0+threadIdx.x;l<l0+512;l+=256){
    float xm=(l>0)?x[l-1]:0.f;
    float xc=x[l];
    float xp=(l<LLEN-1)?x[l+1]:0.f;
    sq+=xc*xc;
#pragma unroll
    for(int c=0;c<4;c++){
      float a=leaky(w1A[c*3+0]*xm + w1A[c*3+1]*xc + w1A[c*3+2]*xp);
      tA[c]+=a;
      if(l==0) a0A[b*4+c]=a;
      if(l==LLEN-1) aLA[b*4+c]=a;
    }
#pragma unroll
    for(int c=0;c<64;c++){
      float a=leaky(w1B[c*3+0]*xm + w1B[c*3+1]*xc + w1B[c*3+2]*xp);
      tB[c]+=a;
      if(l==0) a0B[b*64+c]=a;
      if(l==LLEN-1) aLB[b*64+c]=a;
    }
  }
  sq=wave_sum64(sq);
#pragma unroll
  for(int c=0;c<4;c++) tA[c]=wave_sum64(tA[c]);
#pragma unroll
  for(int c=0;c<64;c++){
    float v=tB[c];
    for(int off=32;off;off>>=1) v+=__shfl_down(v,off);
    tB[c]=v;
  }
  __shared__ float redB[4][64];
  __shared__ float redA[4][4];
  __shared__ float redQ[4];
  int wave=threadIdx.x>>6, lane=threadIdx.x&63;
  if(lane==0){
#pragma unroll
    for(int c=0;c<64;c++) redB[wave][c]=tB[c];
#pragma unroll
    for(int c=0;c<4;c++) redA[wave][c]=tA[c];
    redQ[wave]=sq;
  }
  __syncthreads();
  if(threadIdx.x<64){
    float s=redB[0][threadIdx.x]+redB[1][threadIdx.x]+redB[2][threadIdx.x]+redB[3][threadIdx.x];
    atomicAdd(&totB[b*64+threadIdx.x], s);
  } else if(threadIdx.x<68){
    int c=threadIdx.x-64;
    float s=redA[0][c]+redA[1][c]+redA[2][c]+redA[3][c];
    atomicAdd(&totA[b*4+c], s);
  } else if(threadIdx.x==68){
    atomicAdd(&rmsacc[b], redQ[0]+redQ[1]+redQ[2]+redQ[3]);
  }
}

// ---------------- k_pre: imgT transpose (blocks 0..143) + static weight prep (144..611) ----------------
__global__ __launch_bounds__(256) void k_pre(const float* __restrict__ img,
                      const float* __restrict__ w1, const float* __restrict__ w2,
                      const float* __restrict__ wa,
                      unsigned short* __restrict__ imgT,
                      unsigned short* __restrict__ W1T, unsigned short* __restrict__ W2T,
                      unsigned short* __restrict__ WAT){
  if(blockIdx.x<144){
    int blk=blockIdx.x;
    int b=blk/36, t=blk%36;
    int p0=t*64;
    __shared__ float tile[64][65];
    int pp=threadIdx.x&63, c4=threadIdx.x>>6;
    for(int r=0;r<16;r++){
      int c=c4*16+r;
      tile[c][pp]=img[(b*64+c)*HW + p0+pp];
    }
    __syncthreads();
    int px=threadIdx.x>>2, cg=(threadIdx.x&3)*16;
    unsigned out[8];
#pragma unroll
    for(int q=0;q<8;q++){
      unsigned lo=f2bf(tile[cg+2*q][px]);
      unsigned hi=f2bf(tile[cg+2*q+1][px]);
      out[q]=lo|(hi<<16);
    }
    unsigned* dst=(unsigned*)(imgT + ((size_t)(b*HW+p0+px)*64 + cg));
#pragma unroll
    for(int q=0;q<8;q++) dst[q]=out[q];
  } else {
    int n=(blockIdx.x-144)*256+threadIdx.x;
    if(n<9*64*64){
      int tap=n>>12, oc=(n>>6)&63, c=n&63;
      W1T[n]=f2bf(w1[oc*576+c*9+tap]);
    } else if(n<9*64*64+9*128*64){
      int m=n-9*64*64;
      int tap=m/8192, r=m-tap*8192, oc=r>>6, c=r&63;
      W2T[m]=f2bf(w2[oc*576+c*9+tap]);
    } else {
      int q=n-9*64*64-9*128*64;
      if(q<9*16*64){
        int tap=q>>10, r=q&1023, o=r>>6, c=r&63;
        WAT[q]=(o<8)?f2bf(wa[o*576+c*9+tap]):(unsigned short)0;
      }
    }
  }
}

// ---------------- k_conv1: ic1 MFMA (blocks 0..95) + iA MFMA mean (96..119) ----------------
__global__ __launch_bounds__(256) void k_conv1(const unsigned short* __restrict__ imgT,
                        const unsigned short* __restrict__ W1T,
                        const unsigned short* __restrict__ WAT,
                        const float* __restrict__ bn1, const float* __restrict__ bnA,
                        unsigned short* __restrict__ ie1T, float* __restrict__ i1){
  int lane=threadIdx.x&63, mt=threadIdx.x>>6;
  int n0=lane&15, kg=lane>>4;
  if(blockIdx.x<96){
    int blk=blockIdx.x;
    int b=blk/24, hp=blk-b*24;
    int h0=hp*2;
    const unsigned short* ib=imgT+(size_t)b*HW*64;
    floatx4 acc[6];
#pragma unroll
    for(int i=0;i<6;i++) acc[i]=(floatx4){0.f,0.f,0.f,0.f};
    for(int ti=0;ti<3;ti++){
      for(int tj=0;tj<3;tj++){
        int tap=ti*3+tj;
        int dh=ti-1, dw=tj-1;
        const unsigned short* Ab=W1T+(size_t)tap*4096;
#pragma unroll
        for(int c0=0;c0<64;c0+=32){
          short8 a=*(const short8*)(Ab+((mt*16+n0)*64+c0+kg*8));
#pragma unroll
          for(int rr=0;rr<2;rr++){
            int r=h0+rr+dh;
            if((unsigned)r>=48u) continue;
#pragma unroll
            for(int wc=0;wc<3;wc++){
              int w=wc*16+n0+dw;
              bool inb=(unsigned)w<48u;
              short8 bv={0,0,0,0,0,0,0,0};
              if(inb) bv=*(const short8*)(ib+((size_t)(r*48+w)*64+c0+kg*8));
              acc[rr*3+wc]=__builtin_amdgcn_mfma_f32_16x16x32_bf16(a,bv,acc[rr*3+wc],0,0,0);
            }
          }
        }
      }
    }
    int obase=mt*16+kg*4;
    float scale[4],m_[4],be_[4];
#pragma unroll
    for(int reg=0;reg<4;reg++){
      int o=obase+reg;
      scale[reg]=bn1[o]/sqrtf(bn1[192+o]+1e-5f);
      m_[reg]=bn1[128+o]; be_[reg]=bn1[64+o];
    }
#pragma unroll
    for(int rr=0;rr<2;rr++){
#pragma unroll
      for(int wc=0;wc<3;wc++){
        int px=(h0+rr)*48+wc*16+n0;
        float v0=leaky((acc[rr*3+wc][0]-m_[0])*scale[0]+be_[0]);
        float v1=leaky((acc[rr*3+wc][1]-m_[1])*scale[1]+be_[1]);
        float v2=leaky((acc[rr*3+wc][2]-m_[2])*scale[2]+be_[2]);
        float v3=leaky((acc[rr*3+wc][3]-m_[3])*scale[3]+be_[3]);
        unsigned w0=f2bf(v0)|((unsigned)f2bf(v1)<<16);
        unsigned w1=f2bf(v2)|((unsigned)f2bf(v3)<<16);
        uint2 pk={w0,w1};
        *(uint2*)(ie1T+((size_t)(b*HW+px)*64+obase))=pk;
      }
    }
  } else {
    int blk=blockIdx.x-96;
    int b=blk/6, hg=blk%6;
    int hp=hg*4+mt;
    int h0=hp*2;
    const unsigned short* ib=imgT+(size_t)b*HW*64;
    floatx4 acc[6];
#pragma unroll
    for(int i=0;i<6;i++) acc[i]=(floatx4){0.f,0.f,0.f,0.f};
    for(int ti=0;ti<3;ti++){
      for(int tj=0;tj<3;tj++){
        int tap=ti*3+tj;
        int dh=ti-1, dw=tj-1;
        const unsigned short* Ab=WAT+(size_t)tap*1024;
#pragma unroll
        for(int c0=0;c0<64;c0+=32){
          short8 a=*(const short8*)(Ab+(n0*64+c0+kg*8));
#pragma unroll
          for(int rr=0;rr<2;rr++){
            int r=h0+rr+dh;
            if((unsigned)r>=48u) continue;
#pragma unroll
            for(int wc=0;wc<3;wc++){
              int w=wc*16+n0+dw;
              bool inb=(unsigned)w<48u;
              short8 bv={0,0,0,0,0,0,0,0};
              if(inb) bv=*(const short8*)(ib+((size_t)(r*48+w)*64+c0+kg*8));
              acc[rr*3+wc]=__builtin_amdgcn_mfma_f32_16x16x32_bf16(a,bv,acc[rr*3+wc],0,0,0);
            }
          }
        }
      }
    }
    int obase=kg*4;
#pragma unroll
    for(int reg=0;reg<4;reg++){
      int o=obase+reg;
      float part=0;
      if(o<8){
        float scale=bnA[o]/sqrtf(bnA[24+o]+1e-5f);
        float m_=bnA[16+o], be_=bnA[8+o];
#pragma unroll
        for(int i=0;i<6;i++) part+=leaky((acc[i][reg]-m_)*scale+be_);
      }
      for(int off=1;off<16;off<<=1) part+=__shfl_xor(part,off);
      if(n0==0 && o<8) atomicAdd(&i1[b*8+o], part*(1.f/2304.f));
    }
  }
}

// ---------------- bv_ic2 conv via MFMA + bn + leaky + spatial mean -> ie (B,128) ----------------
__global__ __launch_bounds__(256) void k_ic2M(const unsigned short* __restrict__ ie1T,
                       const unsigned short* __restrict__ W2T,
                       const float* __restrict__ bn, float* __restrict__ ie){
  int blk=blockIdx.x;
  int b=blk/24, hp=blk-b*24;
  int mo=blockIdx.y*64;
  int lane=threadIdx.x&63, mt=threadIdx.x>>6;
  int n0=lane&15, kg=lane>>4;
  int h0=hp*2;
  const unsigned short* ib=ie1T+(size_t)b*HW*64;
  floatx4 acc[6];
#pragma unroll
  for(int i=0;i<6;i++) acc[i]=(floatx4){0.f,0.f,0.f,0.f};
  for(int ti=0;ti<3;ti++){
    for(int tj=0;tj<3;tj++){
      int tap=ti*3+tj;
      int dh=ti-1, dw=tj-1;
      const unsigned short* Ab=W2T+(size_t)tap*8192;
#pragma unroll
      for(int c0=0;c0<64;c0+=32){
        short8 a=*(const short8*)(Ab+((mo+mt*16+n0)*64+c0+kg*8));
#pragma unroll
        for(int rr=0;rr<2;rr++){
          int r=h0+rr+dh;
          if((unsigned)r>=48u) continue;
#pragma unroll
          for(int wc=0;wc<3;wc++){
            int w=wc*16+n0+dw;
            bool inb=(unsigned)w<48u;
            short8 bv={0,0,0,0,0,0,0,0};
            if(inb) bv=*(const short8*)(ib+((size_t)(r*48+w)*64+c0+kg*8));
            acc[rr*3+wc]=__builtin_amdgcn_mfma_f32_16x16x32_bf16(a,bv,acc[rr*3+wc],0,0,0);
          }
        }
      }
    }
  }
  int obase=mo+mt*16+kg*4;
#pragma unroll
  for(int reg=0;reg<4;reg++){
    int o=obase+reg;
    float scale=bn[o]/sqrtf(bn[384+o]+1e-5f);
    float m_=bn[256+o], be_=bn[128+o];
    float part=0;
#pragma unroll
    for(int i=0;i<6;i++) part+=leaky((acc[i][reg]-m_)*scale+be_);
    for(int off=1;off<16;off<<=1) part+=__shfl_xor(part,off);
    if(n0==0) atomicAdd(&ie[b*128+o], part*(1.f/2304.f));
  }
}

// ---------------- fused mid: te + att + ff + sel + m1/m3 hidden (single block) ----------------
__global__ __launch_bounds__(256) void k_mid(
    const float* __restrict__ totA, const float* __restrict__ a0A, const float* __restrict__ aLA,
    const float* __restrict__ totB, const float* __restrict__ a0B, const float* __restrict__ aLB,
    const float* __restrict__ rmsacc,
    const float* __restrict__ tA_w2, const float* __restrict__ bv_t2,
    const float* __restrict__ i1, const float* __restrict__ ie,
    const float* __restrict__ at_w1, const float* __restrict__ at_b1,
    const float* __restrict__ at_ln_g, const float* __restrict__ at_ln_b,
    const float* __restrict__ at_w2, const float* __restrict__ at_b2,
    const float* __restrict__ protos,
    const float* __restrict__ bv_w1, const float* __restrict__ bv_b1,
    const float* __restrict__ bv_ln_g, const float* __restrict__ bv_ln_b,
    const float* __restrict__ bv_w2, const float* __restrict__ bv_b2,
    const float* __restrict__ bank,
    const float* __restrict__ m1_w1, const float* __restrict__ m1_b1,
    const float* __restrict__ m1_g,  const float* __restrict__ m1_bb,
    const float* __restrict__ m3_w1, const float* __restrict__ m3_b1,
    const float* __restrict__ m3_g,  const float* __restrict__ m3_bb,
    int* __restrict__ idxo, float* __restrict__ hid1, float* __restrict__ hid3){
  __shared__ float sT[256], s0[256], sL[256];
  __shared__ float te_s[512], t1_s[32];
  __shared__ float f1[64], h[256], tif[512], tifn[512], tden[32], pden[4], pn[64], z[128];
  __shared__ int sidx[32], sfirst[16], srank[32], rows[32];
  __shared__ float fbuf[1024], hh[256], ffn_s[1024], finv[4];
  __shared__ float scores[256];
  __shared__ int order[256];
  __shared__ float bvf[8192];
  int tid=threadIdx.x;
  const float invL=1.0f/16384.0f;

  // ---- stage 1: te (B,128) + t1 (B,8); rms scale applied here (leaky pos-homogeneous) ----
  sT[tid]=totB[tid]; s0[tid]=a0B[tid]; sL[tid]=aLB[tid];
  __syncthreads();
  for(int ii=tid;ii<512;ii+=256){
    int b=ii>>7, c2=ii&127;
    float sc=1.0f/(sqrtf(rmsacc[b]*invL)+1e-8f);
    const float* wr=bv_t2+c2*192;
    float s=0;
    for(int c1=0;c1<64;c1+=8){
      float4 q[6];
      const float4* r4=(const float4*)(wr+c1*3);
#pragma unroll
      for(int u=0;u<6;u++) q[u]=r4[u];
      const float* qq=(const float*)q;
#pragma unroll
      for(int u=0;u<8;u++){
        int c=c1+u;
        float T=sT[b*64+c], A0=s0[b*64+c], AL=sL[b*64+c];
        s += qq[u*3+0]*(T-AL) + qq[u*3+1]*T + qq[u*3+2]*(T-A0);
      }
    }
    te_s[ii]=s*invL*sc;
  }
  if(tid<32){
    int b=tid>>3, c2=tid&7;
    float s=0;
    for(int c1=0;c1<4;c1++){
      float T=totA[b*4+c1], A0=a0A[b*4+c1], AL=aLA[b*4+c1];
      const float* w=&tA_w2[(c2*4+c1)*3];
      s += w[0]*(T-AL) + w[1]*T + w[2]*(T-A0);
    }
    t1_s[tid]=s*invL;
  }
  __syncthreads();

  // ---- stage 2: attention MLP -> idx/first/rank ----
  if(tid<32) f1[(tid>>3)*16+(tid&7)]=t1_s[tid];
  else if(tid<64){ int r=tid-32; f1[(r>>3)*16+8+(r&7)]=i1[r]; }
  __syncthreads();
  int b=tid>>6, j=tid&63;
  {
    float s=at_b1[j];
    for(int i=0;i<16;i++) s+=f1[b*16+i]*at_w1[i*64+j];
    float mu=wave_sum64(s)*(1.f/64.f);
    float d=s-mu;
    float var=wave_sum64(d*d)*(1.f/64.f);
    float inv=1.0f/sqrtf(var+1e-5f);
    h[tid]=fmaxf(d*inv*at_ln_g[j]+at_ln_b[j],0.f);
  }
  __syncthreads();
  for(int ii=tid;ii<512;ii+=256){
    int bb=ii>>7, n=ii&127;
    float ss=at_b2[n];
    for(int k=0;k<64;k++) ss+=h[bb*64+k]*at_w2[k*128+n];
    tif[ii]=ss;
  }
  __syncthreads();
  if(tid<32){
    int bb=tid>>3, f=tid&7;
    float ss=0; for(int e=0;e<16;e++){float v=tif[bb*128+e*8+f]; ss+=v*v;}
    tden[tid]=fmaxf(sqrtf(ss),1e-8f);
  } else if(tid<36){
    int t=tid-32;
    float ss=0; for(int e=0;e<16;e++){float v=protos[t*16+e]; ss+=v*v;}
    pden[t]=fmaxf(sqrtf(ss),1e-8f);
  }
  __syncthreads();
  for(int ii=tid;ii<512;ii+=256){
    int bb=ii>>7, n=ii&127, f=n&7;
    tifn[ii]=tif[ii]/tden[bb*8+f];
  }
  if(tid<64) pn[tid]=protos[tid]/pden[tid>>4];
  __syncthreads();
  if(tid<128){
    int bb=tid>>5, f=(tid>>2)&7, t=tid&3;
    float ss=0;
    for(int e=0;e<16;e++) ss+=pn[t*16+e]*tifn[bb*128+e*8+f];
    float u=jax_uniform128(tid);
    float g=-logf(-logf(u));
    z[tid]=ss+g;
  }
  __syncthreads();
  if(tid<32){
    float best=z[tid*4]; int bi=0;
    for(int t=1;t<4;t++){ float v=z[tid*4+t]; if(v>best){best=v;bi=t;} }
    sidx[tid]=bi;
  }
  __syncthreads();
  if(tid<16){
    int bb=tid>>2, t=tid&3;
    int fi=0;
    for(int f=7;f>=0;f--) if(sidx[bb*8+f]==t) fi=f;
    sfirst[tid]=fi;
  } else if(tid<48){
    int r=tid-16, bb=r>>3, f=r&7;
    int c=0; for(int f2=0;f2<f;f2++) if(sidx[bb*8+f2]==sidx[bb*8+f]) c++;
    srank[r]=c;
  }
  __syncthreads();

  // ---- stage 3: branch-B MLP -> normalized ff ----
  for(int ii=tid;ii<512;ii+=256){
    int bb=ii>>7, k=ii&127;
    fbuf[bb*256+k]=te_s[ii];
    fbuf[bb*256+128+k]=ie[ii];
  }
  __syncthreads();
  {
    float s=bv_b1[j];
    for(int k=0;k<256;k++) s+=fbuf[b*256+k]*bv_w1[k*64+j];
    float mu=wave_sum64(s)*(1.f/64.f);
    float d=s-mu;
    float var=wave_sum64(d*d)*(1.f/64.f);
    float inv=1.0f/sqrtf(var+1e-5f);
    hh[tid]=fmaxf(d*inv*bv_ln_g[j]+bv_ln_b[j],0.f);
  }
  __syncthreads();
  for(int ii=tid;ii<1024;ii+=256){
    int bb=ii>>8, n=ii&255;
    float ss=bv_b2[n];
    for(int k=0;k<64;k++) ss+=hh[bb*64+k]*bv_w2[k*256+n];
    ffn_s[ii]=ss;
  }
  __syncthreads();
  {
    int lane=tid&63;
    float sq=0;
#pragma unroll
    for(int u=0;u<4;u++){ float v=ffn_s[b*256+u*64+lane]; sq+=v*v; }
    sq=wave_sum64(sq);
    if(lane==0) finv[b]=1.0f/fmaxf(sqrtf(sq),1e-12f);
  }
  __syncthreads();
  for(int ii=tid;ii<1024;ii+=256) ffn_s[ii]*=finv[ii>>8];
  __syncthreads();

  // ---- stage 4: scores + argsort + selection ----
  {
    int bb=tid>>6, t=(tid>>4)&3, v=tid&15;
    int tt=sidx[bb*8+sfirst[bb*4+t]];
    const float4* row=(const float4*)(bank+(tt*16+v)*256);
    float s=0, nb=0;
    for(int d4=0;d4<64;d4++){
      float4 r=row[d4];
      const float* fb=&ffn_s[bb*256+d4*4];
      s +=fb[0]*r.x+fb[1]*r.y+fb[2]*r.z+fb[3]*r.w;
      nb+=r.x*r.x+r.y*r.y+r.z*r.z+r.w*r.w;
    }
    scores[tid]=s/fmaxf(sqrtf(nb),1e-12f);
  }
  __syncthreads();
  if(tid<16){
    const float* sc=&scores[tid*16];
    unsigned used=0;
    for(int pk=0;pk<16;pk++){
      int best=-1; float bv=-1e30f;
      for(int v2=0;v2<16;v2++){
        if(used&(1u<<v2)) continue;
        float vv=sc[v2];
        if(best<0||vv>bv){bv=vv;best=v2;}
      }
      used|=1u<<best;
      order[tid*16+pk]=best;
    }
  }
  __syncthreads();
  if(tid<32){
    int bb=tid>>3;
    int t=sidx[tid];
    int v=order[(bb*4+t)*16+srank[tid]];
    rows[tid]=t*16+v;
    idxo[tid]=t;
  }
  __syncthreads();

  // ---- stage 5: gather bank rows + m1/m3 hidden (register LN via wave reduce) ----
  for(int ii=tid;ii<8192;ii+=256){
    int r=ii>>8, d=ii&255;
    bvf[ii]=bank[rows[r]*256+d];
  }
  __syncthreads();
  {
    int lane=tid&63, wv=tid>>6;
    for(int it=0;it<8;it++){
      int r=wv*8+it;
      float s1=m1_b1[lane], s3=m3_b1[lane];
      for(int d=0;d<256;d++){
        float bvv=bvf[r*256+d];
        s1+=bvv*m1_w1[d*64+lane];
        s3+=bvv*m3_w1[d*64+lane];
      }
      float mu=wave_sum64(s1)*(1.f/64.f);
      float dd=s1-mu;
      float var=wave_sum64(dd*dd)*(1.f/64.f);
      hid1[r*64+lane]=fmaxf(dd*(1.0f/sqrtf(var+1e-5f))*m1_g[lane]+m1_bb[lane],0.f);
      mu=wave_sum64(s3)*(1.f/64.f);
      dd=s3-mu;
      var=wave_sum64(dd*dd)*(1.f/64.f);
      hid3[r*64+lane]=fmaxf(dd*(1.0f/sqrtf(var+1e-5f))*m3_g[lane]+m3_bb[lane],0.f);
    }
  }
}

// ---------------- k_heads: w1 head (blocks 0..15) + w3 head (16..159) ----------------
__global__ __launch_bounds__(256) void k_heads(const float* __restrict__ hid1, const float* __restrict__ hid3,
                        const float* __restrict__ w2a, const float* __restrict__ b2a,
                        const float* __restrict__ w2b, const float* __restrict__ b2b,
                        unsigned short* __restrict__ A1, unsigned short* __restrict__ A3){
  __shared__ float hl[2048];
  if(blockIdx.x<16){
    int n=blockIdx.x*256+threadIdx.x;
    for(int i=threadIdx.x;i<2048;i+=256) hl[i]=hid1[i];
    __syncthreads();
    float wcol[64];
#pragma unroll
    for(int k=0;k<64;k++) wcol[k]=w2a[k*4096+n];
    float bb=b2a[n];
    for(int bf=0;bf<32;bf++){
      float s=bb;
#pragma unroll
      for(int k=0;k<64;k++) s+=hl[bf*64+k]*wcol[k];
      A1[bf*4096+n]=f2bf(s);
    }
  } else {
    int n=(blockIdx.x-16)*256+threadIdx.x;
    for(int i=threadIdx.x;i<2048;i+=256) hl[i]=hid3[i];
    __syncthreads();
    float wcol[64];
#pragma unroll
    for(int k=0;k<64;k++) wcol[k]=w2b[(size_t)k*36864+n];
    float bb=b2b[n];
    int o=n/576, rem=n-o*576;
    int c=rem/9, tap=rem-c*9;
    size_t base=((size_t)tap*64+o)*64+c;
    for(int bf=0;bf<32;bf++){
      float s=bb;
#pragma unroll
      for(int k=0;k<64;k++) s+=hl[bf*64+k]*wcol[k];
      A3[(size_t)bf*9*4096+base]=f2bf(s);
    }
  }
}

// ---------------- fused dynamic conv: f-loop in-block + bn + leaky + f-mean + zc 1x1 + residual ----------------
__global__ __launch_bounds__(256) void k_dynF(const unsigned short* __restrict__ imgT,
                       const unsigned short* __restrict__ A1, const unsigned short* __restrict__ A3,
                       const int* __restrict__ idx, const float* __restrict__ bn,
                       const float* __restrict__ zc_w, const float* __restrict__ zc_b,
                       const float* __restrict__ img, float* __restrict__ out){
  int blk=blockIdx.x;
  int b=blk/48, r0=blk-b*48;
  int lane=threadIdx.x&63, mt=threadIdx.x>>6;
  int n0=lane&15, kg=lane>>4;
  __shared__ float xl[64*49];     // [c][px], stride 49 (2-way max conflicts)
  __shared__ float zl[4096];      // zc_w staged
  for(int i=threadIdx.x;i<4096;i+=256) zl[i]=zc_w[i];
  const unsigned short* ib=imgT+(size_t)b*HW*64;
  int obase=mt*16+kg*4;
  float scale[4],m_[4],be_[4];
#pragma unroll
  for(int reg=0;reg<4;reg++){
    int o=obase+reg;
    scale[reg]=bn[o]/sqrtf(bn[192+o]+1e-5f);
    m_[reg]=bn[128+o]; be_[reg]=bn[64+o];
  }
  float xsum[3][4];
#pragma unroll
  for(int wc=0;wc<3;wc++)
#pragma unroll
    for(int reg=0;reg<4;reg++) xsum[wc][reg]=0.f;
  for(int f=0;f<8;f++){
    int bf=b*8+f;
    int tt=idx[bf];
    floatx4 acc[3];
#pragma unroll
    for(int i=0;i<3;i++) acc[i]=(floatx4){0.f,0.f,0.f,0.f};
    if(tt==0){
      const unsigned short* Ab=A1+(size_t)bf*4096;
#pragma unroll
      for(int c0=0;c0<64;c0+=32){
        short8 a=*(const short8*)(Ab+((mt*16+n0)*64+c0+kg*8));
#pragma unroll
        for(int wc=0;wc<3;wc++){
          int px=r0*48+wc*16+n0;
          short8 bv=*(const short8*)(ib+((size_t)px*64+c0+kg*8));
          acc[wc]=__builtin_amdgcn_mfma_f32_16x16x32_bf16(a,bv,acc[wc],0,0,0);
        }
      }
    } else {
      int d=tt;
      const unsigned short* A3b=A3+(size_t)bf*9*4096;
      for(int ti=0;ti<3;ti++){
        int r=r0+d*(ti-1);
        if((unsigned)r>=48u) continue;
        for(int tj=0;tj<3;tj++){
          int tap=ti*3+tj;
          int dw=d*(tj-1);
          const unsigned short* Ab=A3b+(size_t)tap*4096;
#pragma unroll
          for(int c0=0;c0<64;c0+=32){
            short8 a=*(const short8*)(Ab+((mt*16+n0)*64+c0+kg*8));
#pragma unroll
            for(int wc=0;wc<3;wc++){
              int w=wc*16+n0+dw;
              bool inb=(unsigned)w<48u;
              short8 bv={0,0,0,0,0,0,0,0};
              if(inb) bv=*(const short8*)(ib+((size_t)(r*48+w)*64+c0+kg*8));
              acc[wc]=__builtin_amdgcn_mfma_f32_16x16x32_bf16(a,bv,acc[wc],0,0,0);
            }
          }
        }
      }
    }
#pragma unroll
    for(int wc=0;wc<3;wc++)
#pragma unroll
      for(int reg=0;reg<4;reg++)
        xsum[wc][reg]+=leaky((acc[wc][reg]-m_[reg])*scale[reg]+be_[reg]);
  }
#pragma unroll
  for(int wc=0;wc<3;wc++)
#pragma unroll
    for(int reg=0;reg<4;reg++)
      xl[(obase+reg)*49 + wc*16+n0]=xsum[wc][reg]*0.125f;
  __syncthreads();
  size_t base=(size_t)b*64*HW + r0*48;
  for(int e=threadIdx.x;e<3072;e+=256){
    int o=e/48, px=e-o*48;
    float s=zc_b[o];
#pragma unroll
    for(int c=0;c<64;c++) s+=zl[o*64+c]*xl[c*49+px];
    size_t a=base+(size_t)o*HW+px;
    out[a]=s+img[a];
  }
}

extern "C" void kernel_launch(void* const* d_in, const int* in_sizes, int n_in,
                              void* d_out, int out_size, void* d_ws, size_t ws_size,
                              hipStream_t stream){
  const float* bank   =(const float*)d_in[0];
  const float* task_f =(const float*)d_in[1];
  const float* img_f  =(const float*)d_in[2];
  const float* protos =(const float*)d_in[3];
  const float* tA_w1  =(const float*)d_in[4];
  const float* tA_w2  =(const float*)d_in[5];
  const float* iA_w   =(const float*)d_in[6];
  const float* iA_bn  =(const float*)d_in[7];
  const float* at_w1  =(const float*)d_in[8];
  const float* at_b1  =(const float*)d_in[9];
  const float* at_ln_g=(const float*)d_in[10];
  const float* at_ln_b=(const float*)d_in[11];
  const float* at_w2  =(const float*)d_in[12];
  const float* at_b2  =(const float*)d_in[13];
  const float* bv_t1  =(const float*)d_in[14];
  const float* bv_t2  =(const float*)d_in[15];
  const float* bv_ic1 =(const float*)d_in[16];
  const float* bv_bn1 =(const float*)d_in[17];
  const float* bv_ic2 =(const float*)d_in[18];
  const float* bv_bn2 =(const float*)d_in[19];
  const float* bv_w1  =(const float*)d_in[20];
  const float* bv_b1  =(const float*)d_in[21];
  const float* bv_ln_g=(const float*)d_in[22];
  const float* bv_ln_b=(const float*)d_in[23];
  const float* bv_w2  =(const float*)d_in[24];
  const float* bv_b2  =(const float*)d_in[25];
  const float* m1_w1  =(const float*)d_in[26];
  const float* m1_b1  =(const float*)d_in[27];
  const float* m1_ln_g=(const float*)d_in[28];
  const float* m1_ln_b=(const float*)d_in[29];
  const float* m1_w2  =(const float*)d_in[30];
  const float* m1_b2  =(const float*)d_in[31];
  const float* m3_w1  =(const float*)d_in[32];
  const float* m3_b1  =(const float*)d_in[33];
  const float* m3_ln_g=(const float*)d_in[34];
  const float* m3_ln_b=(const float*)d_in[35];
  const float* m3_w2  =(const float*)d_in[36];
  const float* m3_b2  =(const float*)d_in[37];
  const float* blr_bn =(const float*)d_in[38];
  const float* zc_w   =(const float*)d_in[39];
  const float* zc_b   =(const float*)d_in[40];

  float* ws=(float*)d_ws;
  float* totA=ws+0;       float* a0A=ws+16;      float* aLA=ws+32;
  float* totB=ws+48;      float* a0B=ws+304;     float* aLB=ws+560;
  float* rmsacc=ws+816;   float* i1 =ws+820;     float* ie =ws+852;   // ie: 852..1364
  int*   idxp  =(int*)(ws+2932);
  float* hid1=ws+3044;    float* hid3=ws+5092;
  unsigned short* A1p =(unsigned short*)(ws+7140);     // 131072 bf16
  unsigned short* A3p =(unsigned short*)(ws+72676);    // 1179648 bf16
  unsigned short* imgT=(unsigned short*)(ws+662500);   // 589824 bf16
  unsigned short* ie1T=(unsigned short*)(ws+957412);   // 589824 bf16
  unsigned short* W1Tp=(unsigned short*)(ws+1252324);  // 36864 bf16
  unsigned short* W2Tp=(unsigned short*)(ws+1270756);  // 73728 bf16
  unsigned short* WATp=(unsigned short*)(ws+1307620);  // 9216 bf16 -> ends 1312228
  // total ~5.2 MB

  hipMemsetAsync(ws, 0, 1364*sizeof(float), stream);   // stats accumulators + rmsacc + i1 + ie

  k_stats<<<dim3(NB,32),256,0,stream>>>(task_f, tA_w1, bv_t1,
                                        totA, a0A, aLA, totB, a0B, aLB, rmsacc);
  k_pre<<<612,256,0,stream>>>(img_f, bv_ic1, bv_ic2, iA_w, imgT, W1Tp, W2Tp, WATp);
  k_conv1<<<120,256,0,stream>>>(imgT, W1Tp, WATp, bv_bn1, iA_bn, ie1T, i1);
  k_ic2M<<<dim3(96,2),256,0,stream>>>(ie1T, W2Tp, bv_bn2, ie);
  k_mid<<<1,256,0,stream>>>(totA,a0A,aLA,totB,a0B,aLB, rmsacc, tA_w2, bv_t2, i1, ie,
                            at_w1, at_b1, at_ln_g, at_ln_b, at_w2, at_b2, protos,
                            bv_w1, bv_b1, bv_ln_g, bv_ln_b, bv_w2, bv_b2, bank,
                            m1_w1, m1_b1, m1_ln_g, m1_ln_b,
                            m3_w1, m3_b1, m3_ln_g, m3_ln_b,
                            idxp, hid1, hid3);
  k_heads<<<160,256,0,stream>>>(hid1, hid3, m1_w2, m1_b2, m3_w2, m3_b2, A1p, A3p);
  k_dynF<<<192,256,0,stream>>>(imgT, A1p, A3p, idxp, blr_bn, zc_w, zc_b, img_f, (float*)d_out);

  (void)in_sizes; (void)n_in; (void)out_size; (void)ws_size;
}

// Round 7
// 350.514 us; speedup vs baseline: 8.2585x; 1.1446x over previous
//
#include <hip/hip_runtime.h>
#include <math.h>

#define LEAKC 0.2f

#define NB 4
#define NC 64
#define LLEN 16384
#define HW 2304

typedef __attribute__((ext_vector_type(8))) short short8;
typedef __attribute__((ext_vector_type(4))) float floatx4;

__device__ __forceinline__ float leaky(float x){ return x > 0.f ? x : LEAKC*x; }

__device__ __forceinline__ float wave_sum64(float v){
  for(int off=32;off;off>>=1) v += __shfl_xor(v,off);
  return v;
}

__device__ __forceinline__ unsigned short f2bf(float x){
  unsigned u=__float_as_uint(x);
  unsigned r=u+0x7FFFu+((u>>16)&1u);
  return (unsigned short)(r>>16);
}

__device__ __forceinline__ void threefry2x32(unsigned k0, unsigned k1, unsigned& x0, unsigned& x1){
  unsigned ks0=k0, ks1=k1, ks2=k0^k1^0x1BD11BDAu;
  x0+=ks0; x1+=ks1;
  const int rot0[4]={13,15,26,6};
  const int rot1[4]={17,29,16,24};
#define TF_APPLY(rr) {for(int r=0;r<4;r++){x0+=x1; x1=(x1<<rr[r])|(x1>>(32-rr[r])); x1^=x0;}}
  TF_APPLY(rot0); x0+=ks1; x1+=ks2+1u;
  TF_APPLY(rot1); x0+=ks2; x1+=ks0+2u;
  TF_APPLY(rot0); x0+=ks0; x1+=ks1+3u;
  TF_APPLY(rot1); x0+=ks1; x1+=ks2+4u;
  TF_APPLY(rot0); x0+=ks2; x1+=ks0+5u;
#undef TF_APPLY
}

__device__ __forceinline__ float jax_uniform128(int i){
  unsigned x0=0u, x1=(unsigned)i;
  threefry2x32(0u,42u,x0,x1);
  unsigned bits = x0 ^ x1;
  unsigned fb=(bits>>9)|0x3f800000u;
  float f=__uint_as_float(fb)-1.0f;
  float u=f*(1.0f-1e-10f)+1e-10f;
  return fmaxf(1e-10f,u);
}

// ---------------- k_pre: stats (0..127) + imgT transpose (128..271) + weight prep (272..739) ----------------
__global__ __launch_bounds__(256) void k_pre(const float* __restrict__ task_f,
                      const float* __restrict__ w1A, const float* __restrict__ w1B,
                      float* __restrict__ totA, float* __restrict__ a0A, float* __restrict__ aLA,
                      float* __restrict__ totB, float* __restrict__ a0B, float* __restrict__ aLB,
                      float* __restrict__ rmsacc,
                      const float* __restrict__ img,
                      const float* __restrict__ w1, const float* __restrict__ w2,
                      const float* __restrict__ wa,
                      unsigned short* __restrict__ imgT,
                      unsigned short* __restrict__ W1T, unsigned short* __restrict__ W2T,
                      unsigned short* __restrict__ WAT){
  if(blockIdx.x<128){
    int b=blockIdx.x>>5, seg=blockIdx.x&31;
    const float* x=task_f+b*LLEN;
    float tA[4]={0,0,0,0};
    float tB[64];
#pragma unroll
    for(int c=0;c<64;c++) tB[c]=0.f;
    float sq=0.f;
    int l0=seg*512;
    for(int l=l0+threadIdx.x;l<l0+512;l+=256){
      float xm=(l>0)?x[l-1]:0.f;
      float xc=x[l];
      float xp=(l<LLEN-1)?x[l+1]:0.f;
      sq+=xc*xc;
#pragma unroll
      for(int c=0;c<4;c++){
        float a=leaky(w1A[c*3+0]*xm + w1A[c*3+1]*xc + w1A[c*3+2]*xp);
        tA[c]+=a;
        if(l==0) a0A[b*4+c]=a;
        if(l==LLEN-1) aLA[b*4+c]=a;
      }
#pragma unroll
      for(int c=0;c<64;c++){
        float a=leaky(w1B[c*3+0]*xm + w1B[c*3+1]*xc + w1B[c*3+2]*xp);
        tB[c]+=a;
        if(l==0) a0B[b*64+c]=a;
        if(l==LLEN-1) aLB[b*64+c]=a;
      }
    }
    sq=wave_sum64(sq);
#pragma unroll
    for(int c=0;c<4;c++) tA[c]=wave_sum64(tA[c]);
#pragma unroll
    for(int c=0;c<64;c++){
      float v=tB[c];
      for(int off=32;off;off>>=1) v+=__shfl_down(v,off);
      tB[c]=v;
    }
    __shared__ float redB[4][64];
    __shared__ float redA[4][4];
    __shared__ float redQ[4];
    int wave=threadIdx.x>>6, lane=threadIdx.x&63;
    if(lane==0){
#pragma unroll
      for(int c=0;c<64;c++) redB[wave][c]=tB[c];
#pragma unroll
      for(int c=0;c<4;c++) redA[wave][c]=tA[c];
      redQ[wave]=sq;
    }
    __syncthreads();
    if(threadIdx.x<64){
      float s=redB[0][threadIdx.x]+redB[1][threadIdx.x]+redB[2][threadIdx.x]+redB[3][threadIdx.x];
      atomicAdd(&totB[b*64+threadIdx.x], s);
    } else if(threadIdx.x<68){
      int c=threadIdx.x-64;
      float s=redA[0][c]+redA[1][c]+redA[2][c]+redA[3][c];
      atomicAdd(&totA[b*4+c], s);
    } else if(threadIdx.x==68){
      atomicAdd(&rmsacc[b], redQ[0]+redQ[1]+redQ[2]+redQ[3]);
    }
  } else if(blockIdx.x<272){
    int blk=blockIdx.x-128;
    int b=blk/36, t=blk%36;
    int p0=t*64;
    __shared__ float tile[64][65];
    int pp=threadIdx.x&63, c4=threadIdx.x>>6;
    for(int r=0;r<16;r++){
      int c=c4*16+r;
      tile[c][pp]=img[(b*64+c)*HW + p0+pp];
    }
    __syncthreads();
    int px=threadIdx.x>>2, cg=(threadIdx.x&3)*16;
    unsigned out[8];
#pragma unroll
    for(int q=0;q<8;q++){
      unsigned lo=f2bf(tile[cg+2*q][px]);
      unsigned hi=f2bf(tile[cg+2*q+1][px]);
      out[q]=lo|(hi<<16);
    }
    unsigned* dst=(unsigned*)(imgT + ((size_t)(b*HW+p0+px)*64 + cg));
#pragma unroll
    for(int q=0;q<8;q++) dst[q]=out[q];
  } else {
    int n=(blockIdx.x-272)*256+threadIdx.x;
    if(n<9*64*64){
      int tap=n>>12, oc=(n>>6)&63, c=n&63;
      W1T[n]=f2bf(w1[oc*576+c*9+tap]);
    } else if(n<9*64*64+9*128*64){
      int m=n-9*64*64;
      int tap=m/8192, r=m-tap*8192, oc=r>>6, c=r&63;
      W2T[m]=f2bf(w2[oc*576+c*9+tap]);
    } else {
      int q=n-9*64*64-9*128*64;
      if(q<9*16*64){
        int tap=q>>10, r=q&1023, o=r>>6, c=r&63;
        WAT[q]=(o<8)?f2bf(wa[o*576+c*9+tap]):(unsigned short)0;
      }
    }
  }
}

// ---------------- k_conv1: ic1 MFMA (blocks 0..95) + iA MFMA mean (96..119) ----------------
__global__ __launch_bounds__(256) void k_conv1(const unsigned short* __restrict__ imgT,
                        const unsigned short* __restrict__ W1T,
                        const unsigned short* __restrict__ WAT,
                        const float* __restrict__ bn1, const float* __restrict__ bnA,
                        unsigned short* __restrict__ ie1T, float* __restrict__ i1){
  int lane=threadIdx.x&63, mt=threadIdx.x>>6;
  int n0=lane&15, kg=lane>>4;
  if(blockIdx.x<96){
    int blk=blockIdx.x;
    int b=blk/24, hp=blk-b*24;
    int h0=hp*2;
    const unsigned short* ib=imgT+(size_t)b*HW*64;
    floatx4 acc[6];
#pragma unroll
    for(int i=0;i<6;i++) acc[i]=(floatx4){0.f,0.f,0.f,0.f};
    for(int ti=0;ti<3;ti++){
      for(int tj=0;tj<3;tj++){
        int tap=ti*3+tj;
        int dh=ti-1, dw=tj-1;
        const unsigned short* Ab=W1T+(size_t)tap*4096;
#pragma unroll
        for(int c0=0;c0<64;c0+=32){
          short8 a=*(const short8*)(Ab+((mt*16+n0)*64+c0+kg*8));
#pragma unroll
          for(int rr=0;rr<2;rr++){
            int r=h0+rr+dh;
            if((unsigned)r>=48u) continue;
#pragma unroll
            for(int wc=0;wc<3;wc++){
              int w=wc*16+n0+dw;
              bool inb=(unsigned)w<48u;
              short8 bv={0,0,0,0,0,0,0,0};
              if(inb) bv=*(const short8*)(ib+((size_t)(r*48+w)*64+c0+kg*8));
              acc[rr*3+wc]=__builtin_amdgcn_mfma_f32_16x16x32_bf16(a,bv,acc[rr*3+wc],0,0,0);
            }
          }
        }
      }
    }
    int obase=mt*16+kg*4;
    float scale[4],m_[4],be_[4];
#pragma unroll
    for(int reg=0;reg<4;reg++){
      int o=obase+reg;
      scale[reg]=bn1[o]/sqrtf(bn1[192+o]+1e-5f);
      m_[reg]=bn1[128+o]; be_[reg]=bn1[64+o];
    }
#pragma unroll
    for(int rr=0;rr<2;rr++){
#pragma unroll
      for(int wc=0;wc<3;wc++){
        int px=(h0+rr)*48+wc*16+n0;
        float v0=leaky((acc[rr*3+wc][0]-m_[0])*scale[0]+be_[0]);
        float v1=leaky((acc[rr*3+wc][1]-m_[1])*scale[1]+be_[1]);
        float v2=leaky((acc[rr*3+wc][2]-m_[2])*scale[2]+be_[2]);
        float v3=leaky((acc[rr*3+wc][3]-m_[3])*scale[3]+be_[3]);
        unsigned w0=f2bf(v0)|((unsigned)f2bf(v1)<<16);
        unsigned w1=f2bf(v2)|((unsigned)f2bf(v3)<<16);
        uint2 pk={w0,w1};
        *(uint2*)(ie1T+((size_t)(b*HW+px)*64+obase))=pk;
      }
    }
  } else {
    int blk=blockIdx.x-96;
    int b=blk/6, hg=blk%6;
    int hp=hg*4+mt;
    int h0=hp*2;
    const unsigned short* ib=imgT+(size_t)b*HW*64;
    floatx4 acc[6];
#pragma unroll
    for(int i=0;i<6;i++) acc[i]=(floatx4){0.f,0.f,0.f,0.f};
    for(int ti=0;ti<3;ti++){
      for(int tj=0;tj<3;tj++){
        int tap=ti*3+tj;
        int dh=ti-1, dw=tj-1;
        const unsigned short* Ab=WAT+(size_t)tap*1024;
#pragma unroll
        for(int c0=0;c0<64;c0+=32){
          short8 a=*(const short8*)(Ab+(n0*64+c0+kg*8));
#pragma unroll
          for(int rr=0;rr<2;rr++){
            int r=h0+rr+dh;
            if((unsigned)r>=48u) continue;
#pragma unroll
            for(int wc=0;wc<3;wc++){
              int w=wc*16+n0+dw;
              bool inb=(unsigned)w<48u;
              short8 bv={0,0,0,0,0,0,0,0};
              if(inb) bv=*(const short8*)(ib+((size_t)(r*48+w)*64+c0+kg*8));
              acc[rr*3+wc]=__builtin_amdgcn_mfma_f32_16x16x32_bf16(a,bv,acc[rr*3+wc],0,0,0);
            }
          }
        }
      }
    }
    int obase=kg*4;
#pragma unroll
    for(int reg=0;reg<4;reg++){
      int o=obase+reg;
      float part=0;
      if(o<8){
        float scale=bnA[o]/sqrtf(bnA[24+o]+1e-5f);
        float m_=bnA[16+o], be_=bnA[8+o];
#pragma unroll
        for(int i=0;i<6;i++) part+=leaky((acc[i][reg]-m_)*scale+be_);
      }
      for(int off=1;off<16;off<<=1) part+=__shfl_xor(part,off);
      if(n0==0 && o<8) atomicAdd(&i1[b*8+o], part*(1.f/2304.f));
    }
  }
}

// ---------------- bv_ic2 conv via MFMA + bn + leaky + spatial mean -> ie (B,128) ----------------
__global__ __launch_bounds__(256) void k_ic2M(const unsigned short* __restrict__ ie1T,
                       const unsigned short* __restrict__ W2T,
                       const float* __restrict__ bn, float* __restrict__ ie){
  int blk=blockIdx.x;
  int b=blk/24, hp=blk-b*24;
  int mo=blockIdx.y*64;
  int lane=threadIdx.x&63, mt=threadIdx.x>>6;
  int n0=lane&15, kg=lane>>4;
  int h0=hp*2;
  const unsigned short* ib=ie1T+(size_t)b*HW*64;
  floatx4 acc[6];
#pragma unroll
  for(int i=0;i<6;i++) acc[i]=(floatx4){0.f,0.f,0.f,0.f};
  for(int ti=0;ti<3;ti++){
    for(int tj=0;tj<3;tj++){
      int tap=ti*3+tj;
      int dh=ti-1, dw=tj-1;
      const unsigned short* Ab=W2T+(size_t)tap*8192;
#pragma unroll
      for(int c0=0;c0<64;c0+=32){
        short8 a=*(const short8*)(Ab+((mo+mt*16+n0)*64+c0+kg*8));
#pragma unroll
        for(int rr=0;rr<2;rr++){
          int r=h0+rr+dh;
          if((unsigned)r>=48u) continue;
#pragma unroll
          for(int wc=0;wc<3;wc++){
            int w=wc*16+n0+dw;
            bool inb=(unsigned)w<48u;
            short8 bv={0,0,0,0,0,0,0,0};
            if(inb) bv=*(const short8*)(ib+((size_t)(r*48+w)*64+c0+kg*8));
            acc[rr*3+wc]=__builtin_amdgcn_mfma_f32_16x16x32_bf16(a,bv,acc[rr*3+wc],0,0,0);
          }
        }
      }
    }
  }
  int obase=mo+mt*16+kg*4;
#pragma unroll
  for(int reg=0;reg<4;reg++){
    int o=obase+reg;
    float scale=bn[o]/sqrtf(bn[384+o]+1e-5f);
    float m_=bn[256+o], be_=bn[128+o];
    float part=0;
#pragma unroll
    for(int i=0;i<6;i++) part+=leaky((acc[i][reg]-m_)*scale+be_);
    for(int off=1;off<16;off<<=1) part+=__shfl_xor(part,off);
    if(n0==0) atomicAdd(&ie[b*128+o], part*(1.f/2304.f));
  }
}

// ---------------- fused mid, PER-BATCH block (grid=4): te+att+ff+sel+hid ----------------
__global__ __launch_bounds__(256) void k_mid(
    const float* __restrict__ totA, const float* __restrict__ a0A, const float* __restrict__ aLA,
    const float* __restrict__ totB, const float* __restrict__ a0B, const float* __restrict__ aLB,
    const float* __restrict__ rmsacc,
    const float* __restrict__ tA_w2, const float* __restrict__ bv_t2,
    const float* __restrict__ i1, const float* __restrict__ ie,
    const float* __restrict__ at_w1, const float* __restrict__ at_b1,
    const float* __restrict__ at_ln_g, const float* __restrict__ at_ln_b,
    const float* __restrict__ at_w2, const float* __restrict__ at_b2,
    const float* __restrict__ protos,
    const float* __restrict__ bv_w1, const float* __restrict__ bv_b1,
    const float* __restrict__ bv_ln_g, const float* __restrict__ bv_ln_b,
    const float* __restrict__ bv_w2, const float* __restrict__ bv_b2,
    const float* __restrict__ bank,
    const float* __restrict__ m1_w1, const float* __restrict__ m1_b1,
    const float* __restrict__ m1_g,  const float* __restrict__ m1_bb,
    const float* __restrict__ m3_w1, const float* __restrict__ m3_b1,
    const float* __restrict__ m3_g,  const float* __restrict__ m3_bb,
    int* __restrict__ idxo, float* __restrict__ hid1, float* __restrict__ hid3){
  int b=blockIdx.x;
  int tid=threadIdx.x;
  int lane=tid&63, wv=tid>>6;
  const float invL=1.0f/16384.0f;
  __shared__ float sT[64], s0[64], sL[64];
  __shared__ float te_s[128], t1_s[8];
  __shared__ float f1[16], h[64], tif[128], tifn[128], tden[8], pden[4], pn[64], z[32];
  __shared__ int sidx[8], sfirst[4], srank[8], rows[8];
  __shared__ float fbuf[256], hh[64], ffn_s[256], finv_s;
  __shared__ float scores[64];
  __shared__ int order[64];
  __shared__ float bvf[2048];

  // ---- stage 1: te (128) + t1 (8) for this b ----
  if(tid<64){ sT[tid]=totB[b*64+tid]; s0[tid]=a0B[b*64+tid]; sL[tid]=aLB[b*64+tid]; }
  __syncthreads();
  float scB=1.0f/(sqrtf(rmsacc[b]*invL)+1e-8f);
  if(tid<128){
    int c2=tid;
    const float* wr=bv_t2+c2*192;
    float s=0;
    for(int c1=0;c1<64;c1+=8){
      float4 q[6];
      const float4* r4=(const float4*)(wr+c1*3);
#pragma unroll
      for(int u=0;u<6;u++) q[u]=r4[u];
      const float* qq=(const float*)q;
#pragma unroll
      for(int u=0;u<8;u++){
        int c=c1+u;
        float T=sT[c], A0=s0[c], AL=sL[c];
        s += qq[u*3+0]*(T-AL) + qq[u*3+1]*T + qq[u*3+2]*(T-A0);
      }
    }
    te_s[c2]=s*invL*scB;
  } else if(tid<136){
    int c2=tid-128;
    float s=0;
    for(int c1=0;c1<4;c1++){
      float T=totA[b*4+c1], A0=a0A[b*4+c1], AL=aLA[b*4+c1];
      const float* w=&tA_w2[(c2*4+c1)*3];
      s += w[0]*(T-AL) + w[1]*T + w[2]*(T-A0);
    }
    t1_s[c2]=s*invL;
  }
  __syncthreads();

  // ---- stage 2: attention MLP -> idx/first/rank ----
  if(tid<8) f1[tid]=t1_s[tid];
  else if(tid<16) f1[tid]=i1[b*8+tid-8];
  __syncthreads();
  if(tid<64){
    float s=at_b1[lane];
#pragma unroll
    for(int i=0;i<16;i++) s+=f1[i]*at_w1[i*64+lane];
    float mu=wave_sum64(s)*(1.f/64.f);
    float d=s-mu;
    float var=wave_sum64(d*d)*(1.f/64.f);
    h[lane]=fmaxf(d*(1.0f/sqrtf(var+1e-5f))*at_ln_g[lane]+at_ln_b[lane],0.f);
  }
  __syncthreads();
  if(tid<128){
    int n=tid;
    float a0=0,a1=0;
    for(int k=0;k<64;k+=2){
      a0+=h[k]*at_w2[k*128+n];
      a1+=h[k+1]*at_w2[(k+1)*128+n];
    }
    tif[n]=at_b2[n]+a0+a1;
  }
  __syncthreads();
  if(tid<8){
    int f=tid;
    float ss=0; for(int e=0;e<16;e++){float v=tif[e*8+f]; ss+=v*v;}
    tden[f]=fmaxf(sqrtf(ss),1e-8f);
  } else if(tid<12){
    int t=tid-8;
    float ss=0; for(int e=0;e<16;e++){float v=protos[t*16+e]; ss+=v*v;}
    pden[t]=fmaxf(sqrtf(ss),1e-8f);
  }
  __syncthreads();
  if(tid<128) tifn[tid]=tif[tid]/tden[tid&7];
  if(tid<64) pn[tid]=protos[tid]/pden[tid>>4];
  __syncthreads();
  if(tid<32){
    int f=tid>>2, t=tid&3;
    float ss=0;
#pragma unroll
    for(int e=0;e<16;e++) ss+=pn[t*16+e]*tifn[e*8+f];
    float u=jax_uniform128(b*32+f*4+t);
    float g=-logf(-logf(u));
    z[tid]=ss+g;
  }
  __syncthreads();
  if(tid<8){
    float best=z[tid*4]; int bi=0;
    for(int t=1;t<4;t++){ float v=z[tid*4+t]; if(v>best){best=v;bi=t;} }
    sidx[tid]=bi;
  }
  __syncthreads();
  if(tid<4){
    int t=tid;
    int fi=0;
    for(int f=7;f>=0;f--) if(sidx[f]==t) fi=f;
    sfirst[t]=fi;
  } else if(tid<12){
    int f=tid-4;
    int c=0; for(int f2=0;f2<f;f2++) if(sidx[f2]==sidx[f]) c++;
    srank[f]=c;
  }
  __syncthreads();

  // ---- stage 3: branch-B MLP -> normalized ff ----
  if(tid<128) fbuf[tid]=te_s[tid];
  else fbuf[tid]=ie[b*128+tid-128];
  __syncthreads();
  if(tid<64){
    float a0=0,a1=0,a2=0,a3=0;
    for(int k=0;k<256;k+=4){
      a0+=fbuf[k]  *bv_w1[k*64+lane];
      a1+=fbuf[k+1]*bv_w1[(k+1)*64+lane];
      a2+=fbuf[k+2]*bv_w1[(k+2)*64+lane];
      a3+=fbuf[k+3]*bv_w1[(k+3)*64+lane];
    }
    float s=bv_b1[lane]+((a0+a1)+(a2+a3));
    float mu=wave_sum64(s)*(1.f/64.f);
    float d=s-mu;
    float var=wave_sum64(d*d)*(1.f/64.f);
    hh[lane]=fmaxf(d*(1.0f/sqrtf(var+1e-5f))*bv_ln_g[lane]+bv_ln_b[lane],0.f);
  }
  __syncthreads();
  {
    int n=tid;
    float a0=0,a1=0;
    for(int k=0;k<64;k+=2){
      a0+=hh[k]*bv_w2[k*256+n];
      a1+=hh[k+1]*bv_w2[(k+1)*256+n];
    }
    ffn_s[n]=bv_b2[n]+a0+a1;
  }
  __syncthreads();
  if(tid<64){
    float sq=0;
#pragma unroll
    for(int u=0;u<4;u++){ float v=ffn_s[u*64+lane]; sq+=v*v; }
    sq=wave_sum64(sq);
    if(lane==0) finv_s=1.0f/fmaxf(sqrtf(sq),1e-12f);
  }
  __syncthreads();
  ffn_s[tid]*=finv_s;
  __syncthreads();

  // ---- stage 4: scores + argsort + selection ----
  if(tid<64){
    int t=tid>>4, v=tid&15;
    int tt=sidx[sfirst[t]];
    const float4* row=(const float4*)(bank+(tt*16+v)*256);
    float sa=0,sb=0,na=0,nb=0;
    for(int d4=0;d4<64;d4+=2){
      float4 r1=row[d4], r2=row[d4+1];
      const float* f1p=&ffn_s[d4*4];
      sa+=f1p[0]*r1.x+f1p[1]*r1.y+f1p[2]*r1.z+f1p[3]*r1.w;
      na+=r1.x*r1.x+r1.y*r1.y+r1.z*r1.z+r1.w*r1.w;
      sb+=f1p[4]*r2.x+f1p[5]*r2.y+f1p[6]*r2.z+f1p[7]*r2.w;
      nb+=r2.x*r2.x+r2.y*r2.y+r2.z*r2.z+r2.w*r2.w;
    }
    scores[tid]=(sa+sb)/fmaxf(sqrtf(na+nb),1e-12f);
  }
  __syncthreads();
  if(tid<4){
    const float* sc=&scores[tid*16];
    unsigned used=0;
    for(int pk=0;pk<16;pk++){
      int best=-1; float bv=-1e30f;
      for(int v2=0;v2<16;v2++){
        if(used&(1u<<v2)) continue;
        float vv=sc[v2];
        if(best<0||vv>bv){bv=vv;best=v2;}
      }
      used|=1u<<best;
      order[tid*16+pk]=best;
    }
  }
  __syncthreads();
  if(tid<8){
    int t=sidx[tid];
    int v=order[t*16+srank[tid]];
    rows[tid]=t*16+v;
    idxo[b*8+tid]=t;
  }
  __syncthreads();

  // ---- stage 5: gather bank rows + m1/m3 hidden (4-acc ILP, wave LN) ----
  for(int ii=tid;ii<2048;ii+=256){
    int r=ii>>8, d=ii&255;
    bvf[ii]=bank[rows[r]*256+d];
  }
  __syncthreads();
  for(int it=0;it<2;it++){
    int r=wv*2+it;
    const float* bp=&bvf[r*256];
    float a0=0,a1=0,a2=0,a3=0;
    float c0=0,c1=0,c2=0,c3=0;
    for(int d=0;d<256;d+=4){
      float b0=bp[d],b1=bp[d+1],b2=bp[d+2],b3=bp[d+3];
      a0+=b0*m1_w1[d*64+lane];
      a1+=b1*m1_w1[(d+1)*64+lane];
      a2+=b2*m1_w1[(d+2)*64+lane];
      a3+=b3*m1_w1[(d+3)*64+lane];
      c0+=b0*m3_w1[d*64+lane];
      c1+=b1*m3_w1[(d+1)*64+lane];
      c2+=b2*m3_w1[(d+2)*64+lane];
      c3+=b3*m3_w1[(d+3)*64+lane];
    }
    float s1=m1_b1[lane]+((a0+a1)+(a2+a3));
    float s3=m3_b1[lane]+((c0+c1)+(c2+c3));
    float mu=wave_sum64(s1)*(1.f/64.f);
    float dd=s1-mu;
    float var=wave_sum64(dd*dd)*(1.f/64.f);
    hid1[(b*8+r)*64+lane]=fmaxf(dd*(1.0f/sqrtf(var+1e-5f))*m1_g[lane]+m1_bb[lane],0.f);
    mu=wave_sum64(s3)*(1.f/64.f);
    dd=s3-mu;
    var=wave_sum64(dd*dd)*(1.f/64.f);
    hid3[(b*8+r)*64+lane]=fmaxf(dd*(1.0f/sqrtf(var+1e-5f))*m3_g[lane]+m3_bb[lane],0.f);
  }
}

// ---------------- k_heads: w1 head (blocks 0..15) + w3 head (16..159) ----------------
__global__ __launch_bounds__(256) void k_heads(const float* __restrict__ hid1, const float* __restrict__ hid3,
                        const float* __restrict__ w2a, const float* __restrict__ b2a,
                        const float* __restrict__ w2b, const float* __restrict__ b2b,
                        unsigned short* __restrict__ A1, unsigned short* __restrict__ A3){
  __shared__ float hl[2048];
  if(blockIdx.x<16){
    int n=blockIdx.x*256+threadIdx.x;
    for(int i=threadIdx.x;i<2048;i+=256) hl[i]=hid1[i];
    __syncthreads();
    float wcol[64];
#pragma unroll
    for(int k=0;k<64;k++) wcol[k]=w2a[k*4096+n];
    float bb=b2a[n];
    for(int bf=0;bf<32;bf++){
      float s=bb;
#pragma unroll
      for(int k=0;k<64;k++) s+=hl[bf*64+k]*wcol[k];
      A1[bf*4096+n]=f2bf(s);
    }
  } else {
    int n=(blockIdx.x-16)*256+threadIdx.x;
    for(int i=threadIdx.x;i<2048;i+=256) hl[i]=hid3[i];
    __syncthreads();
    float wcol[64];
#pragma unroll
    for(int k=0;k<64;k++) wcol[k]=w2b[(size_t)k*36864+n];
    float bb=b2b[n];
    int o=n/576, rem=n-o*576;
    int c=rem/9, tap=rem-c*9;
    size_t base=((size_t)tap*64+o)*64+c;
    for(int bf=0;bf<32;bf++){
      float s=bb;
#pragma unroll
      for(int k=0;k<64;k++) s+=hl[bf*64+k]*wcol[k];
      A3[(size_t)bf*9*4096+base]=f2bf(s);
    }
  }
}

// ---------------- fused dynamic conv: f-loop in-block + bn + leaky + f-mean + zc 1x1 + residual ----------------
__global__ __launch_bounds__(256) void k_dynF(const unsigned short* __restrict__ imgT,
                       const unsigned short* __restrict__ A1, const unsigned short* __restrict__ A3,
                       const int* __restrict__ idx, const float* __restrict__ bn,
                       const float* __restrict__ zc_w, const float* __restrict__ zc_b,
                       const float* __restrict__ img, float* __restrict__ out){
  int blk=blockIdx.x;
  int b=blk/48, r0=blk-b*48;
  int lane=threadIdx.x&63, mt=threadIdx.x>>6;
  int n0=lane&15, kg=lane>>4;
  __shared__ float xl[64*49];
  __shared__ float zl[4096];
  for(int i=threadIdx.x;i<4096;i+=256) zl[i]=zc_w[i];
  const unsigned short* ib=imgT+(size_t)b*HW*64;
  int obase=mt*16+kg*4;
  float scale[4],m_[4],be_[4];
#pragma unroll
  for(int reg=0;reg<4;reg++){
    int o=obase+reg;
    scale[reg]=bn[o]/sqrtf(bn[192+o]+1e-5f);
    m_[reg]=bn[128+o]; be_[reg]=bn[64+o];
  }
  float xsum[3][4];
#pragma unroll
  for(int wc=0;wc<3;wc++)
#pragma unroll
    for(int reg=0;reg<4;reg++) xsum[wc][reg]=0.f;
  for(int f=0;f<8;f++){
    int bf=b*8+f;
    int tt=idx[bf];
    floatx4 acc[3];
#pragma unroll
    for(int i=0;i<3;i++) acc[i]=(floatx4){0.f,0.f,0.f,0.f};
    if(tt==0){
      const unsigned short* Ab=A1+(size_t)bf*4096;
#pragma unroll
      for(int c0=0;c0<64;c0+=32){
        short8 a=*(const short8*)(Ab+((mt*16+n0)*64+c0+kg*8));
#pragma unroll
        for(int wc=0;wc<3;wc++){
          int px=r0*48+wc*16+n0;
          short8 bv=*(const short8*)(ib+((size_t)px*64+c0+kg*8));
          acc[wc]=__builtin_amdgcn_mfma_f32_16x16x32_bf16(a,bv,acc[wc],0,0,0);
        }
      }
    } else {
      int d=tt;
      const unsigned short* A3b=A3+(size_t)bf*9*4096;
      for(int ti=0;ti<3;ti++){
        int r=r0+d*(ti-1);
        if((unsigned)r>=48u) continue;
        for(int tj=0;tj<3;tj++){
          int tap=ti*3+tj;
          int dw=d*(tj-1);
          const unsigned short* Ab=A3b+(size_t)tap*4096;
#pragma unroll
          for(int c0=0;c0<64;c0+=32){
            short8 a=*(const short8*)(Ab+((mt*16+n0)*64+c0+kg*8));
#pragma unroll
            for(int wc=0;wc<3;wc++){
              int w=wc*16+n0+dw;
              bool inb=(unsigned)w<48u;
              short8 bv={0,0,0,0,0,0,0,0};
              if(inb) bv=*(const short8*)(ib+((size_t)(r*48+w)*64+c0+kg*8));
              acc[wc]=__builtin_amdgcn_mfma_f32_16x16x32_bf16(a,bv,acc[wc],0,0,0);
            }
          }
        }
      }
    }
#pragma unroll
    for(int wc=0;wc<3;wc++)
#pragma unroll
      for(int reg=0;reg<4;reg++)
        xsum[wc][reg]+=leaky((acc[wc][reg]-m_[reg])*scale[reg]+be_[reg]);
  }
#pragma unroll
  for(int wc=0;wc<3;wc++)
#pragma unroll
    for(int reg=0;reg<4;reg++)
      xl[(obase+reg)*49 + wc*16+n0]=xsum[wc][reg]*0.125f;
  __syncthreads();
  size_t base=(size_t)b*64*HW + r0*48;
  for(int e=threadIdx.x;e<3072;e+=256){
    int o=e/48, px=e-o*48;
    float s=zc_b[o];
#pragma unroll
    for(int c=0;c<64;c++) s+=zl[o*64+c]*xl[c*49+px];
    size_t a=base+(size_t)o*HW+px;
    out[a]=s+img[a];
  }
}

extern "C" void kernel_launch(void* const* d_in, const int* in_sizes, int n_in,
                              void* d_out, int out_size, void* d_ws, size_t ws_size,
                              hipStream_t stream){
  const float* bank   =(const float*)d_in[0];
  const float* task_f =(const float*)d_in[1];
  const float* img_f  =(const float*)d_in[2];
  const float* protos =(const float*)d_in[3];
  const float* tA_w1  =(const float*)d_in[4];
  const float* tA_w2  =(const float*)d_in[5];
  const float* iA_w   =(const float*)d_in[6];
  const float* iA_bn  =(const float*)d_in[7];
  const float* at_w1  =(const float*)d_in[8];
  const float* at_b1  =(const float*)d_in[9];
  const float* at_ln_g=(const float*)d_in[10];
  const float* at_ln_b=(const float*)d_in[11];
  const float* at_w2  =(const float*)d_in[12];
  const float* at_b2  =(const float*)d_in[13];
  const float* bv_t1  =(const float*)d_in[14];
  const float* bv_t2  =(const float*)d_in[15];
  const float* bv_ic1 =(const float*)d_in[16];
  const float* bv_bn1 =(const float*)d_in[17];
  const float* bv_ic2 =(const float*)d_in[18];
  const float* bv_bn2 =(const float*)d_in[19];
  const float* bv_w1  =(const float*)d_in[20];
  const float* bv_b1  =(const float*)d_in[21];
  const float* bv_ln_g=(const float*)d_in[22];
  const float* bv_ln_b=(const float*)d_in[23];
  const float* bv_w2  =(const float*)d_in[24];
  const float* bv_b2  =(const float*)d_in[25];
  const float* m1_w1  =(const float*)d_in[26];
  const float* m1_b1  =(const float*)d_in[27];
  const float* m1_ln_g=(const float*)d_in[28];
  const float* m1_ln_b=(const float*)d_in[29];
  const float* m1_w2  =(const float*)d_in[30];
  const float* m1_b2  =(const float*)d_in[31];
  const float* m3_w1  =(const float*)d_in[32];
  const float* m3_b1  =(const float*)d_in[33];
  const float* m3_ln_g=(const float*)d_in[34];
  const float* m3_ln_b=(const float*)d_in[35];
  const float* m3_w2  =(const float*)d_in[36];
  const float* m3_b2  =(const float*)d_in[37];
  const float* blr_bn =(const float*)d_in[38];
  const float* zc_w   =(const float*)d_in[39];
  const float* zc_b   =(const float*)d_in[40];

  float* ws=(float*)d_ws;
  float* totA=ws+0;       float* a0A=ws+16;      float* aLA=ws+32;
  float* totB=ws+48;      float* a0B=ws+304;     float* aLB=ws+560;
  float* rmsacc=ws+816;   float* i1 =ws+820;     float* ie =ws+852;   // ie: 852..1364
  int*   idxp  =(int*)(ws+2932);
  float* hid1=ws+3044;    float* hid3=ws+5092;
  unsigned short* A1p =(unsigned short*)(ws+7140);
  unsigned short* A3p =(unsigned short*)(ws+72676);
  unsigned short* imgT=(unsigned short*)(ws+662500);
  unsigned short* ie1T=(unsigned short*)(ws+957412);
  unsigned short* W1Tp=(unsigned short*)(ws+1252324);
  unsigned short* W2Tp=(unsigned short*)(ws+1270756);
  unsigned short* WATp=(unsigned short*)(ws+1307620);
  // total ~5.2 MB

  hipMemsetAsync(ws, 0, 1364*sizeof(float), stream);   // stats accumulators + rmsacc + i1 + ie

  k_pre<<<740,256,0,stream>>>(task_f, tA_w1, bv_t1,
                              totA, a0A, aLA, totB, a0B, aLB, rmsacc,
                              img_f, bv_ic1, bv_ic2, iA_w, imgT, W1Tp, W2Tp, WATp);
  k_conv1<<<120,256,0,stream>>>(imgT, W1Tp, WATp, bv_bn1, iA_bn, ie1T, i1);
  k_ic2M<<<dim3(96,2),256,0,stream>>>(ie1T, W2Tp, bv_bn2, ie);
  k_mid<<<4,256,0,stream>>>(totA,a0A,aLA,totB,a0B,aLB, rmsacc, tA_w2, bv_t2, i1, ie,
                            at_w1, at_b1, at_ln_g, at_ln_b, at_w2, at_b2, protos,
                            bv_w1, bv_b1, bv_ln_g, bv_ln_b, bv_w2, bv_b2, bank,
                            m1_w1, m1_b1, m1_ln_g, m1_ln_b,
                            m3_w1, m3_b1, m3_ln_g, m3_ln_b,
                            idxp, hid1, hid3);
  k_heads<<<160,256,0,stream>>>(hid1, hid3, m1_w2, m1_b2, m3_w2, m3_b2, A1p, A3p);
  k_dynF<<<192,256,0,stream>>>(imgT, A1p, A3p, idxp, blr_bn, zc_w, zc_b, img_f, (float*)d_out);

  (void)in_sizes; (void)n_in; (void)out_size; (void)ws_size;
}